// Round 17
// baseline (426.522 us; speedup 1.0000x reference)
//
#include <hip/hip_runtime.h>
#include <math.h>

typedef unsigned short u16;
typedef unsigned int u32;
typedef __attribute__((ext_vector_type(8))) short bf16x8;
typedef __attribute__((ext_vector_type(8))) unsigned short u16x8;
typedef __attribute__((ext_vector_type(4))) float f32x4;
typedef __attribute__((ext_vector_type(4))) unsigned int u32x4;

__device__ __forceinline__ u16 f2bf(float f){
  union { float f; unsigned u; } c; c.f = f;
  unsigned u = c.u;
  return (u16)((u + 0x7fffu + ((u >> 16) & 1u)) >> 16);
}
__device__ __forceinline__ float bf2f(u16 h){
  union { unsigned u; float f; } c; c.u = ((unsigned)h) << 16;
  return c.f;
}
__device__ __forceinline__ u32 pack2(float lo, float hi){
  return (u32)f2bf(lo) | ((u32)f2bf(hi) << 16);
}
__device__ __forceinline__ void gload_lds16(const void* g, void* l){
  __builtin_amdgcn_global_load_lds((const __attribute__((address_space(1))) void*)g,
                                   (__attribute__((address_space(3))) void*)l, 16, 0, 0);
}
// attention V^T swizzle: XOR row bits into chunk bits 2-5 (byte bits 6-9).
// PV read chunk = g + ((cg^q)<<2): 64 distinct chunks per read -> conflict-free.
// Staging (key = idx%W): 64 lanes span 64 keys -> banks key/2 cover all 32 -> free.
__device__ __forceinline__ int swz(int row, int bc){
  return (row << 10) + (bc ^ ((row & 15) << 6));
}

#define BAR() asm volatile("s_barrier" ::: "memory")

// ---------------- weight transpose + f32->bf16 : in [K][N] f32 -> out [N][K] bf16
__global__ void transpose_cvt(const float* __restrict__ in, u16* __restrict__ out, int K, int N){
  __shared__ float tile[32][33];
  int n0 = blockIdx.x << 5, k0 = blockIdx.y << 5;
  int tx = threadIdx.x, ty = threadIdx.y;
  #pragma unroll
  for (int r = 0; r < 32; r += 8)
    tile[ty + r][tx] = in[(size_t)(k0 + ty + r) * N + n0 + tx];
  __syncthreads();
  #pragma unroll
  for (int r = 0; r < 32; r += 8)
    out[(size_t)(n0 + ty + r) * K + k0 + tx] = f2bf(tile[tx][ty + r]);
}

__global__ void concat3(const float* __restrict__ a, const float* __restrict__ b,
                        const float* __restrict__ c, float* __restrict__ o){
  int i = blockIdx.x * 256 + threadIdx.x;
  o[i] = i < 1024 ? a[i] : (i < 2048 ? b[i - 1024] : c[i - 2048]);
}

// ---------------- layernorm: [rows][1024] (f32 or bf16 in) -> bf16 out
__device__ __forceinline__ float blockReduce(float v, float* ws){
  #pragma unroll
  for (int m = 1; m < 64; m <<= 1) v += __shfl_xor(v, m, 64);
  int w = threadIdx.x >> 6;
  __syncthreads();
  if ((threadIdx.x & 63) == 0) ws[w] = v;
  __syncthreads();
  return ws[0] + ws[1] + ws[2] + ws[3];
}

struct U16x4 { u16 x, y, z, w; };

template<int BF16IN>
__global__ __launch_bounds__(256) void ln_kernel(const void* __restrict__ in_, const float* __restrict__ g,
    const float* __restrict__ be, u16* __restrict__ out){
  __shared__ float ws[4];
  int row = blockIdx.x;
  float vx, vy, vz, vw;
  if constexpr (BF16IN) {
    const U16x4 v = ((const U16x4*)((const u16*)in_ + ((size_t)row << 10)))[threadIdx.x];
    vx = bf2f(v.x); vy = bf2f(v.y); vz = bf2f(v.z); vw = bf2f(v.w);
  } else {
    const float4 v = ((const float4*)((const float*)in_ + ((size_t)row << 10)))[threadIdx.x];
    vx = v.x; vy = v.y; vz = v.z; vw = v.w;
  }
  float s = vx + vy + vz + vw;
  s = blockReduce(s, ws);
  float mean = s * (1.f / 1024.f);
  float dx = vx - mean, dy = vy - mean, dz = vz - mean, dw = vw - mean;
  float s2 = dx*dx + dy*dy + dz*dz + dw*dw;
  s2 = blockReduce(s2, ws);
  float rstd = rsqrtf(s2 * (1.f / 1024.f) + 1e-5f);
  float4 gv = ((const float4*)g)[threadIdx.x];
  float4 bv = ((const float4*)be)[threadIdx.x];
  U16x4 ov;
  ov.x = f2bf(dx * rstd * gv.x + bv.x);
  ov.y = f2bf(dy * rstd * gv.y + bv.y);
  ov.z = f2bf(dz * rstd * gv.z + bv.z);
  ov.w = f2bf(dw * rstd * gv.w + bv.w);
  ((U16x4*)(out + ((size_t)row << 10)))[threadIdx.x] = ov;
}

// ================= 256x256 8-phase bf16 GEMM =========
template<int QM, int QN, int LB, int RDA, int WAIT, typename F>
__device__ __forceinline__ void ph256(const char* lds, const int (&aoff)[2], const int (&boff)[2],
    bf16x8 (&af)[4][2], bf16x8 (&bv)[2][2], f32x4 (&acc)[8][4], F&& stg){
  if constexpr (RDA) {
    const char* Ar = lds + LB*65536 + QM*16384;
    #pragma unroll
    for (int fi = 0; fi < 4; ++fi)
      #pragma unroll
      for (int ks = 0; ks < 2; ++ks)
        af[fi][ks] = *(const bf16x8*)(Ar + fi*2048 + aoff[ks]);
  }
  {
    const char* Br = lds + LB*65536 + 32768 + QN*16384;
    #pragma unroll
    for (int fj = 0; fj < 2; ++fj)
      #pragma unroll
      for (int ks = 0; ks < 2; ++ks)
        bv[fj][ks] = *(const bf16x8*)(Br + fj*2048 + boff[ks]);
  }
  stg();
  BAR();
  asm volatile("s_waitcnt lgkmcnt(0)" ::: "memory");
  __builtin_amdgcn_sched_barrier(0);
  __builtin_amdgcn_s_setprio(1);
  #pragma unroll
  for (int fi = 0; fi < 4; ++fi)
    #pragma unroll
    for (int fj = 0; fj < 2; ++fj){
      acc[QM*4+fi][QN*2+fj] = __builtin_amdgcn_mfma_f32_16x16x32_bf16(af[fi][0], bv[fj][0], acc[QM*4+fi][QN*2+fj], 0, 0, 0);
      acc[QM*4+fi][QN*2+fj] = __builtin_amdgcn_mfma_f32_16x16x32_bf16(af[fi][1], bv[fj][1], acc[QM*4+fi][QN*2+fj], 0, 0, 0);
    }
  __builtin_amdgcn_s_setprio(0);
  if constexpr (WAIT >= 0)
    asm volatile("s_waitcnt vmcnt(%0)" :: "n"(WAIT) : "memory");
  BAR();
}

// EPI 0: bf16 scatter to q/k/v [3][B*NH, S, HD] (+bias)
// EPI 2: bf16 = gelu(acc + bias)   [tanh-form sigmoid approx]
template<int EPI>
__global__ __launch_bounds__(512, 2) void gemm8(
    const u16* __restrict__ A, const u16* __restrict__ Bt,
    const float* __restrict__ bias, const float* __restrict__ add,
    void* __restrict__ out, int M, int N, int K)
{
  __shared__ char lds[147456];
  const int NT = K >> 6;
  const int NI = NT >> 1;
  const int nbx = N >> 8;
  const int nwg = gridDim.x, orig = blockIdx.x;
  const int q = nwg >> 3, r = nwg & 7, x = orig & 7;
  const int wg = (x < r ? x * (q + 1) : r * (q + 1) + (x - r) * q) + (orig >> 3);
  const int bx = wg % nbx, by = wg / nbx;
  const int m0 = by << 8, n0 = bx << 8;

  const int tid = threadIdx.x, wave = tid >> 6, lane = tid & 63;
  const int wr = (wave >> 2) & 1, wc = wave & 3;
  const int lcol = lane & 15, lrow4 = lane >> 4;

  int aoff[2], boff[2];
  #pragma unroll
  for (int ks = 0; ks < 2; ++ks){
    const int chunk = (ks*4 + lrow4) ^ (lane & 7);
    aoff[ks] = (wr*64 + lcol)*128 + chunk*16;
    boff[ks] = (wc*32 + lcol)*128 + chunk*16;
  }

  auto STAGE = [&](const u16* Mat, int rbase, int isB, int h, int tt){
    const int rb = (tt < NT) ? ((tt & 1) * 65536 + isB * 32768 + h * 16384) : 131072;
    const int tc = (tt < NT) ? tt : NT - 1;
    #pragma unroll
    for (int s = 0; s < 2; ++s){
      const int o = (tid + s*512) << 4;
      const int row = o >> 7;
      const int c = (o >> 4) & 7;
      const char* src = (const char*)(Mat + (size_t)(rbase + h*128 + row) * K + (size_t)tc * 64)
                        + ((c ^ (row & 7)) << 4);
      gload_lds16(src, (char*)lds + rb + o);
    }
  };

  f32x4 acc[8][4] = {};
  bf16x8 af[4][2], bv[2][2];

  STAGE(A,  m0, 0, 0, 0);
  STAGE(Bt, n0, 1, 0, 0);
  STAGE(A,  m0, 0, 1, 0);
  STAGE(Bt, n0, 1, 1, 0);
  STAGE(A,  m0, 0, 0, 1);
  STAGE(Bt, n0, 1, 1, 1);
  STAGE(A,  m0, 0, 1, 1);
  asm volatile("s_waitcnt vmcnt(6)" ::: "memory");
  BAR();

  for (int i = 0; i < NI; ++i) {
    const int T = 2*i;
    ph256<0, 0, 0, 1, -1>(lds, aoff, boff, af, bv, acc, [&]{ STAGE(Bt, n0, 1, 0, T+1); });
    ph256<0, 1, 0, 0, -1>(lds, aoff, boff, af, bv, acc, [&]{ STAGE(A,  m0, 0, 0, T+2); });
    ph256<1, 1, 0, 1, -1>(lds, aoff, boff, af, bv, acc, [&]{});
    ph256<1, 0, 0, 0,  4>(lds, aoff, boff, af, bv, acc, [&]{ STAGE(Bt, n0, 1, 1, T+2); });
    ph256<0, 0, 1, 1, -1>(lds, aoff, boff, af, bv, acc, [&]{ STAGE(Bt, n0, 1, 0, T+2); });
    ph256<0, 1, 1, 0, -1>(lds, aoff, boff, af, bv, acc, [&]{ STAGE(A,  m0, 0, 1, T+2); });
    ph256<1, 1, 1, 1, -1>(lds, aoff, boff, af, bv, acc, [&]{ STAGE(A,  m0, 0, 0, T+3); });
    ph256<1, 0, 1, 0,  6>(lds, aoff, boff, af, bv, acc, [&]{ STAGE(Bt, n0, 1, 1, T+3); STAGE(A, m0, 0, 1, T+3); });
  }

  { size_t bp = (size_t)bias, ap = (size_t)add;
    asm volatile("" : "+v"(bp), "+v"(ap));
    bias = (const float*)bp; add = (const float*)ap; }

  #pragma unroll
  for (int mi = 0; mi < 8; ++mi) {
    const int gmb = m0 + (mi>>2)*128 + wr*64 + (mi&3)*16 + lrow4*4;
    #pragma unroll
    for (int ni = 0; ni < 4; ++ni) {
      const int gn = n0 + (ni>>1)*128 + wc*32 + (ni&1)*16 + lcol;
      const float bs = bias[gn];
      #pragma unroll
      for (int rr = 0; rr < 4; ++rr) {
        const int gm = gmb + rr;
        float v = acc[mi][ni][rr] + bs;
        if constexpr (EPI == 0) {
          const int which = gn >> 10, g = gn & 1023;
          const int b = gm >> 11, s = gm & 2047;
          const int h = g >> 6, d = g & 63;
          ((u16*)out)[(size_t)which * 8388608 + ((((size_t)((b << 4) + h) << 11) + s) << 6) + d] = f2bf(v);
        } else {
          const float y2 = 1.5957691216f * v + 0.0713548353f * v * v * v;
          const float e = __expf(y2);
          ((u16*)out)[(size_t)gm * N + gn] = f2bf(v - v / (1.f + e));
        }
      }
    }
  }
}

// ================= 128x256 4-phase bf16 GEMM (wide) ====
// EPI 1: proj  -> out bf16 = acc + bias + add(f32)
// EPI 3: ffn2  -> out f32  = acc + bias + add(bf16)
template<int QN, int LB, int RDA, int WAIT, typename F>
__device__ __forceinline__ void phW(const char* lds, const int (&aoff)[2], const int (&boff)[2],
    bf16x8 (&af)[4][2], bf16x8 (&bv)[2][2], f32x4 (&acc)[4][4], F&& stg){
  if constexpr (RDA) {
    const char* Ar = lds + LB*49152;
    #pragma unroll
    for (int fi = 0; fi < 4; ++fi)
      #pragma unroll
      for (int ks = 0; ks < 2; ++ks)
        af[fi][ks] = *(const bf16x8*)(Ar + fi*2048 + aoff[ks]);
  }
  {
    const char* Br = lds + LB*49152 + 16384 + QN*16384;
    #pragma unroll
    for (int fj = 0; fj < 2; ++fj)
      #pragma unroll
      for (int ks = 0; ks < 2; ++ks)
        bv[fj][ks] = *(const bf16x8*)(Br + fj*2048 + boff[ks]);
  }
  stg();
  BAR();
  asm volatile("s_waitcnt lgkmcnt(0)" ::: "memory");
  __builtin_amdgcn_sched_barrier(0);
  __builtin_amdgcn_s_setprio(1);
  #pragma unroll
  for (int fi = 0; fi < 4; ++fi)
    #pragma unroll
    for (int fj = 0; fj < 2; ++fj){
      acc[fi][QN*2+fj] = __builtin_amdgcn_mfma_f32_16x16x32_bf16(af[fi][0], bv[fj][0], acc[fi][QN*2+fj], 0, 0, 0);
      acc[fi][QN*2+fj] = __builtin_amdgcn_mfma_f32_16x16x32_bf16(af[fi][1], bv[fj][1], acc[fi][QN*2+fj], 0, 0, 0);
    }
  __builtin_amdgcn_s_setprio(0);
  if constexpr (WAIT >= 0)
    asm volatile("s_waitcnt vmcnt(%0)" :: "n"(WAIT) : "memory");
  BAR();
}

template<int EPI>
__global__ __launch_bounds__(512, 2) void gemmW(
    const u16* __restrict__ A, const u16* __restrict__ Bt,
    const float* __restrict__ bias, const void* __restrict__ add,
    void* __restrict__ out, int M, int N, int K)
{
  __shared__ char lds[106496];
  const int NT = K >> 6;
  const int NI = NT >> 1;
  const int nbx = N >> 8;
  const int nwg = gridDim.x, orig = blockIdx.x;
  const int q = nwg >> 3, r = nwg & 7, x = orig & 7;
  const int wg = (x < r ? x * (q + 1) : r * (q + 1) + (x - r) * q) + (orig >> 3);
  const int bx = wg % nbx, by = wg / nbx;
  const int m0 = by << 7, n0 = bx << 8;

  const int tid = threadIdx.x, wave = tid >> 6, lane = tid & 63;
  const int wr = wave >> 2, wc = wave & 3;
  const int lcol = lane & 15, lrow4 = lane >> 4;

  int aoff[2], boff[2];
  #pragma unroll
  for (int ks = 0; ks < 2; ++ks){
    const int chunk = (ks*4 + lrow4) ^ (lane & 7);
    aoff[ks] = (wr*64 + lcol)*128 + chunk*16;
    boff[ks] = (wc*32 + lcol)*128 + chunk*16;
  }

  auto STAGE = [&](const u16* Mat, int rbase, int kind, int tt){
    const int rb = (tt < NT) ? ((tt & 1) * 49152 + kind * 16384) : 98304;
    const int tc = (tt < NT) ? tt : NT - 1;
    #pragma unroll
    for (int s = 0; s < 2; ++s){
      const int o = (tid + s*512) << 4;
      const int row = o >> 7;
      const int c = (o >> 4) & 7;
      const char* src = (const char*)(Mat + (size_t)(rbase + row) * K + (size_t)tc * 64)
                        + ((c ^ (row & 7)) << 4);
      gload_lds16(src, (char*)lds + rb + o);
    }
  };

  f32x4 acc[4][4] = {};
  bf16x8 af[4][2], bv[2][2];

  STAGE(A,  m0,       0, 0);
  STAGE(Bt, n0,       1, 0);
  STAGE(Bt, n0 + 128, 2, 0);
  STAGE(A,  m0,       0, 1);
  STAGE(Bt, n0,       1, 1);
  asm volatile("s_waitcnt vmcnt(4)" ::: "memory");
  BAR();

  for (int i = 0; i < NI; ++i) {
    const int T = 2*i;
    phW<0, 0, 1, -1>(lds, aoff, boff, af, bv, acc, [&]{ STAGE(Bt, n0 + 128, 2, T+1); });
    phW<1, 0, 0,  4>(lds, aoff, boff, af, bv, acc, [&]{ STAGE(A, m0, 0, T+2); STAGE(Bt, n0, 1, T+2); });
    phW<0, 1, 1, -1>(lds, aoff, boff, af, bv, acc, [&]{ STAGE(Bt, n0 + 128, 2, T+2); });
    phW<1, 1, 0,  4>(lds, aoff, boff, af, bv, acc, [&]{ STAGE(A, m0, 0, T+3); STAGE(Bt, n0, 1, T+3); });
  }

  { size_t bp = (size_t)bias, ap = (size_t)add;
    asm volatile("" : "+v"(bp), "+v"(ap));
    bias = (const float*)bp; add = (const void*)ap; }

  #pragma unroll
  for (int fi = 0; fi < 4; ++fi) {
    const int gmb = m0 + wr*64 + fi*16 + lrow4*4;
    #pragma unroll
    for (int j = 0; j < 4; ++j) {
      const int gn = n0 + (j>>1)*128 + wc*32 + (j&1)*16 + lcol;
      const float bs = bias[gn];
      #pragma unroll
      for (int rr = 0; rr < 4; ++rr) {
        const int gm = gmb + rr;
        float v = acc[fi][j][rr] + bs;
        if constexpr (EPI == 1) {
          ((u16*)out)[(size_t)gm * N + gn] = f2bf(v + ((const float*)add)[(size_t)gm * N + gn]);
        } else {
          ((float*)out)[(size_t)gm * N + gn] = v + bf2f(((const u16*)add)[(size_t)gm * N + gn]);
        }
      }
    }
  }
}

// ================= windowed attention: r12 structure + conflict-free V^T swizzle
template<int NJ>  // NJ = W/16 (24 or 32)
__device__ void attn_core(const u16* __restrict__ Qp, const u16* __restrict__ Kp,
    u16* __restrict__ ctxP, const char* vtb, int start, int widx, int bh)
{
  const int tid = threadIdx.x, wave = tid >> 6, lane = tid & 63;
  const int q = lane & 15, g = lane >> 4;
  constexpr int HALF = NJ / 2;
  const float scale = 0.125f;  // 64^-0.5
  const int b = bh >> 4, h = bh & 15;

  for (int qt = wave; qt < NJ; qt += 4) {
    const int q0 = qt * 16;
    const bf16x8 bq0 = *(const bf16x8*)(Qp + (q0 + q) * 64 + g * 8);
    const bf16x8 bq1 = *(const bf16x8*)(Qp + (q0 + q) * 64 + 32 + g * 8);
    float m = -3.0e38f, l = 0.f;
    f32x4 o[4] = {};
    const int s0 = ((g & 1) << 5) + q;
    const int s1 = s0 + 16;
    const bool lowj = (g < 2);

    #pragma unroll
    for (int hh = 0; hh < 2; ++hh) {
      f32x4 acc[HALF];
      #pragma unroll
      for (int j = 0; j < HALF; ++j) {
        const int jj = hh * HALF + j;
        bf16x8 k0 = *(const bf16x8*)(Kp + (jj*16 + q) * 64 + g * 8);
        bf16x8 k1 = *(const bf16x8*)(Kp + (jj*16 + q) * 64 + 32 + g * 8);
        f32x4 t = {};
        t = __builtin_amdgcn_mfma_f32_16x16x32_bf16(k0, bq0, t, 0, 0, 0);
        t = __builtin_amdgcn_mfma_f32_16x16x32_bf16(k1, bq1, t, 0, 0, 0);
        acc[j] = t;
        if ((j & 3) == 3) __builtin_amdgcn_sched_barrier(0);  // cap load hoisting
      }
      float mh = -3.0e38f;
      #pragma unroll
      for (int j = 0; j < HALF; ++j)
        #pragma unroll
        for (int r = 0; r < 4; ++r) mh = fmaxf(mh, acc[j][r]);
      mh = fmaxf(mh, __shfl_xor(mh, 16, 64));
      mh = fmaxf(mh, __shfl_xor(mh, 32, 64));
      const float mn = fmaxf(m, mh);
      const float fr = __expf((m - mn) * scale);
      m = mn;
      l *= fr;
      #pragma unroll
      for (int df = 0; df < 4; ++df)
        #pragma unroll
        for (int r = 0; r < 4; ++r) o[df][r] *= fr;
      #pragma unroll
      for (int j = 0; j < HALF; ++j)
        #pragma unroll
        for (int r = 0; r < 4; ++r) {
          float e = __expf((acc[j][r] - mn) * scale);
          acc[j][r] = e;
          l += e;
        }
      #pragma unroll
      for (int c = 0; c < HALF / 2; ++c) {
        const u32 a0 = pack2(acc[2*c][0],   acc[2*c][1]);
        const u32 b0 = pack2(acc[2*c][2],   acc[2*c][3]);
        const u32 a1 = pack2(acc[2*c+1][0], acc[2*c+1][1]);
        const u32 b1 = pack2(acc[2*c+1][2], acc[2*c+1][3]);
        const u32 A0l = __shfl(a0, s0, 64), A1l = __shfl(a1, s0, 64);
        const u32 B0l = __shfl(b0, s0, 64), B1l = __shfl(b1, s0, 64);
        const u32 A0h = __shfl(a0, s1, 64), A1h = __shfl(a1, s1, 64);
        const u32 B0h = __shfl(b0, s1, 64), B1h = __shfl(b1, s1, 64);
        union { u32 u[4]; bf16x8 v; } pf;
        pf.u[0] = lowj ? A0l : A1l;
        pf.u[1] = lowj ? B0l : B1l;
        pf.u[2] = lowj ? A0h : A1h;
        pf.u[3] = lowj ? B0h : B1h;
        const int cg = hh * (HALF / 2) + c;
        #pragma unroll
        for (int df = 0; df < 4; ++df) {
          bf16x8 pv = *(const bf16x8*)(vtb + swz(df*16 + q, (cg*32 + g*8) * 2));
          o[df] = __builtin_amdgcn_mfma_f32_16x16x32_bf16(pv, pf.v, o[df], 0, 0, 0);
        }
        if ((c & 1) == 1) __builtin_amdgcn_sched_barrier(0);
      }
    }
    l += __shfl_xor(l, 16, 64);
    l += __shfl_xor(l, 32, 64);
    const float rs = 1.f / l;

    const int p = start + q0 + q;
    const int rel = p - (widx * 256 - 128);
    const float wgt = (rel < 256) ? ((widx == 0) ? 1.f : (float)rel * (1.f / 255.f))
                                  : ((widx == 7) ? 1.f : (1.f - (float)(rel - 256) * (1.f / 255.f)));
    const float rw = rs * wgt;
    u32 w0[4], w1[4];
    #pragma unroll
    for (int df = 0; df < 4; ++df) {
      w0[df] = pack2(o[df][0] * rw, o[df][1] * rw);
      w1[df] = pack2(o[df][2] * rw, o[df][3] * rw);
    }
    u32 W8[8] = {};
    #pragma unroll
    for (int df = 0; df < 4; ++df)
      #pragma unroll
      for (int sg = 0; sg < 4; ++sg) {
        const u32 t0 = __shfl(w0[df], sg*16 + q, 64);
        const u32 t1 = __shfl(w1[df], sg*16 + q, 64);
        if (g == df) { W8[2*sg] = t0; W8[2*sg+1] = t1; }
      }
    u16* dst = ctxP + ((((size_t)(b << 11) + (size_t)p) << 10) + (h << 6) + (g << 4));
    u32x4 lo = { W8[0], W8[1], W8[2], W8[3] };
    u32x4 hi = { W8[4], W8[5], W8[6], W8[7] };
    *(u32x4*)dst = lo;
    *(u32x4*)(dst + 8) = hi;
  }
}

__global__ __launch_bounds__(256, 1) void attn_kernel(const u16* __restrict__ qg, const u16* __restrict__ kg,
    const u16* __restrict__ vg, u16* __restrict__ ctxE, u16* __restrict__ ctxO){
  __shared__ u16 Vt[32768];   // V^T only: 64KB -> 2 blocks/CU
  const int widx = (int)blockIdx.x >> 6;
  const int bh = blockIdx.x & 63;
  const int i0 = widx << 8;
  int start = i0 - 128; if (start < 0) start = 0;
  int end = i0 + 384;   if (end > 2048) end = 2048;
  const int W = end - start;
  const int tid = threadIdx.x;
  const u16* Qp = qg + (((size_t)bh << 11) + start) * 64;
  const u16* Kp = kg + (((size_t)bh << 11) + start) * 64;
  const u16* Vp = vg + (((size_t)bh << 11) + start) * 64;
  char* vtb = (char*)Vt;
  // stage V^T: idx -> key = idx % W (64 lanes span 64 keys -> write banks spread),
  // dchunk = idx / W. Write byte = key*2 ^ ((row&15)<<6) matches PV-read swizzle.
  for (int idx = tid; idx < W * 8; idx += 256) {
    const int key = idx % W, d0 = (idx / W) << 3;
    u16x8 vv = *(const u16x8*)(Vp + key * 64 + d0);
    #pragma unroll
    for (int z = 0; z < 8; ++z)
      *(u16*)(vtb + swz(d0 + z, key * 2)) = vv[z];
  }
  __syncthreads();
  u16* ctxP = (widx & 1) ? ctxO : ctxE;
  if (W == 512) attn_core<32>(Qp, Kp, ctxP, vtb, start, widx, bh);
  else          attn_core<24>(Qp, Kp, ctxP, vtb, start, widx, bh);
}

// merge parity buffers: p<128 -> E; p>=1920 -> O; else E+O. In-place on E is safe.
__global__ __launch_bounds__(256) void merge_kernel(const u16* __restrict__ e,
    const u16* __restrict__ o, u16* __restrict__ out){
  const int i = blockIdx.x * 256 + threadIdx.x;     // u16x8 index
  const int p = (i >> 7) & 2047;                    // (i*8 >> 10) & 2047
  u16x8 ev = ((const u16x8*)e)[i];
  u16x8 ov = ((const u16x8*)o)[i];
  u16x8 r;
  if (p < 128)        r = ev;
  else if (p >= 1920) r = ov;
  else {
    #pragma unroll
    for (int z = 0; z < 8; ++z) r[z] = f2bf(bf2f(ev[z]) + bf2f(ov[z]));
  }
  ((u16x8*)out)[i] = r;
}

// ---------------- host
extern "C" void kernel_launch(void* const* d_in, const int* in_sizes, int n_in,
                              void* d_out, int out_size, void* d_ws, size_t ws_size,
                              hipStream_t stream) {
  const float* hidden = (const float*)d_in[0];
  const float* ln1_g  = (const float*)d_in[1];
  const float* ln1_b  = (const float*)d_in[2];
  const float* wq     = (const float*)d_in[3];
  const float* bq     = (const float*)d_in[4];
  const float* wk     = (const float*)d_in[5];
  const float* bk     = (const float*)d_in[6];
  const float* wv     = (const float*)d_in[7];
  const float* bv     = (const float*)d_in[8];
  const float* wproj  = (const float*)d_in[9];
  const float* bproj  = (const float*)d_in[10];
  const float* ln2_g  = (const float*)d_in[11];
  const float* ln2_b  = (const float*)d_in[12];
  const float* w1     = (const float*)d_in[13];
  const float* b1     = (const float*)d_in[14];
  const float* w2     = (const float*)d_in[15];
  const float* b2     = (const float*)d_in[16];

  char* ws = (char*)d_ws;
  u16* xb    = (u16*)(ws + 0);            // 16 MiB (LN1/LN2 out; ctxO during attn)
  u16* wqkvT = (u16*)(ws + 16777216);     // 6 MiB [3072][1024]
  u16* wpT   = (u16*)(ws + 23068672);     // 2 MiB
  u16* w1T   = (u16*)(ws + 25165824);     // 8 MiB
  u16* w2T   = (u16*)(ws + 33554432);     // 8 MiB
  u16* qb    = (u16*)(ws + 41943040);     // q,k,v contiguous: 3 x 16 MiB
  u16* kb    = (u16*)(ws + 58720256);
  u16* vb    = (u16*)(ws + 75497472);
  u16* ctxE  = (u16*)(ws + 92274688);     // 16 MiB (merged ctx in-place)
  u16* ctxO  = (u16*)(ws + 0);            // aliases xb (dead between qkv and ln2)
  float* bqkv = (float*)(ws + 92274688);  // aliases ctxE start (dead before attn)
  u16* res2  = (u16*)(ws + 109051904);    // 16 MiB bf16
  u16* mid   = (u16*)(ws + 41943040);     // 64 MiB, reuses qb..ctx

  dim3 tb(32, 8);
  transpose_cvt<<<dim3(32, 32), tb, 0, stream>>>(wq, wqkvT, 1024, 1024);
  transpose_cvt<<<dim3(32, 32), tb, 0, stream>>>(wk, wqkvT + 1048576, 1024, 1024);
  transpose_cvt<<<dim3(32, 32), tb, 0, stream>>>(wv, wqkvT + 2097152, 1024, 1024);
  transpose_cvt<<<dim3(32, 32), tb, 0, stream>>>(wproj, wpT, 1024, 1024);
  transpose_cvt<<<dim3(128, 32), tb, 0, stream>>>(w1, w1T, 1024, 4096);
  transpose_cvt<<<dim3(32, 128), tb, 0, stream>>>(w2, w2T, 4096, 1024);
  concat3<<<12, 256, 0, stream>>>(bq, bk, bv, bqkv);

  ln_kernel<0><<<8192, 256, 0, stream>>>(hidden, ln1_g, ln1_b, xb);

  gemm8<0><<<384, 512, 0, stream>>>(xb, wqkvT, bqkv, nullptr, qb, 8192, 3072, 1024);

  attn_kernel<<<512, 256, 0, stream>>>(qb, kb, vb, ctxE, ctxO);
  merge_kernel<<<4096, 256, 0, stream>>>(ctxE, ctxO, ctxE);

  gemmW<1><<<256, 512, 0, stream>>>(ctxE, wpT, bproj, hidden, res2, 8192, 1024, 1024);

  ln_kernel<1><<<8192, 256, 0, stream>>>(res2, ln2_g, ln2_b, xb);

  gemm8<2><<<512, 512, 0, stream>>>(xb, w1T, b1, nullptr, mid, 8192, 4096, 1024);
  gemmW<3><<<256, 512, 0, stream>>>(mid, w2T, b2, res2, (float*)d_out, 8192, 1024, 4096);
}

// Round 18
// 411.503 us; speedup vs baseline: 1.0365x; 1.0365x over previous
//
#include <hip/hip_runtime.h>
#include <math.h>

typedef unsigned short u16;
typedef unsigned int u32;
typedef __attribute__((ext_vector_type(8))) short bf16x8;
typedef __attribute__((ext_vector_type(8))) unsigned short u16x8;
typedef __attribute__((ext_vector_type(4))) float f32x4;
typedef __attribute__((ext_vector_type(4))) unsigned int u32x4;

__device__ __forceinline__ u16 f2bf(float f){
  union { float f; unsigned u; } c; c.f = f;
  unsigned u = c.u;
  return (u16)((u + 0x7fffu + ((u >> 16) & 1u)) >> 16);
}
__device__ __forceinline__ float bf2f(u16 h){
  union { unsigned u; float f; } c; c.u = ((unsigned)h) << 16;
  return c.f;
}
__device__ __forceinline__ u32 pack2(float lo, float hi){
  return (u32)f2bf(lo) | ((u32)f2bf(hi) << 16);
}
__device__ __forceinline__ void gload_lds16(const void* g, void* l){
  __builtin_amdgcn_global_load_lds((const __attribute__((address_space(1))) void*)g,
                                   (__attribute__((address_space(3))) void*)l, 16, 0, 0);
}
// attention V^T swizzle (r17): XOR row bits into chunk bits (byte bits 6-9).
__device__ __forceinline__ int swz(int row, int bc){
  return (row << 10) + (bc ^ ((row & 15) << 6));
}

#define BAR() asm volatile("s_barrier" ::: "memory")

// ---------------- weight transpose + f32->bf16 : in [K][N] f32 -> out [N][K] bf16
__global__ void transpose_cvt(const float* __restrict__ in, u16* __restrict__ out, int K, int N){
  __shared__ float tile[32][33];
  int n0 = blockIdx.x << 5, k0 = blockIdx.y << 5;
  int tx = threadIdx.x, ty = threadIdx.y;
  #pragma unroll
  for (int r = 0; r < 32; r += 8)
    tile[ty + r][tx] = in[(size_t)(k0 + ty + r) * N + n0 + tx];
  __syncthreads();
  #pragma unroll
  for (int r = 0; r < 32; r += 8)
    out[(size_t)(n0 + ty + r) * K + k0 + tx] = f2bf(tile[tx][ty + r]);
}

__global__ void concat3(const float* __restrict__ a, const float* __restrict__ b,
                        const float* __restrict__ c, float* __restrict__ o){
  int i = blockIdx.x * 256 + threadIdx.x;
  o[i] = i < 1024 ? a[i] : (i < 2048 ? b[i - 1024] : c[i - 2048]);
}

// ---------------- layernorm: [rows][1024] (f32 or bf16 in) -> bf16 out
__device__ __forceinline__ float blockReduce(float v, float* ws){
  #pragma unroll
  for (int m = 1; m < 64; m <<= 1) v += __shfl_xor(v, m, 64);
  int w = threadIdx.x >> 6;
  __syncthreads();
  if ((threadIdx.x & 63) == 0) ws[w] = v;
  __syncthreads();
  return ws[0] + ws[1] + ws[2] + ws[3];
}

struct U16x4 { u16 x, y, z, w; };

template<int BF16IN>
__global__ __launch_bounds__(256) void ln_kernel(const void* __restrict__ in_, const float* __restrict__ g,
    const float* __restrict__ be, u16* __restrict__ out){
  __shared__ float ws[4];
  int row = blockIdx.x;
  float vx, vy, vz, vw;
  if constexpr (BF16IN) {
    const U16x4 v = ((const U16x4*)((const u16*)in_ + ((size_t)row << 10)))[threadIdx.x];
    vx = bf2f(v.x); vy = bf2f(v.y); vz = bf2f(v.z); vw = bf2f(v.w);
  } else {
    const float4 v = ((const float4*)((const float*)in_ + ((size_t)row << 10)))[threadIdx.x];
    vx = v.x; vy = v.y; vz = v.z; vw = v.w;
  }
  float s = vx + vy + vz + vw;
  s = blockReduce(s, ws);
  float mean = s * (1.f / 1024.f);
  float dx = vx - mean, dy = vy - mean, dz = vz - mean, dw = vw - mean;
  float s2 = dx*dx + dy*dy + dz*dz + dw*dw;
  s2 = blockReduce(s2, ws);
  float rstd = rsqrtf(s2 * (1.f / 1024.f) + 1e-5f);
  float4 gv = ((const float4*)g)[threadIdx.x];
  float4 bv = ((const float4*)be)[threadIdx.x];
  U16x4 ov;
  ov.x = f2bf(dx * rstd * gv.x + bv.x);
  ov.y = f2bf(dy * rstd * gv.y + bv.y);
  ov.z = f2bf(dz * rstd * gv.z + bv.z);
  ov.w = f2bf(dw * rstd * gv.w + bv.w);
  ((U16x4*)(out + ((size_t)row << 10)))[threadIdx.x] = ov;
}

// ================= 256x256 8-phase bf16 GEMM =========
template<int QM, int QN, int LB, int RDA, int WAIT, typename F>
__device__ __forceinline__ void ph256(const char* lds, const int (&aoff)[2], const int (&boff)[2],
    bf16x8 (&af)[4][2], bf16x8 (&bv)[2][2], f32x4 (&acc)[8][4], F&& stg){
  if constexpr (RDA) {
    const char* Ar = lds + LB*65536 + QM*16384;
    #pragma unroll
    for (int fi = 0; fi < 4; ++fi)
      #pragma unroll
      for (int ks = 0; ks < 2; ++ks)
        af[fi][ks] = *(const bf16x8*)(Ar + fi*2048 + aoff[ks]);
  }
  {
    const char* Br = lds + LB*65536 + 32768 + QN*16384;
    #pragma unroll
    for (int fj = 0; fj < 2; ++fj)
      #pragma unroll
      for (int ks = 0; ks < 2; ++ks)
        bv[fj][ks] = *(const bf16x8*)(Br + fj*2048 + boff[ks]);
  }
  stg();
  BAR();
  asm volatile("s_waitcnt lgkmcnt(0)" ::: "memory");
  __builtin_amdgcn_sched_barrier(0);
  __builtin_amdgcn_s_setprio(1);
  #pragma unroll
  for (int fi = 0; fi < 4; ++fi)
    #pragma unroll
    for (int fj = 0; fj < 2; ++fj){
      acc[QM*4+fi][QN*2+fj] = __builtin_amdgcn_mfma_f32_16x16x32_bf16(af[fi][0], bv[fj][0], acc[QM*4+fi][QN*2+fj], 0, 0, 0);
      acc[QM*4+fi][QN*2+fj] = __builtin_amdgcn_mfma_f32_16x16x32_bf16(af[fi][1], bv[fj][1], acc[QM*4+fi][QN*2+fj], 0, 0, 0);
    }
  __builtin_amdgcn_s_setprio(0);
  if constexpr (WAIT >= 0)
    asm volatile("s_waitcnt vmcnt(%0)" :: "n"(WAIT) : "memory");
  BAR();
}

// EPI 0: bf16 scatter to q/k/v [3][B*NH, S, HD] (+bias)
// EPI 2: bf16 = gelu(acc + bias)   [tanh-form sigmoid approx]
template<int EPI>
__global__ __launch_bounds__(512, 2) void gemm8(
    const u16* __restrict__ A, const u16* __restrict__ Bt,
    const float* __restrict__ bias, const float* __restrict__ add,
    void* __restrict__ out, int M, int N, int K)
{
  __shared__ char lds[147456];
  const int NT = K >> 6;
  const int NI = NT >> 1;
  const int nbx = N >> 8;
  const int nwg = gridDim.x, orig = blockIdx.x;
  const int q = nwg >> 3, r = nwg & 7, x = orig & 7;
  const int wg = (x < r ? x * (q + 1) : r * (q + 1) + (x - r) * q) + (orig >> 3);
  const int bx = wg % nbx, by = wg / nbx;
  const int m0 = by << 8, n0 = bx << 8;

  const int tid = threadIdx.x, wave = tid >> 6, lane = tid & 63;
  const int wr = (wave >> 2) & 1, wc = wave & 3;
  const int lcol = lane & 15, lrow4 = lane >> 4;

  int aoff[2], boff[2];
  #pragma unroll
  for (int ks = 0; ks < 2; ++ks){
    const int chunk = (ks*4 + lrow4) ^ (lane & 7);
    aoff[ks] = (wr*64 + lcol)*128 + chunk*16;
    boff[ks] = (wc*32 + lcol)*128 + chunk*16;
  }

  auto STAGE = [&](const u16* Mat, int rbase, int isB, int h, int tt){
    const int rb = (tt < NT) ? ((tt & 1) * 65536 + isB * 32768 + h * 16384) : 131072;
    const int tc = (tt < NT) ? tt : NT - 1;
    #pragma unroll
    for (int s = 0; s < 2; ++s){
      const int o = (tid + s*512) << 4;
      const int row = o >> 7;
      const int c = (o >> 4) & 7;
      const char* src = (const char*)(Mat + (size_t)(rbase + h*128 + row) * K + (size_t)tc * 64)
                        + ((c ^ (row & 7)) << 4);
      gload_lds16(src, (char*)lds + rb + o);
    }
  };

  f32x4 acc[8][4] = {};
  bf16x8 af[4][2], bv[2][2];

  STAGE(A,  m0, 0, 0, 0);
  STAGE(Bt, n0, 1, 0, 0);
  STAGE(A,  m0, 0, 1, 0);
  STAGE(Bt, n0, 1, 1, 0);
  STAGE(A,  m0, 0, 0, 1);
  STAGE(Bt, n0, 1, 1, 1);
  STAGE(A,  m0, 0, 1, 1);
  asm volatile("s_waitcnt vmcnt(6)" ::: "memory");
  BAR();

  for (int i = 0; i < NI; ++i) {
    const int T = 2*i;
    ph256<0, 0, 0, 1, -1>(lds, aoff, boff, af, bv, acc, [&]{ STAGE(Bt, n0, 1, 0, T+1); });
    ph256<0, 1, 0, 0, -1>(lds, aoff, boff, af, bv, acc, [&]{ STAGE(A,  m0, 0, 0, T+2); });
    ph256<1, 1, 0, 1, -1>(lds, aoff, boff, af, bv, acc, [&]{});
    ph256<1, 0, 0, 0,  4>(lds, aoff, boff, af, bv, acc, [&]{ STAGE(Bt, n0, 1, 1, T+2); });
    ph256<0, 0, 1, 1, -1>(lds, aoff, boff, af, bv, acc, [&]{ STAGE(Bt, n0, 1, 0, T+2); });
    ph256<0, 1, 1, 0, -1>(lds, aoff, boff, af, bv, acc, [&]{ STAGE(A,  m0, 0, 1, T+2); });
    ph256<1, 1, 1, 1, -1>(lds, aoff, boff, af, bv, acc, [&]{ STAGE(A,  m0, 0, 0, T+3); });
    ph256<1, 0, 1, 0,  6>(lds, aoff, boff, af, bv, acc, [&]{ STAGE(Bt, n0, 1, 1, T+3); STAGE(A, m0, 0, 1, T+3); });
  }

  { size_t bp = (size_t)bias, ap = (size_t)add;
    asm volatile("" : "+v"(bp), "+v"(ap));
    bias = (const float*)bp; add = (const float*)ap; }

  #pragma unroll
  for (int mi = 0; mi < 8; ++mi) {
    const int gmb = m0 + (mi>>2)*128 + wr*64 + (mi&3)*16 + lrow4*4;
    #pragma unroll
    for (int ni = 0; ni < 4; ++ni) {
      const int gn = n0 + (ni>>1)*128 + wc*32 + (ni&1)*16 + lcol;
      const float bs = bias[gn];
      #pragma unroll
      for (int rr = 0; rr < 4; ++rr) {
        const int gm = gmb + rr;
        float v = acc[mi][ni][rr] + bs;
        if constexpr (EPI == 0) {
          const int which = gn >> 10, g = gn & 1023;
          const int b = gm >> 11, s = gm & 2047;
          const int h = g >> 6, d = g & 63;
          ((u16*)out)[(size_t)which * 8388608 + ((((size_t)((b << 4) + h) << 11) + s) << 6) + d] = f2bf(v);
        } else {
          const float y2 = 1.5957691216f * v + 0.0713548353f * v * v * v;
          const float e = __expf(y2);
          ((u16*)out)[(size_t)gm * N + gn] = f2bf(v - v / (1.f + e));
        }
      }
    }
  }
}

// ================= 128x256 4-phase bf16 GEMM (wide) ====
// EPI 1: proj  -> out bf16 = acc + bias + add(f32)
// EPI 3: ffn2  -> out f32  = acc + bias + add(bf16)
template<int QN, int LB, int RDA, int WAIT, typename F>
__device__ __forceinline__ void phW(const char* lds, const int (&aoff)[2], const int (&boff)[2],
    bf16x8 (&af)[4][2], bf16x8 (&bv)[2][2], f32x4 (&acc)[4][4], F&& stg){
  if constexpr (RDA) {
    const char* Ar = lds + LB*49152;
    #pragma unroll
    for (int fi = 0; fi < 4; ++fi)
      #pragma unroll
      for (int ks = 0; ks < 2; ++ks)
        af[fi][ks] = *(const bf16x8*)(Ar + fi*2048 + aoff[ks]);
  }
  {
    const char* Br = lds + LB*49152 + 16384 + QN*16384;
    #pragma unroll
    for (int fj = 0; fj < 2; ++fj)
      #pragma unroll
      for (int ks = 0; ks < 2; ++ks)
        bv[fj][ks] = *(const bf16x8*)(Br + fj*2048 + boff[ks]);
  }
  stg();
  BAR();
  asm volatile("s_waitcnt lgkmcnt(0)" ::: "memory");
  __builtin_amdgcn_sched_barrier(0);
  __builtin_amdgcn_s_setprio(1);
  #pragma unroll
  for (int fi = 0; fi < 4; ++fi)
    #pragma unroll
    for (int fj = 0; fj < 2; ++fj){
      acc[fi][QN*2+fj] = __builtin_amdgcn_mfma_f32_16x16x32_bf16(af[fi][0], bv[fj][0], acc[fi][QN*2+fj], 0, 0, 0);
      acc[fi][QN*2+fj] = __builtin_amdgcn_mfma_f32_16x16x32_bf16(af[fi][1], bv[fj][1], acc[fi][QN*2+fj], 0, 0, 0);
    }
  __builtin_amdgcn_s_setprio(0);
  if constexpr (WAIT >= 0)
    asm volatile("s_waitcnt vmcnt(%0)" :: "n"(WAIT) : "memory");
  BAR();
}

template<int EPI>
__global__ __launch_bounds__(512, 2) void gemmW(
    const u16* __restrict__ A, const u16* __restrict__ Bt,
    const float* __restrict__ bias, const void* __restrict__ add,
    void* __restrict__ out, int M, int N, int K)
{
  __shared__ char lds[106496];
  const int NT = K >> 6;
  const int NI = NT >> 1;
  const int nbx = N >> 8;
  const int nwg = gridDim.x, orig = blockIdx.x;
  const int q = nwg >> 3, r = nwg & 7, x = orig & 7;
  const int wg = (x < r ? x * (q + 1) : r * (q + 1) + (x - r) * q) + (orig >> 3);
  const int bx = wg % nbx, by = wg / nbx;
  const int m0 = by << 7, n0 = bx << 8;

  const int tid = threadIdx.x, wave = tid >> 6, lane = tid & 63;
  const int wr = wave >> 2, wc = wave & 3;
  const int lcol = lane & 15, lrow4 = lane >> 4;

  int aoff[2], boff[2];
  #pragma unroll
  for (int ks = 0; ks < 2; ++ks){
    const int chunk = (ks*4 + lrow4) ^ (lane & 7);
    aoff[ks] = (wr*64 + lcol)*128 + chunk*16;
    boff[ks] = (wc*32 + lcol)*128 + chunk*16;
  }

  auto STAGE = [&](const u16* Mat, int rbase, int kind, int tt){
    const int rb = (tt < NT) ? ((tt & 1) * 49152 + kind * 16384) : 98304;
    const int tc = (tt < NT) ? tt : NT - 1;
    #pragma unroll
    for (int s = 0; s < 2; ++s){
      const int o = (tid + s*512) << 4;
      const int row = o >> 7;
      const int c = (o >> 4) & 7;
      const char* src = (const char*)(Mat + (size_t)(rbase + row) * K + (size_t)tc * 64)
                        + ((c ^ (row & 7)) << 4);
      gload_lds16(src, (char*)lds + rb + o);
    }
  };

  f32x4 acc[4][4] = {};
  bf16x8 af[4][2], bv[2][2];

  STAGE(A,  m0,       0, 0);
  STAGE(Bt, n0,       1, 0);
  STAGE(Bt, n0 + 128, 2, 0);
  STAGE(A,  m0,       0, 1);
  STAGE(Bt, n0,       1, 1);
  asm volatile("s_waitcnt vmcnt(4)" ::: "memory");
  BAR();

  for (int i = 0; i < NI; ++i) {
    const int T = 2*i;
    phW<0, 0, 1, -1>(lds, aoff, boff, af, bv, acc, [&]{ STAGE(Bt, n0 + 128, 2, T+1); });
    phW<1, 0, 0,  4>(lds, aoff, boff, af, bv, acc, [&]{ STAGE(A, m0, 0, T+2); STAGE(Bt, n0, 1, T+2); });
    phW<0, 1, 1, -1>(lds, aoff, boff, af, bv, acc, [&]{ STAGE(Bt, n0 + 128, 2, T+2); });
    phW<1, 1, 0,  4>(lds, aoff, boff, af, bv, acc, [&]{ STAGE(A, m0, 0, T+3); STAGE(Bt, n0, 1, T+3); });
  }

  { size_t bp = (size_t)bias, ap = (size_t)add;
    asm volatile("" : "+v"(bp), "+v"(ap));
    bias = (const float*)bp; add = (const void*)ap; }

  #pragma unroll
  for (int fi = 0; fi < 4; ++fi) {
    const int gmb = m0 + wr*64 + fi*16 + lrow4*4;
    #pragma unroll
    for (int j = 0; j < 4; ++j) {
      const int gn = n0 + (j>>1)*128 + wc*32 + (j&1)*16 + lcol;
      const float bs = bias[gn];
      #pragma unroll
      for (int rr = 0; rr < 4; ++rr) {
        const int gm = gmb + rr;
        float v = acc[fi][j][rr] + bs;
        if constexpr (EPI == 1) {
          ((u16*)out)[(size_t)gm * N + gn] = f2bf(v + ((const float*)add)[(size_t)gm * N + gn]);
        } else {
          ((float*)out)[(size_t)gm * N + gn] = v + bf2f(((const u16*)add)[(size_t)gm * N + gn]);
        }
      }
    }
  }
}

// ================= windowed attention: half-split online softmax + K in LDS ==
// 512 blocks x 256 thr, (256,1). LDS: K [W][128B] swizzled (64KB, staged via
// gload_lds16 with pre-swizzled source, r10-proven) + V^T (64KB, r17 swizzle)
// = 128KB -> 1 block/CU. K read from LDS (~70cyc) instead of global L2 (~300+)
// eliminates the dominant per-iter latency exposure; each wave no longer
// re-reads K from global per qt-iter.
template<int NJ>  // NJ = W/16 (24 or 32)
__device__ void attn_core(const u16* __restrict__ Qp, u16* __restrict__ ctxP,
    const char* ktb, const char* vtb, int start, int widx, int bh)
{
  const int tid = threadIdx.x, wave = tid >> 6, lane = tid & 63;
  const int q = lane & 15, g = lane >> 4;
  constexpr int HALF = NJ / 2;
  const float scale = 0.125f;  // 64^-0.5
  const int b = bh >> 4, h = bh & 15;
  const int sw0 = ((g ^ (q & 7)) << 4);
  const int sw1 = (((4 | g) ^ (q & 7)) << 4);

  for (int qt = wave; qt < NJ; qt += 4) {
    const int q0 = qt * 16;
    const bf16x8 bq0 = *(const bf16x8*)(Qp + (q0 + q) * 64 + g * 8);
    const bf16x8 bq1 = *(const bf16x8*)(Qp + (q0 + q) * 64 + 32 + g * 8);
    float m = -3.0e38f, l = 0.f;
    f32x4 o[4] = {};
    const int s0 = ((g & 1) << 5) + q;
    const int s1 = s0 + 16;
    const bool lowj = (g < 2);

    #pragma unroll
    for (int hh = 0; hh < 2; ++hh) {
      f32x4 acc[HALF];
      #pragma unroll
      for (int j = 0; j < HALF; ++j) {
        const int jj = hh * HALF + j;
        const char* kr = ktb + (jj*16 + q) * 128;
        bf16x8 k0 = *(const bf16x8*)(kr + sw0);
        bf16x8 k1 = *(const bf16x8*)(kr + sw1);
        f32x4 t = {};
        t = __builtin_amdgcn_mfma_f32_16x16x32_bf16(k0, bq0, t, 0, 0, 0);
        t = __builtin_amdgcn_mfma_f32_16x16x32_bf16(k1, bq1, t, 0, 0, 0);
        acc[j] = t;
        if ((j & 3) == 3) __builtin_amdgcn_sched_barrier(0);  // cap read hoisting
      }
      float mh = -3.0e38f;
      #pragma unroll
      for (int j = 0; j < HALF; ++j)
        #pragma unroll
        for (int r = 0; r < 4; ++r) mh = fmaxf(mh, acc[j][r]);
      mh = fmaxf(mh, __shfl_xor(mh, 16, 64));
      mh = fmaxf(mh, __shfl_xor(mh, 32, 64));
      const float mn = fmaxf(m, mh);
      const float fr = __expf((m - mn) * scale);
      m = mn;
      l *= fr;
      #pragma unroll
      for (int df = 0; df < 4; ++df)
        #pragma unroll
        for (int r = 0; r < 4; ++r) o[df][r] *= fr;
      #pragma unroll
      for (int j = 0; j < HALF; ++j)
        #pragma unroll
        for (int r = 0; r < 4; ++r) {
          float e = __expf((acc[j][r] - mn) * scale);
          acc[j][r] = e;
          l += e;
        }
      #pragma unroll
      for (int c = 0; c < HALF / 2; ++c) {
        const u32 a0 = pack2(acc[2*c][0],   acc[2*c][1]);
        const u32 b0 = pack2(acc[2*c][2],   acc[2*c][3]);
        const u32 a1 = pack2(acc[2*c+1][0], acc[2*c+1][1]);
        const u32 b1 = pack2(acc[2*c+1][2], acc[2*c+1][3]);
        const u32 A0l = __shfl(a0, s0, 64), A1l = __shfl(a1, s0, 64);
        const u32 B0l = __shfl(b0, s0, 64), B1l = __shfl(b1, s0, 64);
        const u32 A0h = __shfl(a0, s1, 64), A1h = __shfl(a1, s1, 64);
        const u32 B0h = __shfl(b0, s1, 64), B1h = __shfl(b1, s1, 64);
        union { u32 u[4]; bf16x8 v; } pf;
        pf.u[0] = lowj ? A0l : A1l;
        pf.u[1] = lowj ? B0l : B1l;
        pf.u[2] = lowj ? A0h : A1h;
        pf.u[3] = lowj ? B0h : B1h;
        const int cg = hh * (HALF / 2) + c;
        #pragma unroll
        for (int df = 0; df < 4; ++df) {
          bf16x8 pv = *(const bf16x8*)(vtb + swz(df*16 + q, (cg*32 + g*8) * 2));
          o[df] = __builtin_amdgcn_mfma_f32_16x16x32_bf16(pv, pf.v, o[df], 0, 0, 0);
        }
        if ((c & 1) == 1) __builtin_amdgcn_sched_barrier(0);
      }
    }
    l += __shfl_xor(l, 16, 64);
    l += __shfl_xor(l, 32, 64);
    const float rs = 1.f / l;

    const int p = start + q0 + q;
    const int rel = p - (widx * 256 - 128);
    const float wgt = (rel < 256) ? ((widx == 0) ? 1.f : (float)rel * (1.f / 255.f))
                                  : ((widx == 7) ? 1.f : (1.f - (float)(rel - 256) * (1.f / 255.f)));
    const float rw = rs * wgt;
    u32 w0[4], w1[4];
    #pragma unroll
    for (int df = 0; df < 4; ++df) {
      w0[df] = pack2(o[df][0] * rw, o[df][1] * rw);
      w1[df] = pack2(o[df][2] * rw, o[df][3] * rw);
    }
    u32 W8[8] = {};
    #pragma unroll
    for (int df = 0; df < 4; ++df)
      #pragma unroll
      for (int sg = 0; sg < 4; ++sg) {
        const u32 t0 = __shfl(w0[df], sg*16 + q, 64);
        const u32 t1 = __shfl(w1[df], sg*16 + q, 64);
        if (g == df) { W8[2*sg] = t0; W8[2*sg+1] = t1; }
      }
    u16* dst = ctxP + ((((size_t)(b << 11) + (size_t)p) << 10) + (h << 6) + (g << 4));
    u32x4 lo = { W8[0], W8[1], W8[2], W8[3] };
    u32x4 hi = { W8[4], W8[5], W8[6], W8[7] };
    *(u32x4*)dst = lo;
    *(u32x4*)(dst + 8) = hi;
  }
}

__global__ __launch_bounds__(256, 1) void attn_kernel(const u16* __restrict__ qg, const u16* __restrict__ kg,
    const u16* __restrict__ vg, u16* __restrict__ ctxE, u16* __restrict__ ctxO){
  __shared__ char lds[131072];   // K @0 (64KB), V^T @65536 (64KB) -> 1 block/CU
  const int widx = (int)blockIdx.x >> 6;
  const int bh = blockIdx.x & 63;
  const int i0 = widx << 8;
  int start = i0 - 128; if (start < 0) start = 0;
  int end = i0 + 384;   if (end > 2048) end = 2048;
  const int W = end - start;
  const int tid = threadIdx.x;
  const u16* Qp = qg + (((size_t)bh << 11) + start) * 64;
  const u16* Kp = kg + (((size_t)bh << 11) + start) * 64;
  const u16* Vp = vg + (((size_t)bh << 11) + start) * 64;
  // stage K: rows of 128B; LDS chunk c holds global chunk c ^ (row&7) (rule #21)
  const int nks = W >> 5;             // W*8 16B-chunks / 256 threads
  for (int s = 0; s < nks; ++s) {
    const int o = (tid + s*256) << 4;
    const int row = o >> 7, c = (o >> 4) & 7;
    const char* src = (const char*)(Kp + (size_t)row * 64) + ((c ^ (row & 7)) << 4);
    gload_lds16(src, (char*)lds + o);
  }
  // stage V^T (scalar transpose; r17 swizzle; key = idx%W spreads write banks)
  char* vtb = (char*)lds + 65536;
  for (int idx = tid; idx < W * 8; idx += 256) {
    const int key = idx % W, d0 = (idx / W) << 3;
    u16x8 vv = *(const u16x8*)(Vp + key * 64 + d0);
    #pragma unroll
    for (int z = 0; z < 8; ++z)
      *(u16*)(vtb + swz(d0 + z, key * 2)) = vv[z];
  }
  __syncthreads();
  u16* ctxP = (widx & 1) ? ctxO : ctxE;
  if (W == 512) attn_core<32>(Qp, ctxP, (const char*)lds, vtb, start, widx, bh);
  else          attn_core<24>(Qp, ctxP, (const char*)lds, vtb, start, widx, bh);
}

// merge parity buffers: p<128 -> E; p>=1920 -> O; else E+O. In-place on E is safe.
__global__ __launch_bounds__(256) void merge_kernel(const u16* __restrict__ e,
    const u16* __restrict__ o, u16* __restrict__ out){
  const int i = blockIdx.x * 256 + threadIdx.x;     // u16x8 index
  const int p = (i >> 7) & 2047;                    // (i*8 >> 10) & 2047
  u16x8 ev = ((const u16x8*)e)[i];
  u16x8 ov = ((const u16x8*)o)[i];
  u16x8 r;
  if (p < 128)        r = ev;
  else if (p >= 1920) r = ov;
  else {
    #pragma unroll
    for (int z = 0; z < 8; ++z) r[z] = f2bf(bf2f(ev[z]) + bf2f(ov[z]));
  }
  ((u16x8*)out)[i] = r;
}

// ---------------- host
extern "C" void kernel_launch(void* const* d_in, const int* in_sizes, int n_in,
                              void* d_out, int out_size, void* d_ws, size_t ws_size,
                              hipStream_t stream) {
  const float* hidden = (const float*)d_in[0];
  const float* ln1_g  = (const float*)d_in[1];
  const float* ln1_b  = (const float*)d_in[2];
  const float* wq     = (const float*)d_in[3];
  const float* bq     = (const float*)d_in[4];
  const float* wk     = (const float*)d_in[5];
  const float* bk     = (const float*)d_in[6];
  const float* wv     = (const float*)d_in[7];
  const float* bv     = (const float*)d_in[8];
  const float* wproj  = (const float*)d_in[9];
  const float* bproj  = (const float*)d_in[10];
  const float* ln2_g  = (const float*)d_in[11];
  const float* ln2_b  = (const float*)d_in[12];
  const float* w1     = (const float*)d_in[13];
  const float* b1     = (const float*)d_in[14];
  const float* w2     = (const float*)d_in[15];
  const float* b2     = (const float*)d_in[16];

  char* ws = (char*)d_ws;
  u16* xb    = (u16*)(ws + 0);            // 16 MiB (LN1/LN2 out; ctxO during attn)
  u16* wqkvT = (u16*)(ws + 16777216);     // 6 MiB [3072][1024]
  u16* wpT   = (u16*)(ws + 23068672);     // 2 MiB
  u16* w1T   = (u16*)(ws + 25165824);     // 8 MiB
  u16* w2T   = (u16*)(ws + 33554432);     // 8 MiB
  u16* qb    = (u16*)(ws + 41943040);     // q,k,v contiguous: 3 x 16 MiB
  u16* kb    = (u16*)(ws + 58720256);
  u16* vb    = (u16*)(ws + 75497472);
  u16* ctxE  = (u16*)(ws + 92274688);     // 16 MiB (merged ctx in-place)
  u16* ctxO  = (u16*)(ws + 0);            // aliases xb (dead between qkv and ln2)
  float* bqkv = (float*)(ws + 92274688);  // aliases ctxE start (dead before attn)
  u16* res2  = (u16*)(ws + 109051904);    // 16 MiB bf16
  u16* mid   = (u16*)(ws + 41943040);     // 64 MiB, reuses qb..ctx

  dim3 tb(32, 8);
  transpose_cvt<<<dim3(32, 32), tb, 0, stream>>>(wq, wqkvT, 1024, 1024);
  transpose_cvt<<<dim3(32, 32), tb, 0, stream>>>(wk, wqkvT + 1048576, 1024, 1024);
  transpose_cvt<<<dim3(32, 32), tb, 0, stream>>>(wv, wqkvT + 2097152, 1024, 1024);
  transpose_cvt<<<dim3(32, 32), tb, 0, stream>>>(wproj, wpT, 1024, 1024);
  transpose_cvt<<<dim3(128, 32), tb, 0, stream>>>(w1, w1T, 1024, 4096);
  transpose_cvt<<<dim3(32, 128), tb, 0, stream>>>(w2, w2T, 4096, 1024);
  concat3<<<12, 256, 0, stream>>>(bq, bk, bv, bqkv);

  ln_kernel<0><<<8192, 256, 0, stream>>>(hidden, ln1_g, ln1_b, xb);

  gemm8<0><<<384, 512, 0, stream>>>(xb, wqkvT, bqkv, nullptr, qb, 8192, 3072, 1024);

  attn_kernel<<<512, 256, 0, stream>>>(qb, kb, vb, ctxE, ctxO);
  merge_kernel<<<4096, 256, 0, stream>>>(ctxE, ctxO, ctxE);

  gemmW<1><<<256, 512, 0, stream>>>(ctxE, wpT, bproj, hidden, res2, 8192, 1024, 1024);

  ln_kernel<1><<<8192, 256, 0, stream>>>(res2, ln2_g, ln2_b, xb);

  gemm8<2><<<512, 512, 0, stream>>>(xb, w1T, b1, nullptr, mid, 8192, 4096, 1024);
  gemmW<3><<<256, 512, 0, stream>>>(mid, w2T, b2, res2, (float*)d_out, 8192, 1024, 4096);
}

// Round 19
// 379.568 us; speedup vs baseline: 1.1237x; 1.0841x over previous
//
#include <hip/hip_runtime.h>
#include <math.h>

typedef unsigned short u16;
typedef unsigned int u32;
typedef __attribute__((ext_vector_type(8))) short bf16x8;
typedef __attribute__((ext_vector_type(8))) unsigned short u16x8;
typedef __attribute__((ext_vector_type(4))) float f32x4;
typedef __attribute__((ext_vector_type(4))) unsigned int u32x4;

__device__ __forceinline__ u16 f2bf(float f){
  union { float f; unsigned u; } c; c.f = f;
  unsigned u = c.u;
  return (u16)((u + 0x7fffu + ((u >> 16) & 1u)) >> 16);
}
__device__ __forceinline__ float bf2f(u16 h){
  union { unsigned u; float f; } c; c.u = ((unsigned)h) << 16;
  return c.f;
}
__device__ __forceinline__ u32 pack2(float lo, float hi){
  return (u32)f2bf(lo) | ((u32)f2bf(hi) << 16);
}
__device__ __forceinline__ void gload_lds16(const void* g, void* l){
  __builtin_amdgcn_global_load_lds((const __attribute__((address_space(1))) void*)g,
                                   (__attribute__((address_space(3))) void*)l, 16, 0, 0);
}
// attention V^T swizzle (r17): XOR row bits into chunk bits (byte bits 6-9).
__device__ __forceinline__ int swz(int row, int bc){
  return (row << 10) + (bc ^ ((row & 15) << 6));
}

#define BAR() asm volatile("s_barrier" ::: "memory")

// ---------------- weight transpose + f32->bf16 : in [K][N] f32 -> out [N][K] bf16
__global__ void transpose_cvt(const float* __restrict__ in, u16* __restrict__ out, int K, int N){
  __shared__ float tile[32][33];
  int n0 = blockIdx.x << 5, k0 = blockIdx.y << 5;
  int tx = threadIdx.x, ty = threadIdx.y;
  #pragma unroll
  for (int r = 0; r < 32; r += 8)
    tile[ty + r][tx] = in[(size_t)(k0 + ty + r) * N + n0 + tx];
  __syncthreads();
  #pragma unroll
  for (int r = 0; r < 32; r += 8)
    out[(size_t)(n0 + ty + r) * K + k0 + tx] = f2bf(tile[tx][ty + r]);
}

__global__ void concat3(const float* __restrict__ a, const float* __restrict__ b,
                        const float* __restrict__ c, float* __restrict__ o){
  int i = blockIdx.x * 256 + threadIdx.x;
  o[i] = i < 1024 ? a[i] : (i < 2048 ? b[i - 1024] : c[i - 2048]);
}

// ---------------- layernorm: [rows][1024] (f32 or bf16 in) -> bf16 out
__device__ __forceinline__ float blockReduce(float v, float* ws){
  #pragma unroll
  for (int m = 1; m < 64; m <<= 1) v += __shfl_xor(v, m, 64);
  int w = threadIdx.x >> 6;
  __syncthreads();
  if ((threadIdx.x & 63) == 0) ws[w] = v;
  __syncthreads();
  return ws[0] + ws[1] + ws[2] + ws[3];
}

struct U16x4 { u16 x, y, z, w; };

template<int BF16IN>
__global__ __launch_bounds__(256) void ln_kernel(const void* __restrict__ in_, const float* __restrict__ g,
    const float* __restrict__ be, u16* __restrict__ out){
  __shared__ float ws[4];
  int row = blockIdx.x;
  float vx, vy, vz, vw;
  if constexpr (BF16IN) {
    const U16x4 v = ((const U16x4*)((const u16*)in_ + ((size_t)row << 10)))[threadIdx.x];
    vx = bf2f(v.x); vy = bf2f(v.y); vz = bf2f(v.z); vw = bf2f(v.w);
  } else {
    const float4 v = ((const float4*)((const float*)in_ + ((size_t)row << 10)))[threadIdx.x];
    vx = v.x; vy = v.y; vz = v.z; vw = v.w;
  }
  float s = vx + vy + vz + vw;
  s = blockReduce(s, ws);
  float mean = s * (1.f / 1024.f);
  float dx = vx - mean, dy = vy - mean, dz = vz - mean, dw = vw - mean;
  float s2 = dx*dx + dy*dy + dz*dz + dw*dw;
  s2 = blockReduce(s2, ws);
  float rstd = rsqrtf(s2 * (1.f / 1024.f) + 1e-5f);
  float4 gv = ((const float4*)g)[threadIdx.x];
  float4 bv = ((const float4*)be)[threadIdx.x];
  U16x4 ov;
  ov.x = f2bf(dx * rstd * gv.x + bv.x);
  ov.y = f2bf(dy * rstd * gv.y + bv.y);
  ov.z = f2bf(dz * rstd * gv.z + bv.z);
  ov.w = f2bf(dw * rstd * gv.w + bv.w);
  ((U16x4*)(out + ((size_t)row << 10)))[threadIdx.x] = ov;
}

// ================= 256x256 8-phase bf16 GEMM =========
template<int QM, int QN, int LB, int RDA, int WAIT, typename F>
__device__ __forceinline__ void ph256(const char* lds, const int (&aoff)[2], const int (&boff)[2],
    bf16x8 (&af)[4][2], bf16x8 (&bv)[2][2], f32x4 (&acc)[8][4], F&& stg){
  if constexpr (RDA) {
    const char* Ar = lds + LB*65536 + QM*16384;
    #pragma unroll
    for (int fi = 0; fi < 4; ++fi)
      #pragma unroll
      for (int ks = 0; ks < 2; ++ks)
        af[fi][ks] = *(const bf16x8*)(Ar + fi*2048 + aoff[ks]);
  }
  {
    const char* Br = lds + LB*65536 + 32768 + QN*16384;
    #pragma unroll
    for (int fj = 0; fj < 2; ++fj)
      #pragma unroll
      for (int ks = 0; ks < 2; ++ks)
        bv[fj][ks] = *(const bf16x8*)(Br + fj*2048 + boff[ks]);
  }
  stg();
  BAR();
  asm volatile("s_waitcnt lgkmcnt(0)" ::: "memory");
  __builtin_amdgcn_sched_barrier(0);
  __builtin_amdgcn_s_setprio(1);
  #pragma unroll
  for (int fi = 0; fi < 4; ++fi)
    #pragma unroll
    for (int fj = 0; fj < 2; ++fj){
      acc[QM*4+fi][QN*2+fj] = __builtin_amdgcn_mfma_f32_16x16x32_bf16(af[fi][0], bv[fj][0], acc[QM*4+fi][QN*2+fj], 0, 0, 0);
      acc[QM*4+fi][QN*2+fj] = __builtin_amdgcn_mfma_f32_16x16x32_bf16(af[fi][1], bv[fj][1], acc[QM*4+fi][QN*2+fj], 0, 0, 0);
    }
  __builtin_amdgcn_s_setprio(0);
  if constexpr (WAIT >= 0)
    asm volatile("s_waitcnt vmcnt(%0)" :: "n"(WAIT) : "memory");
  BAR();
}

// EPI 0: bf16 scatter to q/k/v [3][B*NH, S, HD] (+bias)
// EPI 2: bf16 = gelu(acc + bias)   [tanh-form sigmoid approx]
template<int EPI>
__global__ __launch_bounds__(512, 2) void gemm8(
    const u16* __restrict__ A, const u16* __restrict__ Bt,
    const float* __restrict__ bias, const float* __restrict__ add,
    void* __restrict__ out, int M, int N, int K)
{
  __shared__ char lds[147456];
  const int NT = K >> 6;
  const int NI = NT >> 1;
  const int nbx = N >> 8;
  const int nwg = gridDim.x, orig = blockIdx.x;
  const int q = nwg >> 3, r = nwg & 7, x = orig & 7;
  const int wg = (x < r ? x * (q + 1) : r * (q + 1) + (x - r) * q) + (orig >> 3);
  const int bx = wg % nbx, by = wg / nbx;
  const int m0 = by << 8, n0 = bx << 8;

  const int tid = threadIdx.x, wave = tid >> 6, lane = tid & 63;
  const int wr = (wave >> 2) & 1, wc = wave & 3;
  const int lcol = lane & 15, lrow4 = lane >> 4;

  int aoff[2], boff[2];
  #pragma unroll
  for (int ks = 0; ks < 2; ++ks){
    const int chunk = (ks*4 + lrow4) ^ (lane & 7);
    aoff[ks] = (wr*64 + lcol)*128 + chunk*16;
    boff[ks] = (wc*32 + lcol)*128 + chunk*16;
  }

  auto STAGE = [&](const u16* Mat, int rbase, int isB, int h, int tt){
    const int rb = (tt < NT) ? ((tt & 1) * 65536 + isB * 32768 + h * 16384) : 131072;
    const int tc = (tt < NT) ? tt : NT - 1;
    #pragma unroll
    for (int s = 0; s < 2; ++s){
      const int o = (tid + s*512) << 4;
      const int row = o >> 7;
      const int c = (o >> 4) & 7;
      const char* src = (const char*)(Mat + (size_t)(rbase + h*128 + row) * K + (size_t)tc * 64)
                        + ((c ^ (row & 7)) << 4);
      gload_lds16(src, (char*)lds + rb + o);
    }
  };

  f32x4 acc[8][4] = {};
  bf16x8 af[4][2], bv[2][2];

  STAGE(A,  m0, 0, 0, 0);
  STAGE(Bt, n0, 1, 0, 0);
  STAGE(A,  m0, 0, 1, 0);
  STAGE(Bt, n0, 1, 1, 0);
  STAGE(A,  m0, 0, 0, 1);
  STAGE(Bt, n0, 1, 1, 1);
  STAGE(A,  m0, 0, 1, 1);
  asm volatile("s_waitcnt vmcnt(6)" ::: "memory");
  BAR();

  for (int i = 0; i < NI; ++i) {
    const int T = 2*i;
    ph256<0, 0, 0, 1, -1>(lds, aoff, boff, af, bv, acc, [&]{ STAGE(Bt, n0, 1, 0, T+1); });
    ph256<0, 1, 0, 0, -1>(lds, aoff, boff, af, bv, acc, [&]{ STAGE(A,  m0, 0, 0, T+2); });
    ph256<1, 1, 0, 1, -1>(lds, aoff, boff, af, bv, acc, [&]{});
    ph256<1, 0, 0, 0,  4>(lds, aoff, boff, af, bv, acc, [&]{ STAGE(Bt, n0, 1, 1, T+2); });
    ph256<0, 0, 1, 1, -1>(lds, aoff, boff, af, bv, acc, [&]{ STAGE(Bt, n0, 1, 0, T+2); });
    ph256<0, 1, 1, 0, -1>(lds, aoff, boff, af, bv, acc, [&]{ STAGE(A,  m0, 0, 1, T+2); });
    ph256<1, 1, 1, 1, -1>(lds, aoff, boff, af, bv, acc, [&]{ STAGE(A,  m0, 0, 0, T+3); });
    ph256<1, 0, 1, 0,  6>(lds, aoff, boff, af, bv, acc, [&]{ STAGE(Bt, n0, 1, 1, T+3); STAGE(A, m0, 0, 1, T+3); });
  }

  { size_t bp = (size_t)bias, ap = (size_t)add;
    asm volatile("" : "+v"(bp), "+v"(ap));
    bias = (const float*)bp; add = (const float*)ap; }

  #pragma unroll
  for (int mi = 0; mi < 8; ++mi) {
    const int gmb = m0 + (mi>>2)*128 + wr*64 + (mi&3)*16 + lrow4*4;
    #pragma unroll
    for (int ni = 0; ni < 4; ++ni) {
      const int gn = n0 + (ni>>1)*128 + wc*32 + (ni&1)*16 + lcol;
      const float bs = bias[gn];
      #pragma unroll
      for (int rr = 0; rr < 4; ++rr) {
        const int gm = gmb + rr;
        float v = acc[mi][ni][rr] + bs;
        if constexpr (EPI == 0) {
          const int which = gn >> 10, g = gn & 1023;
          const int b = gm >> 11, s = gm & 2047;
          const int h = g >> 6, d = g & 63;
          ((u16*)out)[(size_t)which * 8388608 + ((((size_t)((b << 4) + h) << 11) + s) << 6) + d] = f2bf(v);
        } else {
          const float y2 = 1.5957691216f * v + 0.0713548353f * v * v * v;
          const float e = __expf(y2);
          ((u16*)out)[(size_t)gm * N + gn] = f2bf(v - v / (1.f + e));
        }
      }
    }
  }
}

// ================= 128x256 4-phase bf16 GEMM (wide) ====
// EPI 1: proj  -> out bf16 = acc + bias + add(f32)
// EPI 3: ffn2  -> out f32  = acc + bias + add(bf16)
template<int QN, int LB, int RDA, int WAIT, typename F>
__device__ __forceinline__ void phW(const char* lds, const int (&aoff)[2], const int (&boff)[2],
    bf16x8 (&af)[4][2], bf16x8 (&bv)[2][2], f32x4 (&acc)[4][4], F&& stg){
  if constexpr (RDA) {
    const char* Ar = lds + LB*49152;
    #pragma unroll
    for (int fi = 0; fi < 4; ++fi)
      #pragma unroll
      for (int ks = 0; ks < 2; ++ks)
        af[fi][ks] = *(const bf16x8*)(Ar + fi*2048 + aoff[ks]);
  }
  {
    const char* Br = lds + LB*49152 + 16384 + QN*16384;
    #pragma unroll
    for (int fj = 0; fj < 2; ++fj)
      #pragma unroll
      for (int ks = 0; ks < 2; ++ks)
        bv[fj][ks] = *(const bf16x8*)(Br + fj*2048 + boff[ks]);
  }
  stg();
  BAR();
  asm volatile("s_waitcnt lgkmcnt(0)" ::: "memory");
  __builtin_amdgcn_sched_barrier(0);
  __builtin_amdgcn_s_setprio(1);
  #pragma unroll
  for (int fi = 0; fi < 4; ++fi)
    #pragma unroll
    for (int fj = 0; fj < 2; ++fj){
      acc[fi][QN*2+fj] = __builtin_amdgcn_mfma_f32_16x16x32_bf16(af[fi][0], bv[fj][0], acc[fi][QN*2+fj], 0, 0, 0);
      acc[fi][QN*2+fj] = __builtin_amdgcn_mfma_f32_16x16x32_bf16(af[fi][1], bv[fj][1], acc[fi][QN*2+fj], 0, 0, 0);
    }
  __builtin_amdgcn_s_setprio(0);
  if constexpr (WAIT >= 0)
    asm volatile("s_waitcnt vmcnt(%0)" :: "n"(WAIT) : "memory");
  BAR();
}

template<int EPI>
__global__ __launch_bounds__(512, 2) void gemmW(
    const u16* __restrict__ A, const u16* __restrict__ Bt,
    const float* __restrict__ bias, const void* __restrict__ add,
    void* __restrict__ out, int M, int N, int K)
{
  __shared__ char lds[106496];
  const int NT = K >> 6;
  const int NI = NT >> 1;
  const int nbx = N >> 8;
  const int nwg = gridDim.x, orig = blockIdx.x;
  const int q = nwg >> 3, r = nwg & 7, x = orig & 7;
  const int wg = (x < r ? x * (q + 1) : r * (q + 1) + (x - r) * q) + (orig >> 3);
  const int bx = wg % nbx, by = wg / nbx;
  const int m0 = by << 7, n0 = bx << 8;

  const int tid = threadIdx.x, wave = tid >> 6, lane = tid & 63;
  const int wr = wave >> 2, wc = wave & 3;
  const int lcol = lane & 15, lrow4 = lane >> 4;

  int aoff[2], boff[2];
  #pragma unroll
  for (int ks = 0; ks < 2; ++ks){
    const int chunk = (ks*4 + lrow4) ^ (lane & 7);
    aoff[ks] = (wr*64 + lcol)*128 + chunk*16;
    boff[ks] = (wc*32 + lcol)*128 + chunk*16;
  }

  auto STAGE = [&](const u16* Mat, int rbase, int kind, int tt){
    const int rb = (tt < NT) ? ((tt & 1) * 49152 + kind * 16384) : 98304;
    const int tc = (tt < NT) ? tt : NT - 1;
    #pragma unroll
    for (int s = 0; s < 2; ++s){
      const int o = (tid + s*512) << 4;
      const int row = o >> 7;
      const int c = (o >> 4) & 7;
      const char* src = (const char*)(Mat + (size_t)(rbase + row) * K + (size_t)tc * 64)
                        + ((c ^ (row & 7)) << 4);
      gload_lds16(src, (char*)lds + rb + o);
    }
  };

  f32x4 acc[4][4] = {};
  bf16x8 af[4][2], bv[2][2];

  STAGE(A,  m0,       0, 0);
  STAGE(Bt, n0,       1, 0);
  STAGE(Bt, n0 + 128, 2, 0);
  STAGE(A,  m0,       0, 1);
  STAGE(Bt, n0,       1, 1);
  asm volatile("s_waitcnt vmcnt(4)" ::: "memory");
  BAR();

  for (int i = 0; i < NI; ++i) {
    const int T = 2*i;
    phW<0, 0, 1, -1>(lds, aoff, boff, af, bv, acc, [&]{ STAGE(Bt, n0 + 128, 2, T+1); });
    phW<1, 0, 0,  4>(lds, aoff, boff, af, bv, acc, [&]{ STAGE(A, m0, 0, T+2); STAGE(Bt, n0, 1, T+2); });
    phW<0, 1, 1, -1>(lds, aoff, boff, af, bv, acc, [&]{ STAGE(Bt, n0 + 128, 2, T+2); });
    phW<1, 1, 0,  4>(lds, aoff, boff, af, bv, acc, [&]{ STAGE(A, m0, 0, T+3); STAGE(Bt, n0, 1, T+3); });
  }

  { size_t bp = (size_t)bias, ap = (size_t)add;
    asm volatile("" : "+v"(bp), "+v"(ap));
    bias = (const float*)bp; add = (const void*)ap; }

  #pragma unroll
  for (int fi = 0; fi < 4; ++fi) {
    const int gmb = m0 + wr*64 + fi*16 + lrow4*4;
    #pragma unroll
    for (int j = 0; j < 4; ++j) {
      const int gn = n0 + (j>>1)*128 + wc*32 + (j&1)*16 + lcol;
      const float bs = bias[gn];
      #pragma unroll
      for (int rr = 0; rr < 4; ++rr) {
        const int gm = gmb + rr;
        float v = acc[fi][j][rr] + bs;
        if constexpr (EPI == 1) {
          ((u16*)out)[(size_t)gm * N + gn] = f2bf(v + ((const float*)add)[(size_t)gm * N + gn]);
        } else {
          ((float*)out)[(size_t)gm * N + gn] = v + bf2f(((const u16*)add)[(size_t)gm * N + gn]);
        }
      }
    }
  }
}

// ================= windowed attention: quarter-split + K in LDS, 512 threads ==
// 512 blocks x 512 thr (8 waves), (512,1) -> VGPR cap 128; demand ~105 after
// quarter-split (acc[NJ/4]=32 VGPR) + K-from-LDS (no global addr state, r18).
// LDS: K 64KB + V^T 64KB = 128KB -> 1 block/CU x 8 waves = 2 waves/SIMD (2x r18).
template<int NJ>  // NJ = W/16 (24 or 32)
__device__ void attn_core(const u16* __restrict__ Qp, u16* __restrict__ ctxP,
    const char* ktb, const char* vtb, int start, int widx, int bh)
{
  const int tid = threadIdx.x, wave = tid >> 6, lane = tid & 63;
  const int q = lane & 15, g = lane >> 4;
  constexpr int QTR = NJ / 4;
  const float scale = 0.125f;  // 64^-0.5
  const int b = bh >> 4, h = bh & 15;
  const int sw0 = ((g ^ (q & 7)) << 4);
  const int sw1 = (((4 | g) ^ (q & 7)) << 4);

  for (int qt = wave; qt < NJ; qt += 8) {
    const int q0 = qt * 16;
    const bf16x8 bq0 = *(const bf16x8*)(Qp + (q0 + q) * 64 + g * 8);
    const bf16x8 bq1 = *(const bf16x8*)(Qp + (q0 + q) * 64 + 32 + g * 8);
    float m = -3.0e38f, l = 0.f;
    f32x4 o[4] = {};
    const int s0 = ((g & 1) << 5) + q;
    const int s1 = s0 + 16;
    const bool lowj = (g < 2);

    #pragma unroll
    for (int hh = 0; hh < 4; ++hh) {
      f32x4 acc[QTR];
      #pragma unroll
      for (int j = 0; j < QTR; ++j) {
        const int jj = hh * QTR + j;
        const char* kr = ktb + (jj*16 + q) * 128;
        bf16x8 k0 = *(const bf16x8*)(kr + sw0);
        bf16x8 k1 = *(const bf16x8*)(kr + sw1);
        f32x4 t = {};
        t = __builtin_amdgcn_mfma_f32_16x16x32_bf16(k0, bq0, t, 0, 0, 0);
        t = __builtin_amdgcn_mfma_f32_16x16x32_bf16(k1, bq1, t, 0, 0, 0);
        acc[j] = t;
        if ((j & 3) == 3) __builtin_amdgcn_sched_barrier(0);  // cap read hoisting
      }
      float mh = -3.0e38f;
      #pragma unroll
      for (int j = 0; j < QTR; ++j)
        #pragma unroll
        for (int r = 0; r < 4; ++r) mh = fmaxf(mh, acc[j][r]);
      mh = fmaxf(mh, __shfl_xor(mh, 16, 64));
      mh = fmaxf(mh, __shfl_xor(mh, 32, 64));
      const float mn = fmaxf(m, mh);
      const float fr = __expf((m - mn) * scale);
      m = mn;
      l *= fr;
      #pragma unroll
      for (int df = 0; df < 4; ++df)
        #pragma unroll
        for (int r = 0; r < 4; ++r) o[df][r] *= fr;
      #pragma unroll
      for (int j = 0; j < QTR; ++j)
        #pragma unroll
        for (int r = 0; r < 4; ++r) {
          float e = __expf((acc[j][r] - mn) * scale);
          acc[j][r] = e;
          l += e;
        }
      #pragma unroll
      for (int c = 0; c < QTR / 2; ++c) {
        const u32 a0 = pack2(acc[2*c][0],   acc[2*c][1]);
        const u32 b0 = pack2(acc[2*c][2],   acc[2*c][3]);
        const u32 a1 = pack2(acc[2*c+1][0], acc[2*c+1][1]);
        const u32 b1 = pack2(acc[2*c+1][2], acc[2*c+1][3]);
        const u32 A0l = __shfl(a0, s0, 64), A1l = __shfl(a1, s0, 64);
        const u32 B0l = __shfl(b0, s0, 64), B1l = __shfl(b1, s0, 64);
        const u32 A0h = __shfl(a0, s1, 64), A1h = __shfl(a1, s1, 64);
        const u32 B0h = __shfl(b0, s1, 64), B1h = __shfl(b1, s1, 64);
        union { u32 u[4]; bf16x8 v; } pf;
        pf.u[0] = lowj ? A0l : A1l;
        pf.u[1] = lowj ? B0l : B1l;
        pf.u[2] = lowj ? A0h : A1h;
        pf.u[3] = lowj ? B0h : B1h;
        const int cg = hh * (QTR / 2) + c;
        #pragma unroll
        for (int df = 0; df < 4; ++df) {
          bf16x8 pv = *(const bf16x8*)(vtb + swz(df*16 + q, (cg*32 + g*8) * 2));
          o[df] = __builtin_amdgcn_mfma_f32_16x16x32_bf16(pv, pf.v, o[df], 0, 0, 0);
        }
        if ((c & 1) == 1) __builtin_amdgcn_sched_barrier(0);
      }
    }
    l += __shfl_xor(l, 16, 64);
    l += __shfl_xor(l, 32, 64);
    const float rs = 1.f / l;

    const int p = start + q0 + q;
    const int rel = p - (widx * 256 - 128);
    const float wgt = (rel < 256) ? ((widx == 0) ? 1.f : (float)rel * (1.f / 255.f))
                                  : ((widx == 7) ? 1.f : (1.f - (float)(rel - 256) * (1.f / 255.f)));
    const float rw = rs * wgt;
    u32 w0[4], w1[4];
    #pragma unroll
    for (int df = 0; df < 4; ++df) {
      w0[df] = pack2(o[df][0] * rw, o[df][1] * rw);
      w1[df] = pack2(o[df][2] * rw, o[df][3] * rw);
    }
    u32 W8[8] = {};
    #pragma unroll
    for (int df = 0; df < 4; ++df)
      #pragma unroll
      for (int sg = 0; sg < 4; ++sg) {
        const u32 t0 = __shfl(w0[df], sg*16 + q, 64);
        const u32 t1 = __shfl(w1[df], sg*16 + q, 64);
        if (g == df) { W8[2*sg] = t0; W8[2*sg+1] = t1; }
      }
    u16* dst = ctxP + ((((size_t)(b << 11) + (size_t)p) << 10) + (h << 6) + (g << 4));
    u32x4 lo = { W8[0], W8[1], W8[2], W8[3] };
    u32x4 hi = { W8[4], W8[5], W8[6], W8[7] };
    *(u32x4*)dst = lo;
    *(u32x4*)(dst + 8) = hi;
  }
}

__global__ __launch_bounds__(512, 1) void attn_kernel(const u16* __restrict__ qg, const u16* __restrict__ kg,
    const u16* __restrict__ vg, u16* __restrict__ ctxE, u16* __restrict__ ctxO){
  __shared__ char lds[131072];   // K @0 (64KB), V^T @65536 (64KB) -> 1 block/CU
  const int widx = (int)blockIdx.x >> 6;
  const int bh = blockIdx.x & 63;
  const int i0 = widx << 8;
  int start = i0 - 128; if (start < 0) start = 0;
  int end = i0 + 384;   if (end > 2048) end = 2048;
  const int W = end - start;
  const int tid = threadIdx.x;
  const u16* Qp = qg + (((size_t)bh << 11) + start) * 64;
  const u16* Kp = kg + (((size_t)bh << 11) + start) * 64;
  const u16* Vp = vg + (((size_t)bh << 11) + start) * 64;
  // stage K: rows of 128B; LDS chunk c holds global chunk c ^ (row&7) (rule #21)
  const int nks = W >> 6;             // W*8 16B-chunks / 512 threads
  for (int s = 0; s < nks; ++s) {
    const int o = (tid + s*512) << 4;
    const int row = o >> 7, c = (o >> 4) & 7;
    const char* src = (const char*)(Kp + (size_t)row * 64) + ((c ^ (row & 7)) << 4);
    gload_lds16(src, (char*)lds + o);
  }
  // stage V^T (scalar transpose; r17 swizzle; key = idx%W spreads write banks)
  char* vtb = (char*)lds + 65536;
  for (int idx = tid; idx < W * 8; idx += 512) {
    const int key = idx % W, d0 = (idx / W) << 3;
    u16x8 vv = *(const u16x8*)(Vp + key * 64 + d0);
    #pragma unroll
    for (int z = 0; z < 8; ++z)
      *(u16*)(vtb + swz(d0 + z, key * 2)) = vv[z];
  }
  __syncthreads();
  u16* ctxP = (widx & 1) ? ctxO : ctxE;
  if (W == 512) attn_core<32>(Qp, ctxP, (const char*)lds, vtb, start, widx, bh);
  else          attn_core<24>(Qp, ctxP, (const char*)lds, vtb, start, widx, bh);
}

// merge parity buffers: p<128 -> E; p>=1920 -> O; else E+O. In-place on E is safe.
__global__ __launch_bounds__(256) void merge_kernel(const u16* __restrict__ e,
    const u16* __restrict__ o, u16* __restrict__ out){
  const int i = blockIdx.x * 256 + threadIdx.x;     // u16x8 index
  const int p = (i >> 7) & 2047;                    // (i*8 >> 10) & 2047
  u16x8 ev = ((const u16x8*)e)[i];
  u16x8 ov = ((const u16x8*)o)[i];
  u16x8 r;
  if (p < 128)        r = ev;
  else if (p >= 1920) r = ov;
  else {
    #pragma unroll
    for (int z = 0; z < 8; ++z) r[z] = f2bf(bf2f(ev[z]) + bf2f(ov[z]));
  }
  ((u16x8*)out)[i] = r;
}

// ---------------- host
extern "C" void kernel_launch(void* const* d_in, const int* in_sizes, int n_in,
                              void* d_out, int out_size, void* d_ws, size_t ws_size,
                              hipStream_t stream) {
  const float* hidden = (const float*)d_in[0];
  const float* ln1_g  = (const float*)d_in[1];
  const float* ln1_b  = (const float*)d_in[2];
  const float* wq     = (const float*)d_in[3];
  const float* bq     = (const float*)d_in[4];
  const float* wk     = (const float*)d_in[5];
  const float* bk     = (const float*)d_in[6];
  const float* wv     = (const float*)d_in[7];
  const float* bv     = (const float*)d_in[8];
  const float* wproj  = (const float*)d_in[9];
  const float* bproj  = (const float*)d_in[10];
  const float* ln2_g  = (const float*)d_in[11];
  const float* ln2_b  = (const float*)d_in[12];
  const float* w1     = (const float*)d_in[13];
  const float* b1     = (const float*)d_in[14];
  const float* w2     = (const float*)d_in[15];
  const float* b2     = (const float*)d_in[16];

  char* ws = (char*)d_ws;
  u16* xb    = (u16*)(ws + 0);            // 16 MiB (LN1/LN2 out; ctxO during attn)
  u16* wqkvT = (u16*)(ws + 16777216);     // 6 MiB [3072][1024]
  u16* wpT   = (u16*)(ws + 23068672);     // 2 MiB
  u16* w1T   = (u16*)(ws + 25165824);     // 8 MiB
  u16* w2T   = (u16*)(ws + 33554432);     // 8 MiB
  u16* qb    = (u16*)(ws + 41943040);     // q,k,v contiguous: 3 x 16 MiB
  u16* kb    = (u16*)(ws + 58720256);
  u16* vb    = (u16*)(ws + 75497472);
  u16* ctxE  = (u16*)(ws + 92274688);     // 16 MiB (merged ctx in-place)
  u16* ctxO  = (u16*)(ws + 0);            // aliases xb (dead between qkv and ln2)
  float* bqkv = (float*)(ws + 92274688);  // aliases ctxE start (dead before attn)
  u16* res2  = (u16*)(ws + 109051904);    // 16 MiB bf16
  u16* mid   = (u16*)(ws + 41943040);     // 64 MiB, reuses qb..ctx

  dim3 tb(32, 8);
  transpose_cvt<<<dim3(32, 32), tb, 0, stream>>>(wq, wqkvT, 1024, 1024);
  transpose_cvt<<<dim3(32, 32), tb, 0, stream>>>(wk, wqkvT + 1048576, 1024, 1024);
  transpose_cvt<<<dim3(32, 32), tb, 0, stream>>>(wv, wqkvT + 2097152, 1024, 1024);
  transpose_cvt<<<dim3(32, 32), tb, 0, stream>>>(wproj, wpT, 1024, 1024);
  transpose_cvt<<<dim3(128, 32), tb, 0, stream>>>(w1, w1T, 1024, 4096);
  transpose_cvt<<<dim3(32, 128), tb, 0, stream>>>(w2, w2T, 4096, 1024);
  concat3<<<12, 256, 0, stream>>>(bq, bk, bv, bqkv);

  ln_kernel<0><<<8192, 256, 0, stream>>>(hidden, ln1_g, ln1_b, xb);

  gemm8<0><<<384, 512, 0, stream>>>(xb, wqkvT, bqkv, nullptr, qb, 8192, 3072, 1024);

  attn_kernel<<<512, 512, 0, stream>>>(qb, kb, vb, ctxE, ctxO);
  merge_kernel<<<4096, 256, 0, stream>>>(ctxE, ctxO, ctxE);

  gemmW<1><<<256, 512, 0, stream>>>(ctxE, wpT, bproj, hidden, res2, 8192, 1024, 1024);

  ln_kernel<1><<<8192, 256, 0, stream>>>(res2, ln2_g, ln2_b, xb);

  gemm8<2><<<512, 512, 0, stream>>>(xb, w1T, b1, nullptr, mid, 8192, 4096, 1024);
  gemmW<3><<<256, 512, 0, stream>>>(mid, w2T, b2, res2, (float*)d_out, 8192, 1024, 4096);
}

// Round 20
// 379.507 us; speedup vs baseline: 1.1239x; 1.0002x over previous
//
#include <hip/hip_runtime.h>
#include <math.h>

typedef unsigned short u16;
typedef unsigned int u32;
typedef __attribute__((ext_vector_type(8))) short bf16x8;
typedef __attribute__((ext_vector_type(8))) unsigned short u16x8;
typedef __attribute__((ext_vector_type(4))) float f32x4;
typedef __attribute__((ext_vector_type(4))) unsigned int u32x4;

__device__ __forceinline__ u16 f2bf(float f){
  union { float f; unsigned u; } c; c.f = f;
  unsigned u = c.u;
  return (u16)((u + 0x7fffu + ((u >> 16) & 1u)) >> 16);
}
__device__ __forceinline__ float bf2f(u16 h){
  union { unsigned u; float f; } c; c.u = ((unsigned)h) << 16;
  return c.f;
}
__device__ __forceinline__ u32 pack2(float lo, float hi){
  return (u32)f2bf(lo) | ((u32)f2bf(hi) << 16);
}
__device__ __forceinline__ void gload_lds16(const void* g, void* l){
  __builtin_amdgcn_global_load_lds((const __attribute__((address_space(1))) void*)g,
                                   (__attribute__((address_space(3))) void*)l, 16, 0, 0);
}
// attention V^T swizzle (r17): XOR row bits into chunk bits (byte bits 6-9).
__device__ __forceinline__ int swz(int row, int bc){
  return (row << 10) + (bc ^ ((row & 15) << 6));
}

#define BAR() asm volatile("s_barrier" ::: "memory")

// ---------------- weight transpose + f32->bf16 : in [K][N] f32 -> out [N][K] bf16
__global__ void transpose_cvt(const float* __restrict__ in, u16* __restrict__ out, int K, int N){
  __shared__ float tile[32][33];
  int n0 = blockIdx.x << 5, k0 = blockIdx.y << 5;
  int tx = threadIdx.x, ty = threadIdx.y;
  #pragma unroll
  for (int r = 0; r < 32; r += 8)
    tile[ty + r][tx] = in[(size_t)(k0 + ty + r) * N + n0 + tx];
  __syncthreads();
  #pragma unroll
  for (int r = 0; r < 32; r += 8)
    out[(size_t)(n0 + ty + r) * K + k0 + tx] = f2bf(tile[tx][ty + r]);
}

__global__ void concat3(const float* __restrict__ a, const float* __restrict__ b,
                        const float* __restrict__ c, float* __restrict__ o){
  int i = blockIdx.x * 256 + threadIdx.x;
  o[i] = i < 1024 ? a[i] : (i < 2048 ? b[i - 1024] : c[i - 2048]);
}

// ---------------- layernorm: [rows][1024] (f32 or bf16 in) -> bf16 out
__device__ __forceinline__ float blockReduce(float v, float* ws){
  #pragma unroll
  for (int m = 1; m < 64; m <<= 1) v += __shfl_xor(v, m, 64);
  int w = threadIdx.x >> 6;
  __syncthreads();
  if ((threadIdx.x & 63) == 0) ws[w] = v;
  __syncthreads();
  return ws[0] + ws[1] + ws[2] + ws[3];
}

struct U16x4 { u16 x, y, z, w; };

template<int BF16IN>
__global__ __launch_bounds__(256) void ln_kernel(const void* __restrict__ in_, const float* __restrict__ g,
    const float* __restrict__ be, u16* __restrict__ out){
  __shared__ float ws[4];
  int row = blockIdx.x;
  float vx, vy, vz, vw;
  if constexpr (BF16IN) {
    const U16x4 v = ((const U16x4*)((const u16*)in_ + ((size_t)row << 10)))[threadIdx.x];
    vx = bf2f(v.x); vy = bf2f(v.y); vz = bf2f(v.z); vw = bf2f(v.w);
  } else {
    const float4 v = ((const float4*)((const float*)in_ + ((size_t)row << 10)))[threadIdx.x];
    vx = v.x; vy = v.y; vz = v.z; vw = v.w;
  }
  float s = vx + vy + vz + vw;
  s = blockReduce(s, ws);
  float mean = s * (1.f / 1024.f);
  float dx = vx - mean, dy = vy - mean, dz = vz - mean, dw = vw - mean;
  float s2 = dx*dx + dy*dy + dz*dz + dw*dw;
  s2 = blockReduce(s2, ws);
  float rstd = rsqrtf(s2 * (1.f / 1024.f) + 1e-5f);
  float4 gv = ((const float4*)g)[threadIdx.x];
  float4 bv = ((const float4*)be)[threadIdx.x];
  U16x4 ov;
  ov.x = f2bf(dx * rstd * gv.x + bv.x);
  ov.y = f2bf(dy * rstd * gv.y + bv.y);
  ov.z = f2bf(dz * rstd * gv.z + bv.z);
  ov.w = f2bf(dw * rstd * gv.w + bv.w);
  ((U16x4*)(out + ((size_t)row << 10)))[threadIdx.x] = ov;
}

// ================= 256x256 8-phase bf16 GEMM =========
template<int QM, int QN, int LB, int RDA, int WAIT, typename F>
__device__ __forceinline__ void ph256(const char* lds, const int (&aoff)[2], const int (&boff)[2],
    bf16x8 (&af)[4][2], bf16x8 (&bv)[2][2], f32x4 (&acc)[8][4], F&& stg){
  if constexpr (RDA) {
    const char* Ar = lds + LB*65536 + QM*16384;
    #pragma unroll
    for (int fi = 0; fi < 4; ++fi)
      #pragma unroll
      for (int ks = 0; ks < 2; ++ks)
        af[fi][ks] = *(const bf16x8*)(Ar + fi*2048 + aoff[ks]);
  }
  {
    const char* Br = lds + LB*65536 + 32768 + QN*16384;
    #pragma unroll
    for (int fj = 0; fj < 2; ++fj)
      #pragma unroll
      for (int ks = 0; ks < 2; ++ks)
        bv[fj][ks] = *(const bf16x8*)(Br + fj*2048 + boff[ks]);
  }
  stg();
  BAR();
  asm volatile("s_waitcnt lgkmcnt(0)" ::: "memory");
  __builtin_amdgcn_sched_barrier(0);
  __builtin_amdgcn_s_setprio(1);
  #pragma unroll
  for (int fi = 0; fi < 4; ++fi)
    #pragma unroll
    for (int fj = 0; fj < 2; ++fj){
      acc[QM*4+fi][QN*2+fj] = __builtin_amdgcn_mfma_f32_16x16x32_bf16(af[fi][0], bv[fj][0], acc[QM*4+fi][QN*2+fj], 0, 0, 0);
      acc[QM*4+fi][QN*2+fj] = __builtin_amdgcn_mfma_f32_16x16x32_bf16(af[fi][1], bv[fj][1], acc[QM*4+fi][QN*2+fj], 0, 0, 0);
    }
  __builtin_amdgcn_s_setprio(0);
  if constexpr (WAIT >= 0)
    asm volatile("s_waitcnt vmcnt(%0)" :: "n"(WAIT) : "memory");
  BAR();
}

// EPI 0: bf16 scatter to q/k/v [3][B*NH, S, HD] (+bias)
// EPI 2: bf16 = gelu(acc + bias)   [tanh-form sigmoid approx]
// Staging addresses hoisted: base pointers [mat-half][s] + tt*128B per tile.
template<int EPI>
__global__ __launch_bounds__(512, 2) void gemm8(
    const u16* __restrict__ A, const u16* __restrict__ Bt,
    const float* __restrict__ bias, const float* __restrict__ add,
    void* __restrict__ out, int M, int N, int K)
{
  __shared__ char lds[147456];
  const int NT = K >> 6;
  const int NI = NT >> 1;
  const int nbx = N >> 8;
  const int nwg = gridDim.x, orig = blockIdx.x;
  const int q = nwg >> 3, r = nwg & 7, x = orig & 7;
  const int wg = (x < r ? x * (q + 1) : r * (q + 1) + (x - r) * q) + (orig >> 3);
  const int bx = wg % nbx, by = wg / nbx;
  const int m0 = by << 8, n0 = bx << 8;

  const int tid = threadIdx.x, wave = tid >> 6, lane = tid & 63;
  const int wr = (wave >> 2) & 1, wc = wave & 3;
  const int lcol = lane & 15, lrow4 = lane >> 4;

  int aoff[2], boff[2];
  #pragma unroll
  for (int ks = 0; ks < 2; ++ks){
    const int chunk = (ks*4 + lrow4) ^ (lane & 7);
    aoff[ks] = (wr*64 + lcol)*128 + chunk*16;
    boff[ks] = (wc*32 + lcol)*128 + chunk*16;
  }

  // precomputed staging base pointers: [isB][h][s]; dest offsets o_s constant
  const int o0 = tid << 4, o1 = (tid + 512) << 4;
  const int row0 = o0 >> 7, c0 = (o0 >> 4) & 7;
  const int row1 = o1 >> 7, c1 = (o1 >> 4) & 7;
  const char* gbase[2][2][2];
  #pragma unroll
  for (int h = 0; h < 2; ++h) {
    gbase[0][h][0] = (const char*)(A  + (size_t)(m0 + h*128 + row0) * K) + ((c0 ^ (row0 & 7)) << 4);
    gbase[0][h][1] = (const char*)(A  + (size_t)(m0 + h*128 + row1) * K) + ((c1 ^ (row1 & 7)) << 4);
    gbase[1][h][0] = (const char*)(Bt + (size_t)(n0 + h*128 + row0) * K) + ((c0 ^ (row0 & 7)) << 4);
    gbase[1][h][1] = (const char*)(Bt + (size_t)(n0 + h*128 + row1) * K) + ((c1 ^ (row1 & 7)) << 4);
  }

  auto STAGE = [&](int isB, int h, int tt){
    const int rb = (tt < NT) ? ((tt & 1) * 65536 + isB * 32768 + h * 16384) : 131072;
    const size_t tb = (size_t)((tt < NT) ? tt : NT - 1) << 7;   // tile byte offset
    gload_lds16(gbase[isB][h][0] + tb, (char*)lds + rb + o0);
    gload_lds16(gbase[isB][h][1] + tb, (char*)lds + rb + o1);
  };

  f32x4 acc[8][4] = {};
  bf16x8 af[4][2], bv[2][2];

  STAGE(0, 0, 0);
  STAGE(1, 0, 0);
  STAGE(0, 1, 0);
  STAGE(1, 1, 0);
  STAGE(0, 0, 1);
  STAGE(1, 1, 1);
  STAGE(0, 1, 1);
  asm volatile("s_waitcnt vmcnt(6)" ::: "memory");
  BAR();

  for (int i = 0; i < NI; ++i) {
    const int T = 2*i;
    ph256<0, 0, 0, 1, -1>(lds, aoff, boff, af, bv, acc, [&]{ STAGE(1, 0, T+1); });
    ph256<0, 1, 0, 0, -1>(lds, aoff, boff, af, bv, acc, [&]{ STAGE(0, 0, T+2); });
    ph256<1, 1, 0, 1, -1>(lds, aoff, boff, af, bv, acc, [&]{});
    ph256<1, 0, 0, 0,  4>(lds, aoff, boff, af, bv, acc, [&]{ STAGE(1, 1, T+2); });
    ph256<0, 0, 1, 1, -1>(lds, aoff, boff, af, bv, acc, [&]{ STAGE(1, 0, T+2); });
    ph256<0, 1, 1, 0, -1>(lds, aoff, boff, af, bv, acc, [&]{ STAGE(0, 1, T+2); });
    ph256<1, 1, 1, 1, -1>(lds, aoff, boff, af, bv, acc, [&]{ STAGE(0, 0, T+3); });
    ph256<1, 0, 1, 0,  6>(lds, aoff, boff, af, bv, acc, [&]{ STAGE(1, 1, T+3); STAGE(0, 1, T+3); });
  }

  { size_t bp = (size_t)bias, ap = (size_t)add;
    asm volatile("" : "+v"(bp), "+v"(ap));
    bias = (const float*)bp; add = (const float*)ap; }

  #pragma unroll
  for (int mi = 0; mi < 8; ++mi) {
    const int gmb = m0 + (mi>>2)*128 + wr*64 + (mi&3)*16 + lrow4*4;
    #pragma unroll
    for (int ni = 0; ni < 4; ++ni) {
      const int gn = n0 + (ni>>1)*128 + wc*32 + (ni&1)*16 + lcol;
      const float bs = bias[gn];
      #pragma unroll
      for (int rr = 0; rr < 4; ++rr) {
        const int gm = gmb + rr;
        float v = acc[mi][ni][rr] + bs;
        if constexpr (EPI == 0) {
          const int which = gn >> 10, g = gn & 1023;
          const int b = gm >> 11, s = gm & 2047;
          const int h = g >> 6, d = g & 63;
          ((u16*)out)[(size_t)which * 8388608 + ((((size_t)((b << 4) + h) << 11) + s) << 6) + d] = f2bf(v);
        } else {
          const float y2 = 1.5957691216f * v + 0.0713548353f * v * v * v;
          const float e = __expf(y2);
          ((u16*)out)[(size_t)gm * N + gn] = f2bf(v - v / (1.f + e));
        }
      }
    }
  }
}

// ================= 128x256 4-phase bf16 GEMM (wide) ====
// EPI 1: proj  -> out bf16 = acc + bias + add(f32)
// EPI 3: ffn2  -> out f32  = acc + bias + add(bf16)
template<int QN, int LB, int RDA, int WAIT, typename F>
__device__ __forceinline__ void phW(const char* lds, const int (&aoff)[2], const int (&boff)[2],
    bf16x8 (&af)[4][2], bf16x8 (&bv)[2][2], f32x4 (&acc)[4][4], F&& stg){
  if constexpr (RDA) {
    const char* Ar = lds + LB*49152;
    #pragma unroll
    for (int fi = 0; fi < 4; ++fi)
      #pragma unroll
      for (int ks = 0; ks < 2; ++ks)
        af[fi][ks] = *(const bf16x8*)(Ar + fi*2048 + aoff[ks]);
  }
  {
    const char* Br = lds + LB*49152 + 16384 + QN*16384;
    #pragma unroll
    for (int fj = 0; fj < 2; ++fj)
      #pragma unroll
      for (int ks = 0; ks < 2; ++ks)
        bv[fj][ks] = *(const bf16x8*)(Br + fj*2048 + boff[ks]);
  }
  stg();
  BAR();
  asm volatile("s_waitcnt lgkmcnt(0)" ::: "memory");
  __builtin_amdgcn_sched_barrier(0);
  __builtin_amdgcn_s_setprio(1);
  #pragma unroll
  for (int fi = 0; fi < 4; ++fi)
    #pragma unroll
    for (int fj = 0; fj < 2; ++fj){
      acc[fi][QN*2+fj] = __builtin_amdgcn_mfma_f32_16x16x32_bf16(af[fi][0], bv[fj][0], acc[fi][QN*2+fj], 0, 0, 0);
      acc[fi][QN*2+fj] = __builtin_amdgcn_mfma_f32_16x16x32_bf16(af[fi][1], bv[fj][1], acc[fi][QN*2+fj], 0, 0, 0);
    }
  __builtin_amdgcn_s_setprio(0);
  if constexpr (WAIT >= 0)
    asm volatile("s_waitcnt vmcnt(%0)" :: "n"(WAIT) : "memory");
  BAR();
}

template<int EPI>
__global__ __launch_bounds__(512, 2) void gemmW(
    const u16* __restrict__ A, const u16* __restrict__ Bt,
    const float* __restrict__ bias, const void* __restrict__ add,
    void* __restrict__ out, int M, int N, int K)
{
  __shared__ char lds[106496];
  const int NT = K >> 6;
  const int NI = NT >> 1;
  const int nbx = N >> 8;
  const int nwg = gridDim.x, orig = blockIdx.x;
  const int q = nwg >> 3, r = nwg & 7, x = orig & 7;
  const int wg = (x < r ? x * (q + 1) : r * (q + 1) + (x - r) * q) + (orig >> 3);
  const int bx = wg % nbx, by = wg / nbx;
  const int m0 = by << 7, n0 = bx << 8;

  const int tid = threadIdx.x, wave = tid >> 6, lane = tid & 63;
  const int wr = wave >> 2, wc = wave & 3;
  const int lcol = lane & 15, lrow4 = lane >> 4;

  int aoff[2], boff[2];
  #pragma unroll
  for (int ks = 0; ks < 2; ++ks){
    const int chunk = (ks*4 + lrow4) ^ (lane & 7);
    aoff[ks] = (wr*64 + lcol)*128 + chunk*16;
    boff[ks] = (wc*32 + lcol)*128 + chunk*16;
  }

  // precomputed staging base pointers: kind 0=A@m0, 1=B@n0, 2=B@n0+128
  const int o0 = tid << 4, o1 = (tid + 512) << 4;
  const int row0 = o0 >> 7, c0 = (o0 >> 4) & 7;
  const int row1 = o1 >> 7, c1 = (o1 >> 4) & 7;
  const char* gbase[3][2];
  gbase[0][0] = (const char*)(A  + (size_t)(m0 + row0) * K) + ((c0 ^ (row0 & 7)) << 4);
  gbase[0][1] = (const char*)(A  + (size_t)(m0 + row1) * K) + ((c1 ^ (row1 & 7)) << 4);
  gbase[1][0] = (const char*)(Bt + (size_t)(n0 + row0) * K) + ((c0 ^ (row0 & 7)) << 4);
  gbase[1][1] = (const char*)(Bt + (size_t)(n0 + row1) * K) + ((c1 ^ (row1 & 7)) << 4);
  gbase[2][0] = (const char*)(Bt + (size_t)(n0 + 128 + row0) * K) + ((c0 ^ (row0 & 7)) << 4);
  gbase[2][1] = (const char*)(Bt + (size_t)(n0 + 128 + row1) * K) + ((c1 ^ (row1 & 7)) << 4);

  auto STAGE = [&](int kind, int tt){
    const int rb = (tt < NT) ? ((tt & 1) * 49152 + kind * 16384) : 98304;
    const size_t tb = (size_t)((tt < NT) ? tt : NT - 1) << 7;
    gload_lds16(gbase[kind][0] + tb, (char*)lds + rb + o0);
    gload_lds16(gbase[kind][1] + tb, (char*)lds + rb + o1);
  };

  f32x4 acc[4][4] = {};
  bf16x8 af[4][2], bv[2][2];

  STAGE(0, 0);
  STAGE(1, 0);
  STAGE(2, 0);
  STAGE(0, 1);
  STAGE(1, 1);
  asm volatile("s_waitcnt vmcnt(4)" ::: "memory");
  BAR();

  for (int i = 0; i < NI; ++i) {
    const int T = 2*i;
    phW<0, 0, 1, -1>(lds, aoff, boff, af, bv, acc, [&]{ STAGE(2, T+1); });
    phW<1, 0, 0,  4>(lds, aoff, boff, af, bv, acc, [&]{ STAGE(0, T+2); STAGE(1, T+2); });
    phW<0, 1, 1, -1>(lds, aoff, boff, af, bv, acc, [&]{ STAGE(2, T+2); });
    phW<1, 1, 0,  4>(lds, aoff, boff, af, bv, acc, [&]{ STAGE(0, T+3); STAGE(1, T+3); });
  }

  { size_t bp = (size_t)bias, ap = (size_t)add;
    asm volatile("" : "+v"(bp), "+v"(ap));
    bias = (const float*)bp; add = (const void*)ap; }

  #pragma unroll
  for (int fi = 0; fi < 4; ++fi) {
    const int gmb = m0 + wr*64 + fi*16 + lrow4*4;
    #pragma unroll
    for (int j = 0; j < 4; ++j) {
      const int gn = n0 + (j>>1)*128 + wc*32 + (j&1)*16 + lcol;
      const float bs = bias[gn];
      #pragma unroll
      for (int rr = 0; rr < 4; ++rr) {
        const int gm = gmb + rr;
        float v = acc[fi][j][rr] + bs;
        if constexpr (EPI == 1) {
          ((u16*)out)[(size_t)gm * N + gn] = f2bf(v + ((const float*)add)[(size_t)gm * N + gn]);
        } else {
          ((float*)out)[(size_t)gm * N + gn] = v + bf2f(((const u16*)add)[(size_t)gm * N + gn]);
        }
      }
    }
  }
}

// ================= windowed attention: quarter-split + K in LDS, 512 threads ==
// (r19, unchanged: 512 blocks x 512 thr, (512,1), K 64KB + V^T 64KB LDS)
template<int NJ>  // NJ = W/16 (24 or 32)
__device__ void attn_core(const u16* __restrict__ Qp, u16* __restrict__ ctxP,
    const char* ktb, const char* vtb, int start, int widx, int bh)
{
  const int tid = threadIdx.x, wave = tid >> 6, lane = tid & 63;
  const int q = lane & 15, g = lane >> 4;
  constexpr int QTR = NJ / 4;
  const float scale = 0.125f;  // 64^-0.5
  const int b = bh >> 4, h = bh & 15;
  const int sw0 = ((g ^ (q & 7)) << 4);
  const int sw1 = (((4 | g) ^ (q & 7)) << 4);

  for (int qt = wave; qt < NJ; qt += 8) {
    const int q0 = qt * 16;
    const bf16x8 bq0 = *(const bf16x8*)(Qp + (q0 + q) * 64 + g * 8);
    const bf16x8 bq1 = *(const bf16x8*)(Qp + (q0 + q) * 64 + 32 + g * 8);
    float m = -3.0e38f, l = 0.f;
    f32x4 o[4] = {};
    const int s0 = ((g & 1) << 5) + q;
    const int s1 = s0 + 16;
    const bool lowj = (g < 2);

    #pragma unroll
    for (int hh = 0; hh < 4; ++hh) {
      f32x4 acc[QTR];
      #pragma unroll
      for (int j = 0; j < QTR; ++j) {
        const int jj = hh * QTR + j;
        const char* kr = ktb + (jj*16 + q) * 128;
        bf16x8 k0 = *(const bf16x8*)(kr + sw0);
        bf16x8 k1 = *(const bf16x8*)(kr + sw1);
        f32x4 t = {};
        t = __builtin_amdgcn_mfma_f32_16x16x32_bf16(k0, bq0, t, 0, 0, 0);
        t = __builtin_amdgcn_mfma_f32_16x16x32_bf16(k1, bq1, t, 0, 0, 0);
        acc[j] = t;
        if ((j & 3) == 3) __builtin_amdgcn_sched_barrier(0);  // cap read hoisting
      }
      float mh = -3.0e38f;
      #pragma unroll
      for (int j = 0; j < QTR; ++j)
        #pragma unroll
        for (int r = 0; r < 4; ++r) mh = fmaxf(mh, acc[j][r]);
      mh = fmaxf(mh, __shfl_xor(mh, 16, 64));
      mh = fmaxf(mh, __shfl_xor(mh, 32, 64));
      const float mn = fmaxf(m, mh);
      const float fr = __expf((m - mn) * scale);
      m = mn;
      l *= fr;
      #pragma unroll
      for (int df = 0; df < 4; ++df)
        #pragma unroll
        for (int r = 0; r < 4; ++r) o[df][r] *= fr;
      #pragma unroll
      for (int j = 0; j < QTR; ++j)
        #pragma unroll
        for (int r = 0; r < 4; ++r) {
          float e = __expf((acc[j][r] - mn) * scale);
          acc[j][r] = e;
          l += e;
        }
      #pragma unroll
      for (int c = 0; c < QTR / 2; ++c) {
        const u32 a0 = pack2(acc[2*c][0],   acc[2*c][1]);
        const u32 b0 = pack2(acc[2*c][2],   acc[2*c][3]);
        const u32 a1 = pack2(acc[2*c+1][0], acc[2*c+1][1]);
        const u32 b1 = pack2(acc[2*c+1][2], acc[2*c+1][3]);
        const u32 A0l = __shfl(a0, s0, 64), A1l = __shfl(a1, s0, 64);
        const u32 B0l = __shfl(b0, s0, 64), B1l = __shfl(b1, s0, 64);
        const u32 A0h = __shfl(a0, s1, 64), A1h = __shfl(a1, s1, 64);
        const u32 B0h = __shfl(b0, s1, 64), B1h = __shfl(b1, s1, 64);
        union { u32 u[4]; bf16x8 v; } pf;
        pf.u[0] = lowj ? A0l : A1l;
        pf.u[1] = lowj ? B0l : B1l;
        pf.u[2] = lowj ? A0h : A1h;
        pf.u[3] = lowj ? B0h : B1h;
        const int cg = hh * (QTR / 2) + c;
        #pragma unroll
        for (int df = 0; df < 4; ++df) {
          bf16x8 pv = *(const bf16x8*)(vtb + swz(df*16 + q, (cg*32 + g*8) * 2));
          o[df] = __builtin_amdgcn_mfma_f32_16x16x32_bf16(pv, pf.v, o[df], 0, 0, 0);
        }
        if ((c & 1) == 1) __builtin_amdgcn_sched_barrier(0);
      }
    }
    l += __shfl_xor(l, 16, 64);
    l += __shfl_xor(l, 32, 64);
    const float rs = 1.f / l;

    const int p = start + q0 + q;
    const int rel = p - (widx * 256 - 128);
    const float wgt = (rel < 256) ? ((widx == 0) ? 1.f : (float)rel * (1.f / 255.f))
                                  : ((widx == 7) ? 1.f : (1.f - (float)(rel - 256) * (1.f / 255.f)));
    const float rw = rs * wgt;
    u32 w0[4], w1[4];
    #pragma unroll
    for (int df = 0; df < 4; ++df) {
      w0[df] = pack2(o[df][0] * rw, o[df][1] * rw);
      w1[df] = pack2(o[df][2] * rw, o[df][3] * rw);
    }
    u32 W8[8] = {};
    #pragma unroll
    for (int df = 0; df < 4; ++df)
      #pragma unroll
      for (int sg = 0; sg < 4; ++sg) {
        const u32 t0 = __shfl(w0[df], sg*16 + q, 64);
        const u32 t1 = __shfl(w1[df], sg*16 + q, 64);
        if (g == df) { W8[2*sg] = t0; W8[2*sg+1] = t1; }
      }
    u16* dst = ctxP + ((((size_t)(b << 11) + (size_t)p) << 10) + (h << 6) + (g << 4));
    u32x4 lo = { W8[0], W8[1], W8[2], W8[3] };
    u32x4 hi = { W8[4], W8[5], W8[6], W8[7] };
    *(u32x4*)dst = lo;
    *(u32x4*)(dst + 8) = hi;
  }
}

__global__ __launch_bounds__(512, 1) void attn_kernel(const u16* __restrict__ qg, const u16* __restrict__ kg,
    const u16* __restrict__ vg, u16* __restrict__ ctxE, u16* __restrict__ ctxO){
  __shared__ char lds[131072];   // K @0 (64KB), V^T @65536 (64KB) -> 1 block/CU
  const int widx = (int)blockIdx.x >> 6;
  const int bh = blockIdx.x & 63;
  const int i0 = widx << 8;
  int start = i0 - 128; if (start < 0) start = 0;
  int end = i0 + 384;   if (end > 2048) end = 2048;
  const int W = end - start;
  const int tid = threadIdx.x;
  const u16* Qp = qg + (((size_t)bh << 11) + start) * 64;
  const u16* Kp = kg + (((size_t)bh << 11) + start) * 64;
  const u16* Vp = vg + (((size_t)bh << 11) + start) * 64;
  // stage K: rows of 128B; LDS chunk c holds global chunk c ^ (row&7) (rule #21)
  const int nks = W >> 6;             // W*8 16B-chunks / 512 threads
  for (int s = 0; s < nks; ++s) {
    const int o = (tid + s*512) << 4;
    const int row = o >> 7, c = (o >> 4) & 7;
    const char* src = (const char*)(Kp + (size_t)row * 64) + ((c ^ (row & 7)) << 4);
    gload_lds16(src, (char*)lds + o);
  }
  // stage V^T (scalar transpose; r17 swizzle; key = idx%W spreads write banks)
  char* vtb = (char*)lds + 65536;
  for (int idx = tid; idx < W * 8; idx += 512) {
    const int key = idx % W, d0 = (idx / W) << 3;
    u16x8 vv = *(const u16x8*)(Vp + key * 64 + d0);
    #pragma unroll
    for (int z = 0; z < 8; ++z)
      *(u16*)(vtb + swz(d0 + z, key * 2)) = vv[z];
  }
  __syncthreads();
  u16* ctxP = (widx & 1) ? ctxO : ctxE;
  if (W == 512) attn_core<32>(Qp, ctxP, (const char*)lds, vtb, start, widx, bh);
  else          attn_core<24>(Qp, ctxP, (const char*)lds, vtb, start, widx, bh);
}

// merge parity buffers: p<128 -> E; p>=1920 -> O; else E+O. In-place on E is safe.
__global__ __launch_bounds__(256) void merge_kernel(const u16* __restrict__ e,
    const u16* __restrict__ o, u16* __restrict__ out){
  const int i = blockIdx.x * 256 + threadIdx.x;     // u16x8 index
  const int p = (i >> 7) & 2047;                    // (i*8 >> 10) & 2047
  u16x8 ev = ((const u16x8*)e)[i];
  u16x8 ov = ((const u16x8*)o)[i];
  u16x8 r;
  if (p < 128)        r = ev;
  else if (p >= 1920) r = ov;
  else {
    #pragma unroll
    for (int z = 0; z < 8; ++z) r[z] = f2bf(bf2f(ev[z]) + bf2f(ov[z]));
  }
  ((u16x8*)out)[i] = r;
}

// ---------------- host
extern "C" void kernel_launch(void* const* d_in, const int* in_sizes, int n_in,
                              void* d_out, int out_size, void* d_ws, size_t ws_size,
                              hipStream_t stream) {
  const float* hidden = (const float*)d_in[0];
  const float* ln1_g  = (const float*)d_in[1];
  const float* ln1_b  = (const float*)d_in[2];
  const float* wq     = (const float*)d_in[3];
  const float* bq     = (const float*)d_in[4];
  const float* wk     = (const float*)d_in[5];
  const float* bk     = (const float*)d_in[6];
  const float* wv     = (const float*)d_in[7];
  const float* bv     = (const float*)d_in[8];
  const float* wproj  = (const float*)d_in[9];
  const float* bproj  = (const float*)d_in[10];
  const float* ln2_g  = (const float*)d_in[11];
  const float* ln2_b  = (const float*)d_in[12];
  const float* w1     = (const float*)d_in[13];
  const float* b1     = (const float*)d_in[14];
  const float* w2     = (const float*)d_in[15];
  const float* b2     = (const float*)d_in[16];

  char* ws = (char*)d_ws;
  u16* xb    = (u16*)(ws + 0);            // 16 MiB (LN1/LN2 out; ctxO during attn)
  u16* wqkvT = (u16*)(ws + 16777216);     // 6 MiB [3072][1024]
  u16* wpT   = (u16*)(ws + 23068672);     // 2 MiB
  u16* w1T   = (u16*)(ws + 25165824);     // 8 MiB
  u16* w2T   = (u16*)(ws + 33554432);     // 8 MiB
  u16* qb    = (u16*)(ws + 41943040);     // q,k,v contiguous: 3 x 16 MiB
  u16* kb    = (u16*)(ws + 58720256);
  u16* vb    = (u16*)(ws + 75497472);
  u16* ctxE  = (u16*)(ws + 92274688);     // 16 MiB (merged ctx in-place)
  u16* ctxO  = (u16*)(ws + 0);            // aliases xb (dead between qkv and ln2)
  float* bqkv = (float*)(ws + 92274688);  // aliases ctxE start (dead before attn)
  u16* res2  = (u16*)(ws + 109051904);    // 16 MiB bf16
  u16* mid   = (u16*)(ws + 41943040);     // 64 MiB, reuses qb..ctx

  dim3 tb(32, 8);
  transpose_cvt<<<dim3(32, 32), tb, 0, stream>>>(wq, wqkvT, 1024, 1024);
  transpose_cvt<<<dim3(32, 32), tb, 0, stream>>>(wk, wqkvT + 1048576, 1024, 1024);
  transpose_cvt<<<dim3(32, 32), tb, 0, stream>>>(wv, wqkvT + 2097152, 1024, 1024);
  transpose_cvt<<<dim3(32, 32), tb, 0, stream>>>(wproj, wpT, 1024, 1024);
  transpose_cvt<<<dim3(128, 32), tb, 0, stream>>>(w1, w1T, 1024, 4096);
  transpose_cvt<<<dim3(32, 128), tb, 0, stream>>>(w2, w2T, 4096, 1024);
  concat3<<<12, 256, 0, stream>>>(bq, bk, bv, bqkv);

  ln_kernel<0><<<8192, 256, 0, stream>>>(hidden, ln1_g, ln1_b, xb);

  gemm8<0><<<384, 512, 0, stream>>>(xb, wqkvT, bqkv, nullptr, qb, 8192, 3072, 1024);

  attn_kernel<<<512, 512, 0, stream>>>(qb, kb, vb, ctxE, ctxO);
  merge_kernel<<<4096, 256, 0, stream>>>(ctxE, ctxO, ctxE);

  gemmW<1><<<256, 512, 0, stream>>>(ctxE, wpT, bproj, hidden, res2, 8192, 1024, 1024);

  ln_kernel<1><<<8192, 256, 0, stream>>>(res2, ln2_g, ln2_b, xb);

  gemm8<2><<<512, 512, 0, stream>>>(xb, w1T, b1, nullptr, mid, 8192, 4096, 1024);
  gemmW<3><<<256, 512, 0, stream>>>(mid, w2T, b2, res2, (float*)d_out, 8192, 1024, 4096);
}

// Round 21
// 374.764 us; speedup vs baseline: 1.1381x; 1.0127x over previous
//
#include <hip/hip_runtime.h>
#include <math.h>

typedef unsigned short u16;
typedef unsigned int u32;
typedef __attribute__((ext_vector_type(8))) short bf16x8;
typedef __attribute__((ext_vector_type(8))) unsigned short u16x8;
typedef __attribute__((ext_vector_type(4))) float f32x4;
typedef __attribute__((ext_vector_type(4))) unsigned int u32x4;

__device__ __forceinline__ u16 f2bf(float f){
  union { float f; unsigned u; } c; c.f = f;
  unsigned u = c.u;
  return (u16)((u + 0x7fffu + ((u >> 16) & 1u)) >> 16);
}
__device__ __forceinline__ float bf2f(u16 h){
  union { unsigned u; float f; } c; c.u = ((unsigned)h) << 16;
  return c.f;
}
__device__ __forceinline__ u32 pack2(float lo, float hi){
  return (u32)f2bf(lo) | ((u32)f2bf(hi) << 16);
}
// single-instruction packed f32->bf16 (RNE), gfx950 has no builtin (T12/m240)
__device__ __forceinline__ u32 pack2cvt(float lo, float hi){
  u32 r;
  asm("v_cvt_pk_bf16_f32 %0, %1, %2" : "=v"(r) : "v"(lo), "v"(hi));
  return r;
}
__device__ __forceinline__ void gload_lds16(const void* g, void* l){
  __builtin_amdgcn_global_load_lds((const __attribute__((address_space(1))) void*)g,
                                   (__attribute__((address_space(3))) void*)l, 16, 0, 0);
}
// attention V^T swizzle (r17): XOR row bits into chunk bits (byte bits 6-9).
__device__ __forceinline__ int swz(int row, int bc){
  return (row << 10) + (bc ^ ((row & 15) << 6));
}

#define BAR() asm volatile("s_barrier" ::: "memory")

// ---------------- weight transpose + f32->bf16 : in [K][N] f32 -> out [N][K] bf16
__global__ void transpose_cvt(const float* __restrict__ in, u16* __restrict__ out, int K, int N){
  __shared__ float tile[32][33];
  int n0 = blockIdx.x << 5, k0 = blockIdx.y << 5;
  int tx = threadIdx.x, ty = threadIdx.y;
  #pragma unroll
  for (int r = 0; r < 32; r += 8)
    tile[ty + r][tx] = in[(size_t)(k0 + ty + r) * N + n0 + tx];
  __syncthreads();
  #pragma unroll
  for (int r = 0; r < 32; r += 8)
    out[(size_t)(n0 + ty + r) * K + k0 + tx] = f2bf(tile[tx][ty + r]);
}

__global__ void concat3(const float* __restrict__ a, const float* __restrict__ b,
                        const float* __restrict__ c, float* __restrict__ o){
  int i = blockIdx.x * 256 + threadIdx.x;
  o[i] = i < 1024 ? a[i] : (i < 2048 ? b[i - 1024] : c[i - 2048]);
}

// ---------------- layernorm: [rows][1024] (f32 or bf16 in) -> bf16 out
__device__ __forceinline__ float blockReduce(float v, float* ws){
  #pragma unroll
  for (int m = 1; m < 64; m <<= 1) v += __shfl_xor(v, m, 64);
  int w = threadIdx.x >> 6;
  __syncthreads();
  if ((threadIdx.x & 63) == 0) ws[w] = v;
  __syncthreads();
  return ws[0] + ws[1] + ws[2] + ws[3];
}

struct U16x4 { u16 x, y, z, w; };

template<int BF16IN>
__global__ __launch_bounds__(256) void ln_kernel(const void* __restrict__ in_, const float* __restrict__ g,
    const float* __restrict__ be, u16* __restrict__ out){
  __shared__ float ws[4];
  int row = blockIdx.x;
  float vx, vy, vz, vw;
  if constexpr (BF16IN) {
    const U16x4 v = ((const U16x4*)((const u16*)in_ + ((size_t)row << 10)))[threadIdx.x];
    vx = bf2f(v.x); vy = bf2f(v.y); vz = bf2f(v.z); vw = bf2f(v.w);
  } else {
    const float4 v = ((const float4*)((const float*)in_ + ((size_t)row << 10)))[threadIdx.x];
    vx = v.x; vy = v.y; vz = v.z; vw = v.w;
  }
  float s = vx + vy + vz + vw;
  s = blockReduce(s, ws);
  float mean = s * (1.f / 1024.f);
  float dx = vx - mean, dy = vy - mean, dz = vz - mean, dw = vw - mean;
  float s2 = dx*dx + dy*dy + dz*dz + dw*dw;
  s2 = blockReduce(s2, ws);
  float rstd = rsqrtf(s2 * (1.f / 1024.f) + 1e-5f);
  float4 gv = ((const float4*)g)[threadIdx.x];
  float4 bv = ((const float4*)be)[threadIdx.x];
  U16x4 ov;
  ov.x = f2bf(dx * rstd * gv.x + bv.x);
  ov.y = f2bf(dy * rstd * gv.y + bv.y);
  ov.z = f2bf(dz * rstd * gv.z + bv.z);
  ov.w = f2bf(dw * rstd * gv.w + bv.w);
  ((U16x4*)(out + ((size_t)row << 10)))[threadIdx.x] = ov;
}

// ================= 256x256 8-phase bf16 GEMM =========
template<int QM, int QN, int LB, int RDA, int WAIT, typename F>
__device__ __forceinline__ void ph256(const char* lds, const int (&aoff)[2], const int (&boff)[2],
    bf16x8 (&af)[4][2], bf16x8 (&bv)[2][2], f32x4 (&acc)[8][4], F&& stg){
  if constexpr (RDA) {
    const char* Ar = lds + LB*65536 + QM*16384;
    #pragma unroll
    for (int fi = 0; fi < 4; ++fi)
      #pragma unroll
      for (int ks = 0; ks < 2; ++ks)
        af[fi][ks] = *(const bf16x8*)(Ar + fi*2048 + aoff[ks]);
  }
  {
    const char* Br = lds + LB*65536 + 32768 + QN*16384;
    #pragma unroll
    for (int fj = 0; fj < 2; ++fj)
      #pragma unroll
      for (int ks = 0; ks < 2; ++ks)
        bv[fj][ks] = *(const bf16x8*)(Br + fj*2048 + boff[ks]);
  }
  stg();
  BAR();
  asm volatile("s_waitcnt lgkmcnt(0)" ::: "memory");
  __builtin_amdgcn_sched_barrier(0);
  __builtin_amdgcn_s_setprio(1);
  #pragma unroll
  for (int fi = 0; fi < 4; ++fi)
    #pragma unroll
    for (int fj = 0; fj < 2; ++fj){
      acc[QM*4+fi][QN*2+fj] = __builtin_amdgcn_mfma_f32_16x16x32_bf16(af[fi][0], bv[fj][0], acc[QM*4+fi][QN*2+fj], 0, 0, 0);
      acc[QM*4+fi][QN*2+fj] = __builtin_amdgcn_mfma_f32_16x16x32_bf16(af[fi][1], bv[fj][1], acc[QM*4+fi][QN*2+fj], 0, 0, 0);
    }
  __builtin_amdgcn_s_setprio(0);
  if constexpr (WAIT >= 0)
    asm volatile("s_waitcnt vmcnt(%0)" :: "n"(WAIT) : "memory");
  BAR();
}

// EPI 0: bf16 scatter to q/k/v [3][B*NH, S, HD] (+bias)
// EPI 2: bf16 = gelu(acc + bias)   [tanh-form sigmoid approx]
// Staging addresses hoisted: base pointers [mat-half][s] + tt*128B per tile.
template<int EPI>
__global__ __launch_bounds__(512, 2) void gemm8(
    const u16* __restrict__ A, const u16* __restrict__ Bt,
    const float* __restrict__ bias, const float* __restrict__ add,
    void* __restrict__ out, int M, int N, int K)
{
  __shared__ char lds[147456];
  const int NT = K >> 6;
  const int NI = NT >> 1;
  const int nbx = N >> 8;
  const int nwg = gridDim.x, orig = blockIdx.x;
  const int q = nwg >> 3, r = nwg & 7, x = orig & 7;
  const int wg = (x < r ? x * (q + 1) : r * (q + 1) + (x - r) * q) + (orig >> 3);
  const int bx = wg % nbx, by = wg / nbx;
  const int m0 = by << 8, n0 = bx << 8;

  const int tid = threadIdx.x, wave = tid >> 6, lane = tid & 63;
  const int wr = (wave >> 2) & 1, wc = wave & 3;
  const int lcol = lane & 15, lrow4 = lane >> 4;

  int aoff[2], boff[2];
  #pragma unroll
  for (int ks = 0; ks < 2; ++ks){
    const int chunk = (ks*4 + lrow4) ^ (lane & 7);
    aoff[ks] = (wr*64 + lcol)*128 + chunk*16;
    boff[ks] = (wc*32 + lcol)*128 + chunk*16;
  }

  // precomputed staging base pointers: [isB][h][s]; dest offsets o_s constant
  const int o0 = tid << 4, o1 = (tid + 512) << 4;
  const int row0 = o0 >> 7, c0 = (o0 >> 4) & 7;
  const int row1 = o1 >> 7, c1 = (o1 >> 4) & 7;
  const char* gbase[2][2][2];
  #pragma unroll
  for (int h = 0; h < 2; ++h) {
    gbase[0][h][0] = (const char*)(A  + (size_t)(m0 + h*128 + row0) * K) + ((c0 ^ (row0 & 7)) << 4);
    gbase[0][h][1] = (const char*)(A  + (size_t)(m0 + h*128 + row1) * K) + ((c1 ^ (row1 & 7)) << 4);
    gbase[1][h][0] = (const char*)(Bt + (size_t)(n0 + h*128 + row0) * K) + ((c0 ^ (row0 & 7)) << 4);
    gbase[1][h][1] = (const char*)(Bt + (size_t)(n0 + h*128 + row1) * K) + ((c1 ^ (row1 & 7)) << 4);
  }

  auto STAGE = [&](int isB, int h, int tt){
    const int rb = (tt < NT) ? ((tt & 1) * 65536 + isB * 32768 + h * 16384) : 131072;
    const size_t tb = (size_t)((tt < NT) ? tt : NT - 1) << 7;   // tile byte offset
    gload_lds16(gbase[isB][h][0] + tb, (char*)lds + rb + o0);
    gload_lds16(gbase[isB][h][1] + tb, (char*)lds + rb + o1);
  };

  f32x4 acc[8][4] = {};
  bf16x8 af[4][2], bv[2][2];

  STAGE(0, 0, 0);
  STAGE(1, 0, 0);
  STAGE(0, 1, 0);
  STAGE(1, 1, 0);
  STAGE(0, 0, 1);
  STAGE(1, 1, 1);
  STAGE(0, 1, 1);
  asm volatile("s_waitcnt vmcnt(6)" ::: "memory");
  BAR();

  for (int i = 0; i < NI; ++i) {
    const int T = 2*i;
    ph256<0, 0, 0, 1, -1>(lds, aoff, boff, af, bv, acc, [&]{ STAGE(1, 0, T+1); });
    ph256<0, 1, 0, 0, -1>(lds, aoff, boff, af, bv, acc, [&]{ STAGE(0, 0, T+2); });
    ph256<1, 1, 0, 1, -1>(lds, aoff, boff, af, bv, acc, [&]{});
    ph256<1, 0, 0, 0,  4>(lds, aoff, boff, af, bv, acc, [&]{ STAGE(1, 1, T+2); });
    ph256<0, 0, 1, 1, -1>(lds, aoff, boff, af, bv, acc, [&]{ STAGE(1, 0, T+2); });
    ph256<0, 1, 1, 0, -1>(lds, aoff, boff, af, bv, acc, [&]{ STAGE(0, 1, T+2); });
    ph256<1, 1, 1, 1, -1>(lds, aoff, boff, af, bv, acc, [&]{ STAGE(0, 0, T+3); });
    ph256<1, 0, 1, 0,  6>(lds, aoff, boff, af, bv, acc, [&]{ STAGE(1, 1, T+3); STAGE(0, 1, T+3); });
  }

  { size_t bp = (size_t)bias, ap = (size_t)add;
    asm volatile("" : "+v"(bp), "+v"(ap));
    bias = (const float*)bp; add = (const float*)ap; }

  #pragma unroll
  for (int mi = 0; mi < 8; ++mi) {
    const int gmb = m0 + (mi>>2)*128 + wr*64 + (mi&3)*16 + lrow4*4;
    #pragma unroll
    for (int ni = 0; ni < 4; ++ni) {
      const int gn = n0 + (ni>>1)*128 + wc*32 + (ni&1)*16 + lcol;
      const float bs = bias[gn];
      #pragma unroll
      for (int rr = 0; rr < 4; ++rr) {
        const int gm = gmb + rr;
        float v = acc[mi][ni][rr] + bs;
        if constexpr (EPI == 0) {
          const int which = gn >> 10, g = gn & 1023;
          const int b = gm >> 11, s = gm & 2047;
          const int h = g >> 6, d = g & 63;
          ((u16*)out)[(size_t)which * 8388608 + ((((size_t)((b << 4) + h) << 11) + s) << 6) + d] = f2bf(v);
        } else {
          const float y2 = 1.5957691216f * v + 0.0713548353f * v * v * v;
          const float e = __expf(y2);
          ((u16*)out)[(size_t)gm * N + gn] = f2bf(v - v / (1.f + e));
        }
      }
    }
  }
}

// ================= 128x256 4-phase bf16 GEMM (wide) ====
// EPI 1: proj  -> out bf16 = acc + bias + add(f32)
// EPI 3: ffn2  -> out f32  = acc + bias + add(bf16)
template<int QN, int LB, int RDA, int WAIT, typename F>
__device__ __forceinline__ void phW(const char* lds, const int (&aoff)[2], const int (&boff)[2],
    bf16x8 (&af)[4][2], bf16x8 (&bv)[2][2], f32x4 (&acc)[4][4], F&& stg){
  if constexpr (RDA) {
    const char* Ar = lds + LB*49152;
    #pragma unroll
    for (int fi = 0; fi < 4; ++fi)
      #pragma unroll
      for (int ks = 0; ks < 2; ++ks)
        af[fi][ks] = *(const bf16x8*)(Ar + fi*2048 + aoff[ks]);
  }
  {
    const char* Br = lds + LB*49152 + 16384 + QN*16384;
    #pragma unroll
    for (int fj = 0; fj < 2; ++fj)
      #pragma unroll
      for (int ks = 0; ks < 2; ++ks)
        bv[fj][ks] = *(const bf16x8*)(Br + fj*2048 + boff[ks]);
  }
  stg();
  BAR();
  asm volatile("s_waitcnt lgkmcnt(0)" ::: "memory");
  __builtin_amdgcn_sched_barrier(0);
  __builtin_amdgcn_s_setprio(1);
  #pragma unroll
  for (int fi = 0; fi < 4; ++fi)
    #pragma unroll
    for (int fj = 0; fj < 2; ++fj){
      acc[fi][QN*2+fj] = __builtin_amdgcn_mfma_f32_16x16x32_bf16(af[fi][0], bv[fj][0], acc[fi][QN*2+fj], 0, 0, 0);
      acc[fi][QN*2+fj] = __builtin_amdgcn_mfma_f32_16x16x32_bf16(af[fi][1], bv[fj][1], acc[fi][QN*2+fj], 0, 0, 0);
    }
  __builtin_amdgcn_s_setprio(0);
  if constexpr (WAIT >= 0)
    asm volatile("s_waitcnt vmcnt(%0)" :: "n"(WAIT) : "memory");
  BAR();
}

template<int EPI>
__global__ __launch_bounds__(512, 2) void gemmW(
    const u16* __restrict__ A, const u16* __restrict__ Bt,
    const float* __restrict__ bias, const void* __restrict__ add,
    void* __restrict__ out, int M, int N, int K)
{
  __shared__ char lds[106496];
  const int NT = K >> 6;
  const int NI = NT >> 1;
  const int nbx = N >> 8;
  const int nwg = gridDim.x, orig = blockIdx.x;
  const int q = nwg >> 3, r = nwg & 7, x = orig & 7;
  const int wg = (x < r ? x * (q + 1) : r * (q + 1) + (x - r) * q) + (orig >> 3);
  const int bx = wg % nbx, by = wg / nbx;
  const int m0 = by << 7, n0 = bx << 8;

  const int tid = threadIdx.x, wave = tid >> 6, lane = tid & 63;
  const int wr = wave >> 2, wc = wave & 3;
  const int lcol = lane & 15, lrow4 = lane >> 4;

  int aoff[2], boff[2];
  #pragma unroll
  for (int ks = 0; ks < 2; ++ks){
    const int chunk = (ks*4 + lrow4) ^ (lane & 7);
    aoff[ks] = (wr*64 + lcol)*128 + chunk*16;
    boff[ks] = (wc*32 + lcol)*128 + chunk*16;
  }

  // precomputed staging base pointers: kind 0=A@m0, 1=B@n0, 2=B@n0+128
  const int o0 = tid << 4, o1 = (tid + 512) << 4;
  const int row0 = o0 >> 7, c0 = (o0 >> 4) & 7;
  const int row1 = o1 >> 7, c1 = (o1 >> 4) & 7;
  const char* gbase[3][2];
  gbase[0][0] = (const char*)(A  + (size_t)(m0 + row0) * K) + ((c0 ^ (row0 & 7)) << 4);
  gbase[0][1] = (const char*)(A  + (size_t)(m0 + row1) * K) + ((c1 ^ (row1 & 7)) << 4);
  gbase[1][0] = (const char*)(Bt + (size_t)(n0 + row0) * K) + ((c0 ^ (row0 & 7)) << 4);
  gbase[1][1] = (const char*)(Bt + (size_t)(n0 + row1) * K) + ((c1 ^ (row1 & 7)) << 4);
  gbase[2][0] = (const char*)(Bt + (size_t)(n0 + 128 + row0) * K) + ((c0 ^ (row0 & 7)) << 4);
  gbase[2][1] = (const char*)(Bt + (size_t)(n0 + 128 + row1) * K) + ((c1 ^ (row1 & 7)) << 4);

  auto STAGE = [&](int kind, int tt){
    const int rb = (tt < NT) ? ((tt & 1) * 49152 + kind * 16384) : 98304;
    const size_t tb = (size_t)((tt < NT) ? tt : NT - 1) << 7;
    gload_lds16(gbase[kind][0] + tb, (char*)lds + rb + o0);
    gload_lds16(gbase[kind][1] + tb, (char*)lds + rb + o1);
  };

  f32x4 acc[4][4] = {};
  bf16x8 af[4][2], bv[2][2];

  STAGE(0, 0);
  STAGE(1, 0);
  STAGE(2, 0);
  STAGE(0, 1);
  STAGE(1, 1);
  asm volatile("s_waitcnt vmcnt(4)" ::: "memory");
  BAR();

  for (int i = 0; i < NI; ++i) {
    const int T = 2*i;
    phW<0, 0, 1, -1>(lds, aoff, boff, af, bv, acc, [&]{ STAGE(2, T+1); });
    phW<1, 0, 0,  4>(lds, aoff, boff, af, bv, acc, [&]{ STAGE(0, T+2); STAGE(1, T+2); });
    phW<0, 1, 1, -1>(lds, aoff, boff, af, bv, acc, [&]{ STAGE(2, T+2); });
    phW<1, 1, 0,  4>(lds, aoff, boff, af, bv, acc, [&]{ STAGE(0, T+3); STAGE(1, T+3); });
  }

  { size_t bp = (size_t)bias, ap = (size_t)add;
    asm volatile("" : "+v"(bp), "+v"(ap));
    bias = (const float*)bp; add = (const void*)ap; }

  #pragma unroll
  for (int fi = 0; fi < 4; ++fi) {
    const int gmb = m0 + wr*64 + fi*16 + lrow4*4;
    #pragma unroll
    for (int j = 0; j < 4; ++j) {
      const int gn = n0 + (j>>1)*128 + wc*32 + (j&1)*16 + lcol;
      const float bs = bias[gn];
      #pragma unroll
      for (int rr = 0; rr < 4; ++rr) {
        const int gm = gmb + rr;
        float v = acc[fi][j][rr] + bs;
        if constexpr (EPI == 1) {
          ((u16*)out)[(size_t)gm * N + gn] = f2bf(v + ((const float*)add)[(size_t)gm * N + gn]);
        } else {
          ((float*)out)[(size_t)gm * N + gn] = v + bf2f(((const u16*)add)[(size_t)gm * N + gn]);
        }
      }
    }
  }
}

// ================= windowed attention: quarter-split + K in LDS, 512 threads ==
// (r19 structure; r21: pack2 -> v_cvt_pk_bf16_f32 single-instruction packs)
template<int NJ>  // NJ = W/16 (24 or 32)
__device__ void attn_core(const u16* __restrict__ Qp, u16* __restrict__ ctxP,
    const char* ktb, const char* vtb, int start, int widx, int bh)
{
  const int tid = threadIdx.x, wave = tid >> 6, lane = tid & 63;
  const int q = lane & 15, g = lane >> 4;
  constexpr int QTR = NJ / 4;
  const float scale = 0.125f;  // 64^-0.5
  const int b = bh >> 4, h = bh & 15;
  const int sw0 = ((g ^ (q & 7)) << 4);
  const int sw1 = (((4 | g) ^ (q & 7)) << 4);

  for (int qt = wave; qt < NJ; qt += 8) {
    const int q0 = qt * 16;
    const bf16x8 bq0 = *(const bf16x8*)(Qp + (q0 + q) * 64 + g * 8);
    const bf16x8 bq1 = *(const bf16x8*)(Qp + (q0 + q) * 64 + 32 + g * 8);
    float m = -3.0e38f, l = 0.f;
    f32x4 o[4] = {};
    const int s0 = ((g & 1) << 5) + q;
    const int s1 = s0 + 16;
    const bool lowj = (g < 2);

    #pragma unroll
    for (int hh = 0; hh < 4; ++hh) {
      f32x4 acc[QTR];
      #pragma unroll
      for (int j = 0; j < QTR; ++j) {
        const int jj = hh * QTR + j;
        const char* kr = ktb + (jj*16 + q) * 128;
        bf16x8 k0 = *(const bf16x8*)(kr + sw0);
        bf16x8 k1 = *(const bf16x8*)(kr + sw1);
        f32x4 t = {};
        t = __builtin_amdgcn_mfma_f32_16x16x32_bf16(k0, bq0, t, 0, 0, 0);
        t = __builtin_amdgcn_mfma_f32_16x16x32_bf16(k1, bq1, t, 0, 0, 0);
        acc[j] = t;
        if ((j & 3) == 3) __builtin_amdgcn_sched_barrier(0);  // cap read hoisting
      }
      float mh = -3.0e38f;
      #pragma unroll
      for (int j = 0; j < QTR; ++j)
        #pragma unroll
        for (int r = 0; r < 4; ++r) mh = fmaxf(mh, acc[j][r]);
      mh = fmaxf(mh, __shfl_xor(mh, 16, 64));
      mh = fmaxf(mh, __shfl_xor(mh, 32, 64));
      const float mn = fmaxf(m, mh);
      const float fr = __expf((m - mn) * scale);
      m = mn;
      l *= fr;
      #pragma unroll
      for (int df = 0; df < 4; ++df)
        #pragma unroll
        for (int r = 0; r < 4; ++r) o[df][r] *= fr;
      #pragma unroll
      for (int j = 0; j < QTR; ++j)
        #pragma unroll
        for (int r = 0; r < 4; ++r) {
          float e = __expf((acc[j][r] - mn) * scale);
          acc[j][r] = e;
          l += e;
        }
      #pragma unroll
      for (int c = 0; c < QTR / 2; ++c) {
        const u32 a0 = pack2cvt(acc[2*c][0],   acc[2*c][1]);
        const u32 b0 = pack2cvt(acc[2*c][2],   acc[2*c][3]);
        const u32 a1 = pack2cvt(acc[2*c+1][0], acc[2*c+1][1]);
        const u32 b1 = pack2cvt(acc[2*c+1][2], acc[2*c+1][3]);
        const u32 A0l = __shfl(a0, s0, 64), A1l = __shfl(a1, s0, 64);
        const u32 B0l = __shfl(b0, s0, 64), B1l = __shfl(b1, s0, 64);
        const u32 A0h = __shfl(a0, s1, 64), A1h = __shfl(a1, s1, 64);
        const u32 B0h = __shfl(b0, s1, 64), B1h = __shfl(b1, s1, 64);
        union { u32 u[4]; bf16x8 v; } pf;
        pf.u[0] = lowj ? A0l : A1l;
        pf.u[1] = lowj ? B0l : B1l;
        pf.u[2] = lowj ? A0h : A1h;
        pf.u[3] = lowj ? B0h : B1h;
        const int cg = hh * (QTR / 2) + c;
        #pragma unroll
        for (int df = 0; df < 4; ++df) {
          bf16x8 pv = *(const bf16x8*)(vtb + swz(df*16 + q, (cg*32 + g*8) * 2));
          o[df] = __builtin_amdgcn_mfma_f32_16x16x32_bf16(pv, pf.v, o[df], 0, 0, 0);
        }
        if ((c & 1) == 1) __builtin_amdgcn_sched_barrier(0);
      }
    }
    l += __shfl_xor(l, 16, 64);
    l += __shfl_xor(l, 32, 64);
    const float rs = 1.f / l;

    const int p = start + q0 + q;
    const int rel = p - (widx * 256 - 128);
    const float wgt = (rel < 256) ? ((widx == 0) ? 1.f : (float)rel * (1.f / 255.f))
                                  : ((widx == 7) ? 1.f : (1.f - (float)(rel - 256) * (1.f / 255.f)));
    const float rw = rs * wgt;
    u32 w0[4], w1[4];
    #pragma unroll
    for (int df = 0; df < 4; ++df) {
      w0[df] = pack2cvt(o[df][0] * rw, o[df][1] * rw);
      w1[df] = pack2cvt(o[df][2] * rw, o[df][3] * rw);
    }
    u32 W8[8] = {};
    #pragma unroll
    for (int df = 0; df < 4; ++df)
      #pragma unroll
      for (int sg = 0; sg < 4; ++sg) {
        const u32 t0 = __shfl(w0[df], sg*16 + q, 64);
        const u32 t1 = __shfl(w1[df], sg*16 + q, 64);
        if (g == df) { W8[2*sg] = t0; W8[2*sg+1] = t1; }
      }
    u16* dst = ctxP + ((((size_t)(b << 11) + (size_t)p) << 10) + (h << 6) + (g << 4));
    u32x4 lo = { W8[0], W8[1], W8[2], W8[3] };
    u32x4 hi = { W8[4], W8[5], W8[6], W8[7] };
    *(u32x4*)dst = lo;
    *(u32x4*)(dst + 8) = hi;
  }
}

__global__ __launch_bounds__(512, 1) void attn_kernel(const u16* __restrict__ qg, const u16* __restrict__ kg,
    const u16* __restrict__ vg, u16* __restrict__ ctxE, u16* __restrict__ ctxO){
  __shared__ char lds[131072];   // K @0 (64KB), V^T @65536 (64KB) -> 1 block/CU
  const int widx = (int)blockIdx.x >> 6;
  const int bh = blockIdx.x & 63;
  const int i0 = widx << 8;
  int start = i0 - 128; if (start < 0) start = 0;
  int end = i0 + 384;   if (end > 2048) end = 2048;
  const int W = end - start;
  const int tid = threadIdx.x;
  const u16* Qp = qg + (((size_t)bh << 11) + start) * 64;
  const u16* Kp = kg + (((size_t)bh << 11) + start) * 64;
  const u16* Vp = vg + (((size_t)bh << 11) + start) * 64;
  // stage K: rows of 128B; LDS chunk c holds global chunk c ^ (row&7) (rule #21)
  const int nks = W >> 6;             // W*8 16B-chunks / 512 threads
  for (int s = 0; s < nks; ++s) {
    const int o = (tid + s*512) << 4;
    const int row = o >> 7, c = (o >> 4) & 7;
    const char* src = (const char*)(Kp + (size_t)row * 64) + ((c ^ (row & 7)) << 4);
    gload_lds16(src, (char*)lds + o);
  }
  // stage V^T (scalar transpose; r17 swizzle; key = idx%W spreads write banks)
  char* vtb = (char*)lds + 65536;
  for (int idx = tid; idx < W * 8; idx += 512) {
    const int key = idx % W, d0 = (idx / W) << 3;
    u16x8 vv = *(const u16x8*)(Vp + key * 64 + d0);
    #pragma unroll
    for (int z = 0; z < 8; ++z)
      *(u16*)(vtb + swz(d0 + z, key * 2)) = vv[z];
  }
  __syncthreads();
  u16* ctxP = (widx & 1) ? ctxO : ctxE;
  if (W == 512) attn_core<32>(Qp, ctxP, (const char*)lds, vtb, start, widx, bh);
  else          attn_core<24>(Qp, ctxP, (const char*)lds, vtb, start, widx, bh);
}

// merge parity buffers: p<128 -> E; p>=1920 -> O; else E+O. In-place on E is safe.
__global__ __launch_bounds__(256) void merge_kernel(const u16* __restrict__ e,
    const u16* __restrict__ o, u16* __restrict__ out){
  const int i = blockIdx.x * 256 + threadIdx.x;     // u16x8 index
  const int p = (i >> 7) & 2047;                    // (i*8 >> 10) & 2047
  u16x8 ev = ((const u16x8*)e)[i];
  u16x8 ov = ((const u16x8*)o)[i];
  u16x8 r;
  if (p < 128)        r = ev;
  else if (p >= 1920) r = ov;
  else {
    #pragma unroll
    for (int z = 0; z < 8; ++z) r[z] = f2bf(bf2f(ev[z]) + bf2f(ov[z]));
  }
  ((u16x8*)out)[i] = r;
}

// ---------------- host
extern "C" void kernel_launch(void* const* d_in, const int* in_sizes, int n_in,
                              void* d_out, int out_size, void* d_ws, size_t ws_size,
                              hipStream_t stream) {
  const float* hidden = (const float*)d_in[0];
  const float* ln1_g  = (const float*)d_in[1];
  const float* ln1_b  = (const float*)d_in[2];
  const float* wq     = (const float*)d_in[3];
  const float* bq     = (const float*)d_in[4];
  const float* wk     = (const float*)d_in[5];
  const float* bk     = (const float*)d_in[6];
  const float* wv     = (const float*)d_in[7];
  const float* bv     = (const float*)d_in[8];
  const float* wproj  = (const float*)d_in[9];
  const float* bproj  = (const float*)d_in[10];
  const float* ln2_g  = (const float*)d_in[11];
  const float* ln2_b  = (const float*)d_in[12];
  const float* w1     = (const float*)d_in[13];
  const float* b1     = (const float*)d_in[14];
  const float* w2     = (const float*)d_in[15];
  const float* b2     = (const float*)d_in[16];

  char* ws = (char*)d_ws;
  u16* xb    = (u16*)(ws + 0);            // 16 MiB (LN1/LN2 out; ctxO during attn)
  u16* wqkvT = (u16*)(ws + 16777216);     // 6 MiB [3072][1024]
  u16* wpT   = (u16*)(ws + 23068672);     // 2 MiB
  u16* w1T   = (u16*)(ws + 25165824);     // 8 MiB
  u16* w2T   = (u16*)(ws + 33554432);     // 8 MiB
  u16* qb    = (u16*)(ws + 41943040);     // q,k,v contiguous: 3 x 16 MiB
  u16* kb    = (u16*)(ws + 58720256);
  u16* vb    = (u16*)(ws + 75497472);
  u16* ctxE  = (u16*)(ws + 92274688);     // 16 MiB (merged ctx in-place)
  u16* ctxO  = (u16*)(ws + 0);            // aliases xb (dead between qkv and ln2)
  float* bqkv = (float*)(ws + 92274688);  // aliases ctxE start (dead before attn)
  u16* res2  = (u16*)(ws + 109051904);    // 16 MiB bf16
  u16* mid   = (u16*)(ws + 41943040);     // 64 MiB, reuses qb..ctx

  dim3 tb(32, 8);
  transpose_cvt<<<dim3(32, 32), tb, 0, stream>>>(wq, wqkvT, 1024, 1024);
  transpose_cvt<<<dim3(32, 32), tb, 0, stream>>>(wk, wqkvT + 1048576, 1024, 1024);
  transpose_cvt<<<dim3(32, 32), tb, 0, stream>>>(wv, wqkvT + 2097152, 1024, 1024);
  transpose_cvt<<<dim3(32, 32), tb, 0, stream>>>(wproj, wpT, 1024, 1024);
  transpose_cvt<<<dim3(128, 32), tb, 0, stream>>>(w1, w1T, 1024, 4096);
  transpose_cvt<<<dim3(32, 128), tb, 0, stream>>>(w2, w2T, 4096, 1024);
  concat3<<<12, 256, 0, stream>>>(bq, bk, bv, bqkv);

  ln_kernel<0><<<8192, 256, 0, stream>>>(hidden, ln1_g, ln1_b, xb);

  gemm8<0><<<384, 512, 0, stream>>>(xb, wqkvT, bqkv, nullptr, qb, 8192, 3072, 1024);

  attn_kernel<<<512, 512, 0, stream>>>(qb, kb, vb, ctxE, ctxO);
  merge_kernel<<<4096, 256, 0, stream>>>(ctxE, ctxO, ctxE);

  gemmW<1><<<256, 512, 0, stream>>>(ctxE, wpT, bproj, hidden, res2, 8192, 1024, 1024);

  ln_kernel<1><<<8192, 256, 0, stream>>>(res2, ln2_g, ln2_b, xb);

  gemm8<2><<<512, 512, 0, stream>>>(xb, w1T, b1, nullptr, mid, 8192, 4096, 1024);
  gemmW<3><<<256, 512, 0, stream>>>(mid, w2T, b2, res2, (float*)d_out, 8192, 1024, 4096);
}

// Round 22
// 363.486 us; speedup vs baseline: 1.1734x; 1.0310x over previous
//
#include <hip/hip_runtime.h>
#include <math.h>

typedef unsigned short u16;
typedef unsigned int u32;
typedef __attribute__((ext_vector_type(8))) short bf16x8;
typedef __attribute__((ext_vector_type(8))) unsigned short u16x8;
typedef __attribute__((ext_vector_type(4))) float f32x4;
typedef __attribute__((ext_vector_type(4))) unsigned int u32x4;

__device__ __forceinline__ u16 f2bf(float f){
  union { float f; unsigned u; } c; c.f = f;
  unsigned u = c.u;
  return (u16)((u + 0x7fffu + ((u >> 16) & 1u)) >> 16);
}
__device__ __forceinline__ float bf2f(u16 h){
  union { unsigned u; float f; } c; c.u = ((unsigned)h) << 16;
  return c.f;
}
// single-instruction packed f32->bf16 (RNE), gfx950 has no builtin (T12/m240)
__device__ __forceinline__ u32 pack2cvt(float lo, float hi){
  u32 r;
  asm("v_cvt_pk_bf16_f32 %0, %1, %2" : "=v"(r) : "v"(lo), "v"(hi));
  return r;
}
__device__ __forceinline__ void gload_lds16(const void* g, void* l){
  __builtin_amdgcn_global_load_lds((const __attribute__((address_space(1))) void*)g,
                                   (__attribute__((address_space(3))) void*)l, 16, 0, 0);
}
// attention V^T swizzle (r17): XOR row bits into chunk bits (byte bits 6-9).
__device__ __forceinline__ int swz(int row, int bc){
  return (row << 10) + (bc ^ ((row & 15) << 6));
}

#define BAR() asm volatile("s_barrier" ::: "memory")

// ---------------- fused prep: 6 weight transposes (f32 [K][N] -> bf16 [N][K])
// + bias concat, one launch. id decode: [0,3072) wq/wk/wv; [3072,4096) wproj;
// [4096,8192) w1; [8192,12288) w2; [12288,12300) bias concat.
__global__ __launch_bounds__(256) void prep_kernel(
    const float* __restrict__ wq, const float* __restrict__ wk,
    const float* __restrict__ wv, const float* __restrict__ wproj,
    const float* __restrict__ w1, const float* __restrict__ w2,
    const float* __restrict__ bq, const float* __restrict__ bk,
    const float* __restrict__ bv,
    u16* __restrict__ wqkvT, u16* __restrict__ wpT,
    u16* __restrict__ w1T, u16* __restrict__ w2T, float* __restrict__ bqkv)
{
  const int id = blockIdx.x;
  const int tx = threadIdx.x, ty = threadIdx.y;
  if (id >= 12288) {                       // bias concat
    const int i = (id - 12288) * 256 + ty * 32 + tx;
    bqkv[i] = i < 1024 ? bq[i] : (i < 2048 ? bk[i - 1024] : bv[i - 2048]);
    return;
  }
  const float* in; u16* out; int K, N, rel;
  if (id < 3072)      { const int w = id >> 10; rel = id & 1023;
                        in = w == 0 ? wq : (w == 1 ? wk : wv);
                        out = wqkvT + w * 1048576; K = 1024; N = 1024; }
  else if (id < 4096) { rel = id - 3072; in = wproj; out = wpT;  K = 1024; N = 1024; }
  else if (id < 8192) { rel = id - 4096; in = w1;    out = w1T;  K = 1024; N = 4096; }
  else                { rel = id - 8192; in = w2;    out = w2T;  K = 4096; N = 1024; }
  const int nbx = N >> 5;
  const int n0 = (rel % nbx) << 5, k0 = (rel / nbx) << 5;
  __shared__ float tile[32][33];
  #pragma unroll
  for (int r = 0; r < 32; r += 8)
    tile[ty + r][tx] = in[(size_t)(k0 + ty + r) * N + n0 + tx];
  __syncthreads();
  #pragma unroll
  for (int r = 0; r < 32; r += 8)
    out[(size_t)(n0 + ty + r) * K + k0 + tx] = f2bf(tile[tx][ty + r]);
}

// ---------------- layernorm: [rows][1024] (f32 or bf16 in) -> bf16 out
__device__ __forceinline__ float blockReduce(float v, float* ws){
  #pragma unroll
  for (int m = 1; m < 64; m <<= 1) v += __shfl_xor(v, m, 64);
  int w = threadIdx.x >> 6;
  __syncthreads();
  if ((threadIdx.x & 63) == 0) ws[w] = v;
  __syncthreads();
  return ws[0] + ws[1] + ws[2] + ws[3];
}

struct U16x4 { u16 x, y, z, w; };

template<int BF16IN>
__global__ __launch_bounds__(256) void ln_kernel(const void* __restrict__ in_, const float* __restrict__ g,
    const float* __restrict__ be, u16* __restrict__ out){
  __shared__ float ws[4];
  int row = blockIdx.x;
  float vx, vy, vz, vw;
  if constexpr (BF16IN) {
    const U16x4 v = ((const U16x4*)((const u16*)in_ + ((size_t)row << 10)))[threadIdx.x];
    vx = bf2f(v.x); vy = bf2f(v.y); vz = bf2f(v.z); vw = bf2f(v.w);
  } else {
    const float4 v = ((const float4*)((const float*)in_ + ((size_t)row << 10)))[threadIdx.x];
    vx = v.x; vy = v.y; vz = v.z; vw = v.w;
  }
  float s = vx + vy + vz + vw;
  s = blockReduce(s, ws);
  float mean = s * (1.f / 1024.f);
  float dx = vx - mean, dy = vy - mean, dz = vz - mean, dw = vw - mean;
  float s2 = dx*dx + dy*dy + dz*dz + dw*dw;
  s2 = blockReduce(s2, ws);
  float rstd = rsqrtf(s2 * (1.f / 1024.f) + 1e-5f);
  float4 gv = ((const float4*)g)[threadIdx.x];
  float4 bv = ((const float4*)be)[threadIdx.x];
  U16x4 ov;
  ov.x = f2bf(dx * rstd * gv.x + bv.x);
  ov.y = f2bf(dy * rstd * gv.y + bv.y);
  ov.z = f2bf(dz * rstd * gv.z + bv.z);
  ov.w = f2bf(dw * rstd * gv.w + bv.w);
  ((U16x4*)(out + ((size_t)row << 10)))[threadIdx.x] = ov;
}

// ================= 256x256 8-phase bf16 GEMM =========
template<int QM, int QN, int LB, int RDA, int WAIT, typename F>
__device__ __forceinline__ void ph256(const char* lds, const int (&aoff)[2], const int (&boff)[2],
    bf16x8 (&af)[4][2], bf16x8 (&bv)[2][2], f32x4 (&acc)[8][4], F&& stg){
  if constexpr (RDA) {
    const char* Ar = lds + LB*65536 + QM*16384;
    #pragma unroll
    for (int fi = 0; fi < 4; ++fi)
      #pragma unroll
      for (int ks = 0; ks < 2; ++ks)
        af[fi][ks] = *(const bf16x8*)(Ar + fi*2048 + aoff[ks]);
  }
  {
    const char* Br = lds + LB*65536 + 32768 + QN*16384;
    #pragma unroll
    for (int fj = 0; fj < 2; ++fj)
      #pragma unroll
      for (int ks = 0; ks < 2; ++ks)
        bv[fj][ks] = *(const bf16x8*)(Br + fj*2048 + boff[ks]);
  }
  stg();
  BAR();
  asm volatile("s_waitcnt lgkmcnt(0)" ::: "memory");
  __builtin_amdgcn_sched_barrier(0);
  __builtin_amdgcn_s_setprio(1);
  #pragma unroll
  for (int fi = 0; fi < 4; ++fi)
    #pragma unroll
    for (int fj = 0; fj < 2; ++fj){
      acc[QM*4+fi][QN*2+fj] = __builtin_amdgcn_mfma_f32_16x16x32_bf16(af[fi][0], bv[fj][0], acc[QM*4+fi][QN*2+fj], 0, 0, 0);
      acc[QM*4+fi][QN*2+fj] = __builtin_amdgcn_mfma_f32_16x16x32_bf16(af[fi][1], bv[fj][1], acc[QM*4+fi][QN*2+fj], 0, 0, 0);
    }
  __builtin_amdgcn_s_setprio(0);
  if constexpr (WAIT >= 0)
    asm volatile("s_waitcnt vmcnt(%0)" :: "n"(WAIT) : "memory");
  BAR();
}

// EPI 0: bf16 scatter to q/k/v [3][B*NH, S, HD] (+bias)
// EPI 2: bf16 = gelu(acc + bias)   [tanh-form sigmoid approx]
template<int EPI>
__global__ __launch_bounds__(512, 2) void gemm8(
    const u16* __restrict__ A, const u16* __restrict__ Bt,
    const float* __restrict__ bias, const float* __restrict__ add,
    void* __restrict__ out, int M, int N, int K)
{
  __shared__ char lds[147456];
  const int NT = K >> 6;
  const int NI = NT >> 1;
  const int nbx = N >> 8;
  const int nwg = gridDim.x, orig = blockIdx.x;
  const int q = nwg >> 3, r = nwg & 7, x = orig & 7;
  const int wg = (x < r ? x * (q + 1) : r * (q + 1) + (x - r) * q) + (orig >> 3);
  const int bx = wg % nbx, by = wg / nbx;
  const int m0 = by << 8, n0 = bx << 8;

  const int tid = threadIdx.x, wave = tid >> 6, lane = tid & 63;
  const int wr = (wave >> 2) & 1, wc = wave & 3;
  const int lcol = lane & 15, lrow4 = lane >> 4;

  int aoff[2], boff[2];
  #pragma unroll
  for (int ks = 0; ks < 2; ++ks){
    const int chunk = (ks*4 + lrow4) ^ (lane & 7);
    aoff[ks] = (wr*64 + lcol)*128 + chunk*16;
    boff[ks] = (wc*32 + lcol)*128 + chunk*16;
  }

  const int o0 = tid << 4, o1 = (tid + 512) << 4;
  const int row0 = o0 >> 7, c0 = (o0 >> 4) & 7;
  const int row1 = o1 >> 7, c1 = (o1 >> 4) & 7;
  const char* gbase[2][2][2];
  #pragma unroll
  for (int h = 0; h < 2; ++h) {
    gbase[0][h][0] = (const char*)(A  + (size_t)(m0 + h*128 + row0) * K) + ((c0 ^ (row0 & 7)) << 4);
    gbase[0][h][1] = (const char*)(A  + (size_t)(m0 + h*128 + row1) * K) + ((c1 ^ (row1 & 7)) << 4);
    gbase[1][h][0] = (const char*)(Bt + (size_t)(n0 + h*128 + row0) * K) + ((c0 ^ (row0 & 7)) << 4);
    gbase[1][h][1] = (const char*)(Bt + (size_t)(n0 + h*128 + row1) * K) + ((c1 ^ (row1 & 7)) << 4);
  }

  auto STAGE = [&](int isB, int h, int tt){
    const int rb = (tt < NT) ? ((tt & 1) * 65536 + isB * 32768 + h * 16384) : 131072;
    const size_t tb = (size_t)((tt < NT) ? tt : NT - 1) << 7;
    gload_lds16(gbase[isB][h][0] + tb, (char*)lds + rb + o0);
    gload_lds16(gbase[isB][h][1] + tb, (char*)lds + rb + o1);
  };

  f32x4 acc[8][4] = {};
  bf16x8 af[4][2], bv[2][2];

  STAGE(0, 0, 0);
  STAGE(1, 0, 0);
  STAGE(0, 1, 0);
  STAGE(1, 1, 0);
  STAGE(0, 0, 1);
  STAGE(1, 1, 1);
  STAGE(0, 1, 1);
  asm volatile("s_waitcnt vmcnt(6)" ::: "memory");
  BAR();

  for (int i = 0; i < NI; ++i) {
    const int T = 2*i;
    ph256<0, 0, 0, 1, -1>(lds, aoff, boff, af, bv, acc, [&]{ STAGE(1, 0, T+1); });
    ph256<0, 1, 0, 0, -1>(lds, aoff, boff, af, bv, acc, [&]{ STAGE(0, 0, T+2); });
    ph256<1, 1, 0, 1, -1>(lds, aoff, boff, af, bv, acc, [&]{});
    ph256<1, 0, 0, 0,  4>(lds, aoff, boff, af, bv, acc, [&]{ STAGE(1, 1, T+2); });
    ph256<0, 0, 1, 1, -1>(lds, aoff, boff, af, bv, acc, [&]{ STAGE(1, 0, T+2); });
    ph256<0, 1, 1, 0, -1>(lds, aoff, boff, af, bv, acc, [&]{ STAGE(0, 1, T+2); });
    ph256<1, 1, 1, 1, -1>(lds, aoff, boff, af, bv, acc, [&]{ STAGE(0, 0, T+3); });
    ph256<1, 0, 1, 0,  6>(lds, aoff, boff, af, bv, acc, [&]{ STAGE(1, 1, T+3); STAGE(0, 1, T+3); });
  }

  { size_t bp = (size_t)bias, ap = (size_t)add;
    asm volatile("" : "+v"(bp), "+v"(ap));
    bias = (const float*)bp; add = (const float*)ap; }

  #pragma unroll
  for (int mi = 0; mi < 8; ++mi) {
    const int gmb = m0 + (mi>>2)*128 + wr*64 + (mi&3)*16 + lrow4*4;
    #pragma unroll
    for (int ni = 0; ni < 4; ++ni) {
      const int gn = n0 + (ni>>1)*128 + wc*32 + (ni&1)*16 + lcol;
      const float bs = bias[gn];
      #pragma unroll
      for (int rr = 0; rr < 4; ++rr) {
        const int gm = gmb + rr;
        float v = acc[mi][ni][rr] + bs;
        if constexpr (EPI == 0) {
          const int which = gn >> 10, g = gn & 1023;
          const int b = gm >> 11, s = gm & 2047;
          const int h = g >> 6, d = g & 63;
          ((u16*)out)[(size_t)which * 8388608 + ((((size_t)((b << 4) + h) << 11) + s) << 6) + d] = f2bf(v);
        } else {
          const float y2 = 1.5957691216f * v + 0.0713548353f * v * v * v;
          const float e = __expf(y2);
          ((u16*)out)[(size_t)gm * N + gn] = f2bf(v - v / (1.f + e));
        }
      }
    }
  }
}

// ================= 128x256 4-phase bf16 GEMM (wide) ====
// EPI 1: proj  -> out bf16 = acc + bias + add(f32)
// EPI 3: ffn2  -> out f32  = acc + bias + add(bf16)
template<int QN, int LB, int RDA, int WAIT, typename F>
__device__ __forceinline__ void phW(const char* lds, const int (&aoff)[2], const int (&boff)[2],
    bf16x8 (&af)[4][2], bf16x8 (&bv)[2][2], f32x4 (&acc)[4][4], F&& stg){
  if constexpr (RDA) {
    const char* Ar = lds + LB*49152;
    #pragma unroll
    for (int fi = 0; fi < 4; ++fi)
      #pragma unroll
      for (int ks = 0; ks < 2; ++ks)
        af[fi][ks] = *(const bf16x8*)(Ar + fi*2048 + aoff[ks]);
  }
  {
    const char* Br = lds + LB*49152 + 16384 + QN*16384;
    #pragma unroll
    for (int fj = 0; fj < 2; ++fj)
      #pragma unroll
      for (int ks = 0; ks < 2; ++ks)
        bv[fj][ks] = *(const bf16x8*)(Br + fj*2048 + boff[ks]);
  }
  stg();
  BAR();
  asm volatile("s_waitcnt lgkmcnt(0)" ::: "memory");
  __builtin_amdgcn_sched_barrier(0);
  __builtin_amdgcn_s_setprio(1);
  #pragma unroll
  for (int fi = 0; fi < 4; ++fi)
    #pragma unroll
    for (int fj = 0; fj < 2; ++fj){
      acc[fi][QN*2+fj] = __builtin_amdgcn_mfma_f32_16x16x32_bf16(af[fi][0], bv[fj][0], acc[fi][QN*2+fj], 0, 0, 0);
      acc[fi][QN*2+fj] = __builtin_amdgcn_mfma_f32_16x16x32_bf16(af[fi][1], bv[fj][1], acc[fi][QN*2+fj], 0, 0, 0);
    }
  __builtin_amdgcn_s_setprio(0);
  if constexpr (WAIT >= 0)
    asm volatile("s_waitcnt vmcnt(%0)" :: "n"(WAIT) : "memory");
  BAR();
}

template<int EPI>
__global__ __launch_bounds__(512, 2) void gemmW(
    const u16* __restrict__ A, const u16* __restrict__ Bt,
    const float* __restrict__ bias, const void* __restrict__ add,
    void* __restrict__ out, int M, int N, int K)
{
  __shared__ char lds[106496];
  const int NT = K >> 6;
  const int NI = NT >> 1;
  const int nbx = N >> 8;
  const int nwg = gridDim.x, orig = blockIdx.x;
  const int q = nwg >> 3, r = nwg & 7, x = orig & 7;
  const int wg = (x < r ? x * (q + 1) : r * (q + 1) + (x - r) * q) + (orig >> 3);
  const int bx = wg % nbx, by = wg / nbx;
  const int m0 = by << 7, n0 = bx << 8;

  const int tid = threadIdx.x, wave = tid >> 6, lane = tid & 63;
  const int wr = wave >> 2, wc = wave & 3;
  const int lcol = lane & 15, lrow4 = lane >> 4;

  int aoff[2], boff[2];
  #pragma unroll
  for (int ks = 0; ks < 2; ++ks){
    const int chunk = (ks*4 + lrow4) ^ (lane & 7);
    aoff[ks] = (wr*64 + lcol)*128 + chunk*16;
    boff[ks] = (wc*32 + lcol)*128 + chunk*16;
  }

  const int o0 = tid << 4, o1 = (tid + 512) << 4;
  const int row0 = o0 >> 7, c0 = (o0 >> 4) & 7;
  const int row1 = o1 >> 7, c1 = (o1 >> 4) & 7;
  const char* gbase[3][2];
  gbase[0][0] = (const char*)(A  + (size_t)(m0 + row0) * K) + ((c0 ^ (row0 & 7)) << 4);
  gbase[0][1] = (const char*)(A  + (size_t)(m0 + row1) * K) + ((c1 ^ (row1 & 7)) << 4);
  gbase[1][0] = (const char*)(Bt + (size_t)(n0 + row0) * K) + ((c0 ^ (row0 & 7)) << 4);
  gbase[1][1] = (const char*)(Bt + (size_t)(n0 + row1) * K) + ((c1 ^ (row1 & 7)) << 4);
  gbase[2][0] = (const char*)(Bt + (size_t)(n0 + 128 + row0) * K) + ((c0 ^ (row0 & 7)) << 4);
  gbase[2][1] = (const char*)(Bt + (size_t)(n0 + 128 + row1) * K) + ((c1 ^ (row1 & 7)) << 4);

  auto STAGE = [&](int kind, int tt){
    const int rb = (tt < NT) ? ((tt & 1) * 49152 + kind * 16384) : 98304;
    const size_t tb = (size_t)((tt < NT) ? tt : NT - 1) << 7;
    gload_lds16(gbase[kind][0] + tb, (char*)lds + rb + o0);
    gload_lds16(gbase[kind][1] + tb, (char*)lds + rb + o1);
  };

  f32x4 acc[4][4] = {};
  bf16x8 af[4][2], bv[2][2];

  STAGE(0, 0);
  STAGE(1, 0);
  STAGE(2, 0);
  STAGE(0, 1);
  STAGE(1, 1);
  asm volatile("s_waitcnt vmcnt(4)" ::: "memory");
  BAR();

  for (int i = 0; i < NI; ++i) {
    const int T = 2*i;
    phW<0, 0, 1, -1>(lds, aoff, boff, af, bv, acc, [&]{ STAGE(2, T+1); });
    phW<1, 0, 0,  4>(lds, aoff, boff, af, bv, acc, [&]{ STAGE(0, T+2); STAGE(1, T+2); });
    phW<0, 1, 1, -1>(lds, aoff, boff, af, bv, acc, [&]{ STAGE(2, T+2); });
    phW<1, 1, 0,  4>(lds, aoff, boff, af, bv, acc, [&]{ STAGE(0, T+3); STAGE(1, T+3); });
  }

  { size_t bp = (size_t)bias, ap = (size_t)add;
    asm volatile("" : "+v"(bp), "+v"(ap));
    bias = (const float*)bp; add = (const void*)ap; }

  #pragma unroll
  for (int fi = 0; fi < 4; ++fi) {
    const int gmb = m0 + wr*64 + fi*16 + lrow4*4;
    #pragma unroll
    for (int j = 0; j < 4; ++j) {
      const int gn = n0 + (j>>1)*128 + wc*32 + (j&1)*16 + lcol;
      const float bs = bias[gn];
      #pragma unroll
      for (int rr = 0; rr < 4; ++rr) {
        const int gm = gmb + rr;
        float v = acc[fi][j][rr] + bs;
        if constexpr (EPI == 1) {
          ((u16*)out)[(size_t)gm * N + gn] = f2bf(v + ((const float*)add)[(size_t)gm * N + gn]);
        } else {
          ((float*)out)[(size_t)gm * N + gn] = v + bf2f(((const u16*)add)[(size_t)gm * N + gn]);
        }
      }
    }
  }
}

// ================= windowed attention: quarter-split + K in LDS, 512 threads ==
// (r19 structure; r21 cvt_pk packs)
template<int NJ>  // NJ = W/16 (24 or 32)
__device__ void attn_core(const u16* __restrict__ Qp, u16* __restrict__ ctxP,
    const char* ktb, const char* vtb, int start, int widx, int bh)
{
  const int tid = threadIdx.x, wave = tid >> 6, lane = tid & 63;
  const int q = lane & 15, g = lane >> 4;
  constexpr int QTR = NJ / 4;
  const float scale = 0.125f;  // 64^-0.5
  const int b = bh >> 4, h = bh & 15;
  const int sw0 = ((g ^ (q & 7)) << 4);
  const int sw1 = (((4 | g) ^ (q & 7)) << 4);

  for (int qt = wave; qt < NJ; qt += 8) {
    const int q0 = qt * 16;
    const bf16x8 bq0 = *(const bf16x8*)(Qp + (q0 + q) * 64 + g * 8);
    const bf16x8 bq1 = *(const bf16x8*)(Qp + (q0 + q) * 64 + 32 + g * 8);
    float m = -3.0e38f, l = 0.f;
    f32x4 o[4] = {};
    const int s0 = ((g & 1) << 5) + q;
    const int s1 = s0 + 16;
    const bool lowj = (g < 2);

    #pragma unroll
    for (int hh = 0; hh < 4; ++hh) {
      f32x4 acc[QTR];
      #pragma unroll
      for (int j = 0; j < QTR; ++j) {
        const int jj = hh * QTR + j;
        const char* kr = ktb + (jj*16 + q) * 128;
        bf16x8 k0 = *(const bf16x8*)(kr + sw0);
        bf16x8 k1 = *(const bf16x8*)(kr + sw1);
        f32x4 t = {};
        t = __builtin_amdgcn_mfma_f32_16x16x32_bf16(k0, bq0, t, 0, 0, 0);
        t = __builtin_amdgcn_mfma_f32_16x16x32_bf16(k1, bq1, t, 0, 0, 0);
        acc[j] = t;
        if ((j & 3) == 3) __builtin_amdgcn_sched_barrier(0);  // cap read hoisting
      }
      float mh = -3.0e38f;
      #pragma unroll
      for (int j = 0; j < QTR; ++j)
        #pragma unroll
        for (int r = 0; r < 4; ++r) mh = fmaxf(mh, acc[j][r]);
      mh = fmaxf(mh, __shfl_xor(mh, 16, 64));
      mh = fmaxf(mh, __shfl_xor(mh, 32, 64));
      const float mn = fmaxf(m, mh);
      const float fr = __expf((m - mn) * scale);
      m = mn;
      l *= fr;
      #pragma unroll
      for (int df = 0; df < 4; ++df)
        #pragma unroll
        for (int r = 0; r < 4; ++r) o[df][r] *= fr;
      #pragma unroll
      for (int j = 0; j < QTR; ++j)
        #pragma unroll
        for (int r = 0; r < 4; ++r) {
          float e = __expf((acc[j][r] - mn) * scale);
          acc[j][r] = e;
          l += e;
        }
      #pragma unroll
      for (int c = 0; c < QTR / 2; ++c) {
        const u32 a0 = pack2cvt(acc[2*c][0],   acc[2*c][1]);
        const u32 b0 = pack2cvt(acc[2*c][2],   acc[2*c][3]);
        const u32 a1 = pack2cvt(acc[2*c+1][0], acc[2*c+1][1]);
        const u32 b1 = pack2cvt(acc[2*c+1][2], acc[2*c+1][3]);
        const u32 A0l = __shfl(a0, s0, 64), A1l = __shfl(a1, s0, 64);
        const u32 B0l = __shfl(b0, s0, 64), B1l = __shfl(b1, s0, 64);
        const u32 A0h = __shfl(a0, s1, 64), A1h = __shfl(a1, s1, 64);
        const u32 B0h = __shfl(b0, s1, 64), B1h = __shfl(b1, s1, 64);
        union { u32 u[4]; bf16x8 v; } pf;
        pf.u[0] = lowj ? A0l : A1l;
        pf.u[1] = lowj ? B0l : B1l;
        pf.u[2] = lowj ? A0h : A1h;
        pf.u[3] = lowj ? B0h : B1h;
        const int cg = hh * (QTR / 2) + c;
        #pragma unroll
        for (int df = 0; df < 4; ++df) {
          bf16x8 pv = *(const bf16x8*)(vtb + swz(df*16 + q, (cg*32 + g*8) * 2));
          o[df] = __builtin_amdgcn_mfma_f32_16x16x32_bf16(pv, pf.v, o[df], 0, 0, 0);
        }
        if ((c & 1) == 1) __builtin_amdgcn_sched_barrier(0);
      }
    }
    l += __shfl_xor(l, 16, 64);
    l += __shfl_xor(l, 32, 64);
    const float rs = 1.f / l;

    const int p = start + q0 + q;
    const int rel = p - (widx * 256 - 128);
    const float wgt = (rel < 256) ? ((widx == 0) ? 1.f : (float)rel * (1.f / 255.f))
                                  : ((widx == 7) ? 1.f : (1.f - (float)(rel - 256) * (1.f / 255.f)));
    const float rw = rs * wgt;
    u32 w0[4], w1[4];
    #pragma unroll
    for (int df = 0; df < 4; ++df) {
      w0[df] = pack2cvt(o[df][0] * rw, o[df][1] * rw);
      w1[df] = pack2cvt(o[df][2] * rw, o[df][3] * rw);
    }
    u32 W8[8] = {};
    #pragma unroll
    for (int df = 0; df < 4; ++df)
      #pragma unroll
      for (int sg = 0; sg < 4; ++sg) {
        const u32 t0 = __shfl(w0[df], sg*16 + q, 64);
        const u32 t1 = __shfl(w1[df], sg*16 + q, 64);
        if (g == df) { W8[2*sg] = t0; W8[2*sg+1] = t1; }
      }
    u16* dst = ctxP + ((((size_t)(b << 11) + (size_t)p) << 10) + (h << 6) + (g << 4));
    u32x4 lo = { W8[0], W8[1], W8[2], W8[3] };
    u32x4 hi = { W8[4], W8[5], W8[6], W8[7] };
    *(u32x4*)dst = lo;
    *(u32x4*)(dst + 8) = hi;
  }
}

__global__ __launch_bounds__(512, 1) void attn_kernel(const u16* __restrict__ qg, const u16* __restrict__ kg,
    const u16* __restrict__ vg, u16* __restrict__ ctxE, u16* __restrict__ ctxO){
  __shared__ char lds[131072];   // K @0 (64KB), V^T @65536 (64KB) -> 1 block/CU
  const int widx = (int)blockIdx.x >> 6;
  const int bh = blockIdx.x & 63;
  const int i0 = widx << 8;
  int start = i0 - 128; if (start < 0) start = 0;
  int end = i0 + 384;   if (end > 2048) end = 2048;
  const int W = end - start;
  const int tid = threadIdx.x;
  const u16* Qp = qg + (((size_t)bh << 11) + start) * 64;
  const u16* Kp = kg + (((size_t)bh << 11) + start) * 64;
  const u16* Vp = vg + (((size_t)bh << 11) + start) * 64;
  const int nks = W >> 6;             // W*8 16B-chunks / 512 threads
  for (int s = 0; s < nks; ++s) {
    const int o = (tid + s*512) << 4;
    const int row = o >> 7, c = (o >> 4) & 7;
    const char* src = (const char*)(Kp + (size_t)row * 64) + ((c ^ (row & 7)) << 4);
    gload_lds16(src, (char*)lds + o);
  }
  char* vtb = (char*)lds + 65536;
  for (int idx = tid; idx < W * 8; idx += 512) {
    const int key = idx % W, d0 = (idx / W) << 3;
    u16x8 vv = *(const u16x8*)(Vp + key * 64 + d0);
    #pragma unroll
    for (int z = 0; z < 8; ++z)
      *(u16*)(vtb + swz(d0 + z, key * 2)) = vv[z];
  }
  __syncthreads();
  u16* ctxP = (widx & 1) ? ctxO : ctxE;
  if (W == 512) attn_core<32>(Qp, ctxP, (const char*)lds, vtb, start, widx, bh);
  else          attn_core<24>(Qp, ctxP, (const char*)lds, vtb, start, widx, bh);
}

// merge parity buffers: p<128 -> E; p>=1920 -> O; else E+O. In-place on E is safe.
__global__ __launch_bounds__(256) void merge_kernel(const u16* __restrict__ e,
    const u16* __restrict__ o, u16* __restrict__ out){
  const int i = blockIdx.x * 256 + threadIdx.x;     // u16x8 index
  const int p = (i >> 7) & 2047;                    // (i*8 >> 10) & 2047
  u16x8 ev = ((const u16x8*)e)[i];
  u16x8 ov = ((const u16x8*)o)[i];
  u16x8 r;
  if (p < 128)        r = ev;
  else if (p >= 1920) r = ov;
  else {
    #pragma unroll
    for (int z = 0; z < 8; ++z) r[z] = f2bf(bf2f(ev[z]) + bf2f(ov[z]));
  }
  ((u16x8*)out)[i] = r;
}

// ---------------- host
extern "C" void kernel_launch(void* const* d_in, const int* in_sizes, int n_in,
                              void* d_out, int out_size, void* d_ws, size_t ws_size,
                              hipStream_t stream) {
  const float* hidden = (const float*)d_in[0];
  const float* ln1_g  = (const float*)d_in[1];
  const float* ln1_b  = (const float*)d_in[2];
  const float* wq     = (const float*)d_in[3];
  const float* bq     = (const float*)d_in[4];
  const float* wk     = (const float*)d_in[5];
  const float* bk     = (const float*)d_in[6];
  const float* wv     = (const float*)d_in[7];
  const float* bv     = (const float*)d_in[8];
  const float* wproj  = (const float*)d_in[9];
  const float* bproj  = (const float*)d_in[10];
  const float* ln2_g  = (const float*)d_in[11];
  const float* ln2_b  = (const float*)d_in[12];
  const float* w1     = (const float*)d_in[13];
  const float* b1     = (const float*)d_in[14];
  const float* w2     = (const float*)d_in[15];
  const float* b2     = (const float*)d_in[16];

  char* ws = (char*)d_ws;
  u16* xb    = (u16*)(ws + 0);            // 16 MiB (LN1/LN2 out; ctxO during attn)
  u16* wqkvT = (u16*)(ws + 16777216);     // 6 MiB [3072][1024]
  u16* wpT   = (u16*)(ws + 23068672);     // 2 MiB
  u16* w1T   = (u16*)(ws + 25165824);     // 8 MiB
  u16* w2T   = (u16*)(ws + 33554432);     // 8 MiB
  u16* qb    = (u16*)(ws + 41943040);     // q,k,v contiguous: 3 x 16 MiB
  u16* kb    = (u16*)(ws + 58720256);
  u16* vb    = (u16*)(ws + 75497472);
  u16* ctxE  = (u16*)(ws + 92274688);     // 16 MiB (merged ctx in-place)
  u16* ctxO  = (u16*)(ws + 0);            // aliases xb (dead between qkv and ln2)
  float* bqkv = (float*)(ws + 92274688);  // aliases ctxE start (dead before attn)
  u16* res2  = (u16*)(ws + 109051904);    // 16 MiB bf16
  u16* mid   = (u16*)(ws + 41943040);     // 64 MiB, reuses qb..ctx

  prep_kernel<<<12300, dim3(32, 8), 0, stream>>>(wq, wk, wv, wproj, w1, w2,
                                                 bq, bk, bv,
                                                 wqkvT, wpT, w1T, w2T, bqkv);

  ln_kernel<0><<<8192, 256, 0, stream>>>(hidden, ln1_g, ln1_b, xb);

  gemm8<0><<<384, 512, 0, stream>>>(xb, wqkvT, bqkv, nullptr, qb, 8192, 3072, 1024);

  attn_kernel<<<512, 512, 0, stream>>>(qb, kb, vb, ctxE, ctxO);
  merge_kernel<<<4096, 256, 0, stream>>>(ctxE, ctxO, ctxE);

  gemmW<1><<<256, 512, 0, stream>>>(ctxE, wpT, bproj, hidden, res2, 8192, 1024, 1024);

  ln_kernel<1><<<8192, 256, 0, stream>>>(res2, ln2_g, ln2_b, xb);

  gemm8<2><<<512, 512, 0, stream>>>(xb, w1T, b1, nullptr, mid, 8192, 4096, 1024);
  gemmW<3><<<256, 512, 0, stream>>>(mid, w2T, b2, res2, (float*)d_out, 8192, 1024, 4096);
}

// Round 23
// 362.634 us; speedup vs baseline: 1.1762x; 1.0023x over previous
//
#include <hip/hip_runtime.h>
#include <math.h>

typedef unsigned short u16;
typedef unsigned int u32;
typedef __attribute__((ext_vector_type(8))) short bf16x8;
typedef __attribute__((ext_vector_type(8))) unsigned short u16x8;
typedef __attribute__((ext_vector_type(4))) float f32x4;
typedef __attribute__((ext_vector_type(4))) unsigned int u32x4;

__device__ __forceinline__ u16 f2bf(float f){
  union { float f; unsigned u; } c; c.f = f;
  unsigned u = c.u;
  return (u16)((u + 0x7fffu + ((u >> 16) & 1u)) >> 16);
}
__device__ __forceinline__ float bf2f(u16 h){
  union { unsigned u; float f; } c; c.u = ((unsigned)h) << 16;
  return c.f;
}
// single-instruction packed f32->bf16 (RNE), gfx950 has no builtin (T12/m240)
__device__ __forceinline__ u32 pack2cvt(float lo, float hi){
  u32 r;
  asm("v_cvt_pk_bf16_f32 %0, %1, %2" : "=v"(r) : "v"(lo), "v"(hi));
  return r;
}
__device__ __forceinline__ void gload_lds16(const void* g, void* l){
  __builtin_amdgcn_global_load_lds((const __attribute__((address_space(1))) void*)g,
                                   (__attribute__((address_space(3))) void*)l, 16, 0, 0);
}
// attention V^T swizzle (r17): XOR row bits into chunk bits (byte bits 6-9).
__device__ __forceinline__ int swz(int row, int bc){
  return (row << 10) + (bc ^ ((row & 15) << 6));
}

#define BAR() asm volatile("s_barrier" ::: "memory")

// ---------------- fused prep: 6 weight transposes (f32 [K][N] -> bf16 [N][K])
// + bias concat, one launch. id decode: [0,3072) wq/wk/wv; [3072,4096) wproj;
// [4096,8192) w1; [8192,12288) w2; [12288,12300) bias concat.
__global__ __launch_bounds__(256) void prep_kernel(
    const float* __restrict__ wq, const float* __restrict__ wk,
    const float* __restrict__ wv, const float* __restrict__ wproj,
    const float* __restrict__ w1, const float* __restrict__ w2,
    const float* __restrict__ bq, const float* __restrict__ bk,
    const float* __restrict__ bv,
    u16* __restrict__ wqkvT, u16* __restrict__ wpT,
    u16* __restrict__ w1T, u16* __restrict__ w2T, float* __restrict__ bqkv)
{
  const int id = blockIdx.x;
  const int tx = threadIdx.x, ty = threadIdx.y;
  if (id >= 12288) {                       // bias concat
    const int i = (id - 12288) * 256 + ty * 32 + tx;
    bqkv[i] = i < 1024 ? bq[i] : (i < 2048 ? bk[i - 1024] : bv[i - 2048]);
    return;
  }
  const float* in; u16* out; int K, N, rel;
  if (id < 3072)      { const int w = id >> 10; rel = id & 1023;
                        in = w == 0 ? wq : (w == 1 ? wk : wv);
                        out = wqkvT + w * 1048576; K = 1024; N = 1024; }
  else if (id < 4096) { rel = id - 3072; in = wproj; out = wpT;  K = 1024; N = 1024; }
  else if (id < 8192) { rel = id - 4096; in = w1;    out = w1T;  K = 1024; N = 4096; }
  else                { rel = id - 8192; in = w2;    out = w2T;  K = 4096; N = 1024; }
  const int nbx = N >> 5;
  const int n0 = (rel % nbx) << 5, k0 = (rel / nbx) << 5;
  __shared__ float tile[32][33];
  #pragma unroll
  for (int r = 0; r < 32; r += 8)
    tile[ty + r][tx] = in[(size_t)(k0 + ty + r) * N + n0 + tx];
  __syncthreads();
  #pragma unroll
  for (int r = 0; r < 32; r += 8)
    out[(size_t)(n0 + ty + r) * K + k0 + tx] = f2bf(tile[tx][ty + r]);
}

// ---------------- layernorm: [rows][1024] (f32 or bf16 in) -> bf16 out
__device__ __forceinline__ float blockReduce(float v, float* ws){
  #pragma unroll
  for (int m = 1; m < 64; m <<= 1) v += __shfl_xor(v, m, 64);
  int w = threadIdx.x >> 6;
  __syncthreads();
  if ((threadIdx.x & 63) == 0) ws[w] = v;
  __syncthreads();
  return ws[0] + ws[1] + ws[2] + ws[3];
}

struct U16x4 { u16 x, y, z, w; };

template<int BF16IN>
__global__ __launch_bounds__(256) void ln_kernel(const void* __restrict__ in_, const float* __restrict__ g,
    const float* __restrict__ be, u16* __restrict__ out){
  __shared__ float ws[4];
  int row = blockIdx.x;
  float vx, vy, vz, vw;
  if constexpr (BF16IN) {
    const U16x4 v = ((const U16x4*)((const u16*)in_ + ((size_t)row << 10)))[threadIdx.x];
    vx = bf2f(v.x); vy = bf2f(v.y); vz = bf2f(v.z); vw = bf2f(v.w);
  } else {
    const float4 v = ((const float4*)((const float*)in_ + ((size_t)row << 10)))[threadIdx.x];
    vx = v.x; vy = v.y; vz = v.z; vw = v.w;
  }
  float s = vx + vy + vz + vw;
  s = blockReduce(s, ws);
  float mean = s * (1.f / 1024.f);
  float dx = vx - mean, dy = vy - mean, dz = vz - mean, dw = vw - mean;
  float s2 = dx*dx + dy*dy + dz*dz + dw*dw;
  s2 = blockReduce(s2, ws);
  float rstd = rsqrtf(s2 * (1.f / 1024.f) + 1e-5f);
  float4 gv = ((const float4*)g)[threadIdx.x];
  float4 bv = ((const float4*)be)[threadIdx.x];
  U16x4 ov;
  ov.x = f2bf(dx * rstd * gv.x + bv.x);
  ov.y = f2bf(dy * rstd * gv.y + bv.y);
  ov.z = f2bf(dz * rstd * gv.z + bv.z);
  ov.w = f2bf(dw * rstd * gv.w + bv.w);
  ((U16x4*)(out + ((size_t)row << 10)))[threadIdx.x] = ov;
}

// ================= 256x256 8-phase bf16 GEMM =========
// r23: no explicit lgkmcnt(0)/sched_barrier before MFMA — compiler inserts
// fine-grained counted lgkm waits via register deps, letting early MFMAs
// overlap trailing ds_read returns.
template<int QM, int QN, int LB, int RDA, int WAIT, typename F>
__device__ __forceinline__ void ph256(const char* lds, const int (&aoff)[2], const int (&boff)[2],
    bf16x8 (&af)[4][2], bf16x8 (&bv)[2][2], f32x4 (&acc)[8][4], F&& stg){
  if constexpr (RDA) {
    const char* Ar = lds + LB*65536 + QM*16384;
    #pragma unroll
    for (int fi = 0; fi < 4; ++fi)
      #pragma unroll
      for (int ks = 0; ks < 2; ++ks)
        af[fi][ks] = *(const bf16x8*)(Ar + fi*2048 + aoff[ks]);
  }
  {
    const char* Br = lds + LB*65536 + 32768 + QN*16384;
    #pragma unroll
    for (int fj = 0; fj < 2; ++fj)
      #pragma unroll
      for (int ks = 0; ks < 2; ++ks)
        bv[fj][ks] = *(const bf16x8*)(Br + fj*2048 + boff[ks]);
  }
  stg();
  BAR();
  __builtin_amdgcn_s_setprio(1);
  #pragma unroll
  for (int fi = 0; fi < 4; ++fi)
    #pragma unroll
    for (int fj = 0; fj < 2; ++fj){
      acc[QM*4+fi][QN*2+fj] = __builtin_amdgcn_mfma_f32_16x16x32_bf16(af[fi][0], bv[fj][0], acc[QM*4+fi][QN*2+fj], 0, 0, 0);
      acc[QM*4+fi][QN*2+fj] = __builtin_amdgcn_mfma_f32_16x16x32_bf16(af[fi][1], bv[fj][1], acc[QM*4+fi][QN*2+fj], 0, 0, 0);
    }
  __builtin_amdgcn_s_setprio(0);
  if constexpr (WAIT >= 0)
    asm volatile("s_waitcnt vmcnt(%0)" :: "n"(WAIT) : "memory");
  BAR();
}

// EPI 0: bf16 scatter to q/k/v [3][B*NH, S, HD] (+bias)
// EPI 2: bf16 = gelu(acc + bias)   [tanh-form sigmoid approx]
template<int EPI>
__global__ __launch_bounds__(512, 2) void gemm8(
    const u16* __restrict__ A, const u16* __restrict__ Bt,
    const float* __restrict__ bias, const float* __restrict__ add,
    void* __restrict__ out, int M, int N, int K)
{
  __shared__ char lds[147456];
  const int NT = K >> 6;
  const int NI = NT >> 1;
  const int nbx = N >> 8;
  const int nwg = gridDim.x, orig = blockIdx.x;
  const int q = nwg >> 3, r = nwg & 7, x = orig & 7;
  const int wg = (x < r ? x * (q + 1) : r * (q + 1) + (x - r) * q) + (orig >> 3);
  const int bx = wg % nbx, by = wg / nbx;
  const int m0 = by << 8, n0 = bx << 8;

  const int tid = threadIdx.x, wave = tid >> 6, lane = tid & 63;
  const int wr = (wave >> 2) & 1, wc = wave & 3;
  const int lcol = lane & 15, lrow4 = lane >> 4;

  int aoff[2], boff[2];
  #pragma unroll
  for (int ks = 0; ks < 2; ++ks){
    const int chunk = (ks*4 + lrow4) ^ (lane & 7);
    aoff[ks] = (wr*64 + lcol)*128 + chunk*16;
    boff[ks] = (wc*32 + lcol)*128 + chunk*16;
  }

  const int o0 = tid << 4, o1 = (tid + 512) << 4;
  const int row0 = o0 >> 7, c0 = (o0 >> 4) & 7;
  const int row1 = o1 >> 7, c1 = (o1 >> 4) & 7;
  const char* gbase[2][2][2];
  #pragma unroll
  for (int h = 0; h < 2; ++h) {
    gbase[0][h][0] = (const char*)(A  + (size_t)(m0 + h*128 + row0) * K) + ((c0 ^ (row0 & 7)) << 4);
    gbase[0][h][1] = (const char*)(A  + (size_t)(m0 + h*128 + row1) * K) + ((c1 ^ (row1 & 7)) << 4);
    gbase[1][h][0] = (const char*)(Bt + (size_t)(n0 + h*128 + row0) * K) + ((c0 ^ (row0 & 7)) << 4);
    gbase[1][h][1] = (const char*)(Bt + (size_t)(n0 + h*128 + row1) * K) + ((c1 ^ (row1 & 7)) << 4);
  }

  auto STAGE = [&](int isB, int h, int tt){
    const int rb = (tt < NT) ? ((tt & 1) * 65536 + isB * 32768 + h * 16384) : 131072;
    const size_t tb = (size_t)((tt < NT) ? tt : NT - 1) << 7;
    gload_lds16(gbase[isB][h][0] + tb, (char*)lds + rb + o0);
    gload_lds16(gbase[isB][h][1] + tb, (char*)lds + rb + o1);
  };

  f32x4 acc[8][4] = {};
  bf16x8 af[4][2], bv[2][2];

  STAGE(0, 0, 0);
  STAGE(1, 0, 0);
  STAGE(0, 1, 0);
  STAGE(1, 1, 0);
  STAGE(0, 0, 1);
  STAGE(1, 1, 1);
  STAGE(0, 1, 1);
  asm volatile("s_waitcnt vmcnt(6)" ::: "memory");
  BAR();

  for (int i = 0; i < NI; ++i) {
    const int T = 2*i;
    ph256<0, 0, 0, 1, -1>(lds, aoff, boff, af, bv, acc, [&]{ STAGE(1, 0, T+1); });
    ph256<0, 1, 0, 0, -1>(lds, aoff, boff, af, bv, acc, [&]{ STAGE(0, 0, T+2); });
    ph256<1, 1, 0, 1, -1>(lds, aoff, boff, af, bv, acc, [&]{});
    ph256<1, 0, 0, 0,  4>(lds, aoff, boff, af, bv, acc, [&]{ STAGE(1, 1, T+2); });
    ph256<0, 0, 1, 1, -1>(lds, aoff, boff, af, bv, acc, [&]{ STAGE(1, 0, T+2); });
    ph256<0, 1, 1, 0, -1>(lds, aoff, boff, af, bv, acc, [&]{ STAGE(0, 1, T+2); });
    ph256<1, 1, 1, 1, -1>(lds, aoff, boff, af, bv, acc, [&]{ STAGE(0, 0, T+3); });
    ph256<1, 0, 1, 0,  6>(lds, aoff, boff, af, bv, acc, [&]{ STAGE(1, 1, T+3); STAGE(0, 1, T+3); });
  }

  { size_t bp = (size_t)bias, ap = (size_t)add;
    asm volatile("" : "+v"(bp), "+v"(ap));
    bias = (const float*)bp; add = (const float*)ap; }

  #pragma unroll
  for (int mi = 0; mi < 8; ++mi) {
    const int gmb = m0 + (mi>>2)*128 + wr*64 + (mi&3)*16 + lrow4*4;
    #pragma unroll
    for (int ni = 0; ni < 4; ++ni) {
      const int gn = n0 + (ni>>1)*128 + wc*32 + (ni&1)*16 + lcol;
      const float bs = bias[gn];
      #pragma unroll
      for (int rr = 0; rr < 4; ++rr) {
        const int gm = gmb + rr;
        float v = acc[mi][ni][rr] + bs;
        if constexpr (EPI == 0) {
          const int which = gn >> 10, g = gn & 1023;
          const int b = gm >> 11, s = gm & 2047;
          const int h = g >> 6, d = g & 63;
          ((u16*)out)[(size_t)which * 8388608 + ((((size_t)((b << 4) + h) << 11) + s) << 6) + d] = f2bf(v);
        } else {
          const float y2 = 1.5957691216f * v + 0.0713548353f * v * v * v;
          const float e = __expf(y2);
          ((u16*)out)[(size_t)gm * N + gn] = f2bf(v - v / (1.f + e));
        }
      }
    }
  }
}

// ================= 128x256 4-phase bf16 GEMM (wide) ====
// EPI 1: proj  -> out bf16 = acc + bias + add(f32)
// EPI 3: ffn2  -> out f32  = acc + bias + add(bf16)
template<int QN, int LB, int RDA, int WAIT, typename F>
__device__ __forceinline__ void phW(const char* lds, const int (&aoff)[2], const int (&boff)[2],
    bf16x8 (&af)[4][2], bf16x8 (&bv)[2][2], f32x4 (&acc)[4][4], F&& stg){
  if constexpr (RDA) {
    const char* Ar = lds + LB*49152;
    #pragma unroll
    for (int fi = 0; fi < 4; ++fi)
      #pragma unroll
      for (int ks = 0; ks < 2; ++ks)
        af[fi][ks] = *(const bf16x8*)(Ar + fi*2048 + aoff[ks]);
  }
  {
    const char* Br = lds + LB*49152 + 16384 + QN*16384;
    #pragma unroll
    for (int fj = 0; fj < 2; ++fj)
      #pragma unroll
      for (int ks = 0; ks < 2; ++ks)
        bv[fj][ks] = *(const bf16x8*)(Br + fj*2048 + boff[ks]);
  }
  stg();
  BAR();
  __builtin_amdgcn_s_setprio(1);
  #pragma unroll
  for (int fi = 0; fi < 4; ++fi)
    #pragma unroll
    for (int fj = 0; fj < 2; ++fj){
      acc[fi][QN*2+fj] = __builtin_amdgcn_mfma_f32_16x16x32_bf16(af[fi][0], bv[fj][0], acc[fi][QN*2+fj], 0, 0, 0);
      acc[fi][QN*2+fj] = __builtin_amdgcn_mfma_f32_16x16x32_bf16(af[fi][1], bv[fj][1], acc[fi][QN*2+fj], 0, 0, 0);
    }
  __builtin_amdgcn_s_setprio(0);
  if constexpr (WAIT >= 0)
    asm volatile("s_waitcnt vmcnt(%0)" :: "n"(WAIT) : "memory");
  BAR();
}

template<int EPI>
__global__ __launch_bounds__(512, 2) void gemmW(
    const u16* __restrict__ A, const u16* __restrict__ Bt,
    const float* __restrict__ bias, const void* __restrict__ add,
    void* __restrict__ out, int M, int N, int K)
{
  __shared__ char lds[106496];
  const int NT = K >> 6;
  const int NI = NT >> 1;
  const int nbx = N >> 8;
  const int nwg = gridDim.x, orig = blockIdx.x;
  const int q = nwg >> 3, r = nwg & 7, x = orig & 7;
  const int wg = (x < r ? x * (q + 1) : r * (q + 1) + (x - r) * q) + (orig >> 3);
  const int bx = wg % nbx, by = wg / nbx;
  const int m0 = by << 7, n0 = bx << 8;

  const int tid = threadIdx.x, wave = tid >> 6, lane = tid & 63;
  const int wr = wave >> 2, wc = wave & 3;
  const int lcol = lane & 15, lrow4 = lane >> 4;

  int aoff[2], boff[2];
  #pragma unroll
  for (int ks = 0; ks < 2; ++ks){
    const int chunk = (ks*4 + lrow4) ^ (lane & 7);
    aoff[ks] = (wr*64 + lcol)*128 + chunk*16;
    boff[ks] = (wc*32 + lcol)*128 + chunk*16;
  }

  const int o0 = tid << 4, o1 = (tid + 512) << 4;
  const int row0 = o0 >> 7, c0 = (o0 >> 4) & 7;
  const int row1 = o1 >> 7, c1 = (o1 >> 4) & 7;
  const char* gbase[3][2];
  gbase[0][0] = (const char*)(A  + (size_t)(m0 + row0) * K) + ((c0 ^ (row0 & 7)) << 4);
  gbase[0][1] = (const char*)(A  + (size_t)(m0 + row1) * K) + ((c1 ^ (row1 & 7)) << 4);
  gbase[1][0] = (const char*)(Bt + (size_t)(n0 + row0) * K) + ((c0 ^ (row0 & 7)) << 4);
  gbase[1][1] = (const char*)(Bt + (size_t)(n0 + row1) * K) + ((c1 ^ (row1 & 7)) << 4);
  gbase[2][0] = (const char*)(Bt + (size_t)(n0 + 128 + row0) * K) + ((c0 ^ (row0 & 7)) << 4);
  gbase[2][1] = (const char*)(Bt + (size_t)(n0 + 128 + row1) * K) + ((c1 ^ (row1 & 7)) << 4);

  auto STAGE = [&](int kind, int tt){
    const int rb = (tt < NT) ? ((tt & 1) * 49152 + kind * 16384) : 98304;
    const size_t tb = (size_t)((tt < NT) ? tt : NT - 1) << 7;
    gload_lds16(gbase[kind][0] + tb, (char*)lds + rb + o0);
    gload_lds16(gbase[kind][1] + tb, (char*)lds + rb + o1);
  };

  f32x4 acc[4][4] = {};
  bf16x8 af[4][2], bv[2][2];

  STAGE(0, 0);
  STAGE(1, 0);
  STAGE(2, 0);
  STAGE(0, 1);
  STAGE(1, 1);
  asm volatile("s_waitcnt vmcnt(4)" ::: "memory");
  BAR();

  for (int i = 0; i < NI; ++i) {
    const int T = 2*i;
    phW<0, 0, 1, -1>(lds, aoff, boff, af, bv, acc, [&]{ STAGE(2, T+1); });
    phW<1, 0, 0,  4>(lds, aoff, boff, af, bv, acc, [&]{ STAGE(0, T+2); STAGE(1, T+2); });
    phW<0, 1, 1, -1>(lds, aoff, boff, af, bv, acc, [&]{ STAGE(2, T+2); });
    phW<1, 1, 0,  4>(lds, aoff, boff, af, bv, acc, [&]{ STAGE(0, T+3); STAGE(1, T+3); });
  }

  { size_t bp = (size_t)bias, ap = (size_t)add;
    asm volatile("" : "+v"(bp), "+v"(ap));
    bias = (const float*)bp; add = (const void*)ap; }

  #pragma unroll
  for (int fi = 0; fi < 4; ++fi) {
    const int gmb = m0 + wr*64 + fi*16 + lrow4*4;
    #pragma unroll
    for (int j = 0; j < 4; ++j) {
      const int gn = n0 + (j>>1)*128 + wc*32 + (j&1)*16 + lcol;
      const float bs = bias[gn];
      #pragma unroll
      for (int rr = 0; rr < 4; ++rr) {
        const int gm = gmb + rr;
        float v = acc[fi][j][rr] + bs;
        if constexpr (EPI == 1) {
          ((u16*)out)[(size_t)gm * N + gn] = f2bf(v + ((const float*)add)[(size_t)gm * N + gn]);
        } else {
          ((float*)out)[(size_t)gm * N + gn] = v + bf2f(((const u16*)add)[(size_t)gm * N + gn]);
        }
      }
    }
  }
}

// ================= windowed attention: quarter-split + K in LDS, 512 threads ==
// (r19 structure; r21 cvt_pk packs)
template<int NJ>  // NJ = W/16 (24 or 32)
__device__ void attn_core(const u16* __restrict__ Qp, u16* __restrict__ ctxP,
    const char* ktb, const char* vtb, int start, int widx, int bh)
{
  const int tid = threadIdx.x, wave = tid >> 6, lane = tid & 63;
  const int q = lane & 15, g = lane >> 4;
  constexpr int QTR = NJ / 4;
  const float scale = 0.125f;  // 64^-0.5
  const int b = bh >> 4, h = bh & 15;
  const int sw0 = ((g ^ (q & 7)) << 4);
  const int sw1 = (((4 | g) ^ (q & 7)) << 4);

  for (int qt = wave; qt < NJ; qt += 8) {
    const int q0 = qt * 16;
    const bf16x8 bq0 = *(const bf16x8*)(Qp + (q0 + q) * 64 + g * 8);
    const bf16x8 bq1 = *(const bf16x8*)(Qp + (q0 + q) * 64 + 32 + g * 8);
    float m = -3.0e38f, l = 0.f;
    f32x4 o[4] = {};
    const int s0 = ((g & 1) << 5) + q;
    const int s1 = s0 + 16;
    const bool lowj = (g < 2);

    #pragma unroll
    for (int hh = 0; hh < 4; ++hh) {
      f32x4 acc[QTR];
      #pragma unroll
      for (int j = 0; j < QTR; ++j) {
        const int jj = hh * QTR + j;
        const char* kr = ktb + (jj*16 + q) * 128;
        bf16x8 k0 = *(const bf16x8*)(kr + sw0);
        bf16x8 k1 = *(const bf16x8*)(kr + sw1);
        f32x4 t = {};
        t = __builtin_amdgcn_mfma_f32_16x16x32_bf16(k0, bq0, t, 0, 0, 0);
        t = __builtin_amdgcn_mfma_f32_16x16x32_bf16(k1, bq1, t, 0, 0, 0);
        acc[j] = t;
        if ((j & 3) == 3) __builtin_amdgcn_sched_barrier(0);  // cap read hoisting
      }
      float mh = -3.0e38f;
      #pragma unroll
      for (int j = 0; j < QTR; ++j)
        #pragma unroll
        for (int r = 0; r < 4; ++r) mh = fmaxf(mh, acc[j][r]);
      mh = fmaxf(mh, __shfl_xor(mh, 16, 64));
      mh = fmaxf(mh, __shfl_xor(mh, 32, 64));
      const float mn = fmaxf(m, mh);
      const float fr = __expf((m - mn) * scale);
      m = mn;
      l *= fr;
      #pragma unroll
      for (int df = 0; df < 4; ++df)
        #pragma unroll
        for (int r = 0; r < 4; ++r) o[df][r] *= fr;
      #pragma unroll
      for (int j = 0; j < QTR; ++j)
        #pragma unroll
        for (int r = 0; r < 4; ++r) {
          float e = __expf((acc[j][r] - mn) * scale);
          acc[j][r] = e;
          l += e;
        }
      #pragma unroll
      for (int c = 0; c < QTR / 2; ++c) {
        const u32 a0 = pack2cvt(acc[2*c][0],   acc[2*c][1]);
        const u32 b0 = pack2cvt(acc[2*c][2],   acc[2*c][3]);
        const u32 a1 = pack2cvt(acc[2*c+1][0], acc[2*c+1][1]);
        const u32 b1 = pack2cvt(acc[2*c+1][2], acc[2*c+1][3]);
        const u32 A0l = __shfl(a0, s0, 64), A1l = __shfl(a1, s0, 64);
        const u32 B0l = __shfl(b0, s0, 64), B1l = __shfl(b1, s0, 64);
        const u32 A0h = __shfl(a0, s1, 64), A1h = __shfl(a1, s1, 64);
        const u32 B0h = __shfl(b0, s1, 64), B1h = __shfl(b1, s1, 64);
        union { u32 u[4]; bf16x8 v; } pf;
        pf.u[0] = lowj ? A0l : A1l;
        pf.u[1] = lowj ? B0l : B1l;
        pf.u[2] = lowj ? A0h : A1h;
        pf.u[3] = lowj ? B0h : B1h;
        const int cg = hh * (QTR / 2) + c;
        #pragma unroll
        for (int df = 0; df < 4; ++df) {
          bf16x8 pv = *(const bf16x8*)(vtb + swz(df*16 + q, (cg*32 + g*8) * 2));
          o[df] = __builtin_amdgcn_mfma_f32_16x16x32_bf16(pv, pf.v, o[df], 0, 0, 0);
        }
        if ((c & 1) == 1) __builtin_amdgcn_sched_barrier(0);
      }
    }
    l += __shfl_xor(l, 16, 64);
    l += __shfl_xor(l, 32, 64);
    const float rs = 1.f / l;

    const int p = start + q0 + q;
    const int rel = p - (widx * 256 - 128);
    const float wgt = (rel < 256) ? ((widx == 0) ? 1.f : (float)rel * (1.f / 255.f))
                                  : ((widx == 7) ? 1.f : (1.f - (float)(rel - 256) * (1.f / 255.f)));
    const float rw = rs * wgt;
    u32 w0[4], w1[4];
    #pragma unroll
    for (int df = 0; df < 4; ++df) {
      w0[df] = pack2cvt(o[df][0] * rw, o[df][1] * rw);
      w1[df] = pack2cvt(o[df][2] * rw, o[df][3] * rw);
    }
    u32 W8[8] = {};
    #pragma unroll
    for (int df = 0; df < 4; ++df)
      #pragma unroll
      for (int sg = 0; sg < 4; ++sg) {
        const u32 t0 = __shfl(w0[df], sg*16 + q, 64);
        const u32 t1 = __shfl(w1[df], sg*16 + q, 64);
        if (g == df) { W8[2*sg] = t0; W8[2*sg+1] = t1; }
      }
    u16* dst = ctxP + ((((size_t)(b << 11) + (size_t)p) << 10) + (h << 6) + (g << 4));
    u32x4 lo = { W8[0], W8[1], W8[2], W8[3] };
    u32x4 hi = { W8[4], W8[5], W8[6], W8[7] };
    *(u32x4*)dst = lo;
    *(u32x4*)(dst + 8) = hi;
  }
}

__global__ __launch_bounds__(512, 1) void attn_kernel(const u16* __restrict__ qg, const u16* __restrict__ kg,
    const u16* __restrict__ vg, u16* __restrict__ ctxE, u16* __restrict__ ctxO){
  __shared__ char lds[131072];   // K @0 (64KB), V^T @65536 (64KB) -> 1 block/CU
  const int widx = (int)blockIdx.x >> 6;
  const int bh = blockIdx.x & 63;
  const int i0 = widx << 8;
  int start = i0 - 128; if (start < 0) start = 0;
  int end = i0 + 384;   if (end > 2048) end = 2048;
  const int W = end - start;
  const int tid = threadIdx.x;
  const u16* Qp = qg + (((size_t)bh << 11) + start) * 64;
  const u16* Kp = kg + (((size_t)bh << 11) + start) * 64;
  const u16* Vp = vg + (((size_t)bh << 11) + start) * 64;
  const int nks = W >> 6;             // W*8 16B-chunks / 512 threads
  for (int s = 0; s < nks; ++s) {
    const int o = (tid + s*512) << 4;
    const int row = o >> 7, c = (o >> 4) & 7;
    const char* src = (const char*)(Kp + (size_t)row * 64) + ((c ^ (row & 7)) << 4);
    gload_lds16(src, (char*)lds + o);
  }
  char* vtb = (char*)lds + 65536;
  for (int idx = tid; idx < W * 8; idx += 512) {
    const int key = idx % W, d0 = (idx / W) << 3;
    u16x8 vv = *(const u16x8*)(Vp + key * 64 + d0);
    #pragma unroll
    for (int z = 0; z < 8; ++z)
      *(u16*)(vtb + swz(d0 + z, key * 2)) = vv[z];
  }
  __syncthreads();
  u16* ctxP = (widx & 1) ? ctxO : ctxE;
  if (W == 512) attn_core<32>(Qp, ctxP, (const char*)lds, vtb, start, widx, bh);
  else          attn_core<24>(Qp, ctxP, (const char*)lds, vtb, start, widx, bh);
}

// merge parity buffers: p<128 -> E; p>=1920 -> O; else E+O. In-place on E is safe.
__global__ __launch_bounds__(256) void merge_kernel(const u16* __restrict__ e,
    const u16* __restrict__ o, u16* __restrict__ out){
  const int i = blockIdx.x * 256 + threadIdx.x;     // u16x8 index
  const int p = (i >> 7) & 2047;                    // (i*8 >> 10) & 2047
  u16x8 ev = ((const u16x8*)e)[i];
  u16x8 ov = ((const u16x8*)o)[i];
  u16x8 r;
  if (p < 128)        r = ev;
  else if (p >= 1920) r = ov;
  else {
    #pragma unroll
    for (int z = 0; z < 8; ++z) r[z] = f2bf(bf2f(ev[z]) + bf2f(ov[z]));
  }
  ((u16x8*)out)[i] = r;
}

// ---------------- host
extern "C" void kernel_launch(void* const* d_in, const int* in_sizes, int n_in,
                              void* d_out, int out_size, void* d_ws, size_t ws_size,
                              hipStream_t stream) {
  const float* hidden = (const float*)d_in[0];
  const float* ln1_g  = (const float*)d_in[1];
  const float* ln1_b  = (const float*)d_in[2];
  const float* wq     = (const float*)d_in[3];
  const float* bq     = (const float*)d_in[4];
  const float* wk     = (const float*)d_in[5];
  const float* bk     = (const float*)d_in[6];
  const float* wv     = (const float*)d_in[7];
  const float* bv     = (const float*)d_in[8];
  const float* wproj  = (const float*)d_in[9];
  const float* bproj  = (const float*)d_in[10];
  const float* ln2_g  = (const float*)d_in[11];
  const float* ln2_b  = (const float*)d_in[12];
  const float* w1     = (const float*)d_in[13];
  const float* b1     = (const float*)d_in[14];
  const float* w2     = (const float*)d_in[15];
  const float* b2     = (const float*)d_in[16];

  char* ws = (char*)d_ws;
  u16* xb    = (u16*)(ws + 0);            // 16 MiB (LN1/LN2 out; ctxO during attn)
  u16* wqkvT = (u16*)(ws + 16777216);     // 6 MiB [3072][1024]
  u16* wpT   = (u16*)(ws + 23068672);     // 2 MiB
  u16* w1T   = (u16*)(ws + 25165824);     // 8 MiB
  u16* w2T   = (u16*)(ws + 33554432);     // 8 MiB
  u16* qb    = (u16*)(ws + 41943040);     // q,k,v contiguous: 3 x 16 MiB
  u16* kb    = (u16*)(ws + 58720256);
  u16* vb    = (u16*)(ws + 75497472);
  u16* ctxE  = (u16*)(ws + 92274688);     // 16 MiB (merged ctx in-place)
  u16* ctxO  = (u16*)(ws + 0);            // aliases xb (dead between qkv and ln2)
  float* bqkv = (float*)(ws + 92274688);  // aliases ctxE start (dead before attn)
  u16* res2  = (u16*)(ws + 109051904);    // 16 MiB bf16
  u16* mid   = (u16*)(ws + 41943040);     // 64 MiB, reuses qb..ctx

  prep_kernel<<<12300, dim3(32, 8), 0, stream>>>(wq, wk, wv, wproj, w1, w2,
                                                 bq, bk, bv,
                                                 wqkvT, wpT, w1T, w2T, bqkv);

  ln_kernel<0><<<8192, 256, 0, stream>>>(hidden, ln1_g, ln1_b, xb);

  gemm8<0><<<384, 512, 0, stream>>>(xb, wqkvT, bqkv, nullptr, qb, 8192, 3072, 1024);

  attn_kernel<<<512, 512, 0, stream>>>(qb, kb, vb, ctxE, ctxO);
  merge_kernel<<<4096, 256, 0, stream>>>(ctxE, ctxO, ctxE);

  gemmW<1><<<256, 512, 0, stream>>>(ctxE, wpT, bproj, hidden, res2, 8192, 1024, 1024);

  ln_kernel<1><<<8192, 256, 0, stream>>>(res2, ln2_g, ln2_b, xb);

  gemm8<2><<<512, 512, 0, stream>>>(xb, w1T, b1, nullptr, mid, 8192, 4096, 1024);
  gemmW<3><<<256, 512, 0, stream>>>(mid, w2T, b2, res2, (float*)d_out, 8192, 1024, 4096);
}

// Round 24
// 359.185 us; speedup vs baseline: 1.1875x; 1.0096x over previous
//
#include <hip/hip_runtime.h>
#include <math.h>

typedef unsigned short u16;
typedef unsigned int u32;
typedef __attribute__((ext_vector_type(8))) short bf16x8;
typedef __attribute__((ext_vector_type(8))) unsigned short u16x8;
typedef __attribute__((ext_vector_type(4))) float f32x4;
typedef __attribute__((ext_vector_type(4))) unsigned int u32x4;

__device__ __forceinline__ u16 f2bf(float f){
  union { float f; unsigned u; } c; c.f = f;
  unsigned u = c.u;
  return (u16)((u + 0x7fffu + ((u >> 16) & 1u)) >> 16);
}
__device__ __forceinline__ float bf2f(u16 h){
  union { unsigned u; float f; } c; c.u = ((unsigned)h) << 16;
  return c.f;
}
// single-instruction packed f32->bf16 (RNE), gfx950 has no builtin (T12/m240)
__device__ __forceinline__ u32 pack2cvt(float lo, float hi){
  u32 r;
  asm("v_cvt_pk_bf16_f32 %0, %1, %2" : "=v"(r) : "v"(lo), "v"(hi));
  return r;
}
__device__ __forceinline__ void gload_lds16(const void* g, void* l){
  __builtin_amdgcn_global_load_lds((const __attribute__((address_space(1))) void*)g,
                                   (__attribute__((address_space(3))) void*)l, 16, 0, 0);
}
// attention V^T swizzle (r17): XOR row bits into chunk bits (byte bits 6-9).
__device__ __forceinline__ int swz(int row, int bc){
  return (row << 10) + (bc ^ ((row & 15) << 6));
}

#define BAR() asm volatile("s_barrier" ::: "memory")

// ---------------- fused prep: 6 weight transposes (f32 [K][N] -> bf16 [N][K])
// + bias concat, one launch.
__global__ __launch_bounds__(256) void prep_kernel(
    const float* __restrict__ wq, const float* __restrict__ wk,
    const float* __restrict__ wv, const float* __restrict__ wproj,
    const float* __restrict__ w1, const float* __restrict__ w2,
    const float* __restrict__ bq, const float* __restrict__ bk,
    const float* __restrict__ bv,
    u16* __restrict__ wqkvT, u16* __restrict__ wpT,
    u16* __restrict__ w1T, u16* __restrict__ w2T, float* __restrict__ bqkv)
{
  const int id = blockIdx.x;
  const int tx = threadIdx.x, ty = threadIdx.y;
  if (id >= 12288) {                       // bias concat
    const int i = (id - 12288) * 256 + ty * 32 + tx;
    bqkv[i] = i < 1024 ? bq[i] : (i < 2048 ? bk[i - 1024] : bv[i - 2048]);
    return;
  }
  const float* in; u16* out; int K, N, rel;
  if (id < 3072)      { const int w = id >> 10; rel = id & 1023;
                        in = w == 0 ? wq : (w == 1 ? wk : wv);
                        out = wqkvT + w * 1048576; K = 1024; N = 1024; }
  else if (id < 4096) { rel = id - 3072; in = wproj; out = wpT;  K = 1024; N = 1024; }
  else if (id < 8192) { rel = id - 4096; in = w1;    out = w1T;  K = 1024; N = 4096; }
  else                { rel = id - 8192; in = w2;    out = w2T;  K = 4096; N = 1024; }
  const int nbx = N >> 5;
  const int n0 = (rel % nbx) << 5, k0 = (rel / nbx) << 5;
  __shared__ float tile[32][33];
  #pragma unroll
  for (int r = 0; r < 32; r += 8)
    tile[ty + r][tx] = in[(size_t)(k0 + ty + r) * N + n0 + tx];
  __syncthreads();
  #pragma unroll
  for (int r = 0; r < 32; r += 8)
    out[(size_t)(n0 + ty + r) * K + k0 + tx] = f2bf(tile[tx][ty + r]);
}

// ---------------- layernorm: [rows][1024] (f32 or bf16 in) -> bf16 out
__device__ __forceinline__ float blockReduce(float v, float* ws){
  #pragma unroll
  for (int m = 1; m < 64; m <<= 1) v += __shfl_xor(v, m, 64);
  int w = threadIdx.x >> 6;
  __syncthreads();
  if ((threadIdx.x & 63) == 0) ws[w] = v;
  __syncthreads();
  return ws[0] + ws[1] + ws[2] + ws[3];
}

struct U16x4 { u16 x, y, z, w; };

template<int BF16IN>
__global__ __launch_bounds__(256) void ln_kernel(const void* __restrict__ in_, const float* __restrict__ g,
    const float* __restrict__ be, u16* __restrict__ out){
  __shared__ float ws[4];
  int row = blockIdx.x;
  float vx, vy, vz, vw;
  if constexpr (BF16IN) {
    const U16x4 v = ((const U16x4*)((const u16*)in_ + ((size_t)row << 10)))[threadIdx.x];
    vx = bf2f(v.x); vy = bf2f(v.y); vz = bf2f(v.z); vw = bf2f(v.w);
  } else {
    const float4 v = ((const float4*)((const float*)in_ + ((size_t)row << 10)))[threadIdx.x];
    vx = v.x; vy = v.y; vz = v.z; vw = v.w;
  }
  float s = vx + vy + vz + vw;
  s = blockReduce(s, ws);
  float mean = s * (1.f / 1024.f);
  float dx = vx - mean, dy = vy - mean, dz = vz - mean, dw = vw - mean;
  float s2 = dx*dx + dy*dy + dz*dz + dw*dw;
  s2 = blockReduce(s2, ws);
  float rstd = rsqrtf(s2 * (1.f / 1024.f) + 1e-5f);
  float4 gv = ((const float4*)g)[threadIdx.x];
  float4 bv = ((const float4*)be)[threadIdx.x];
  U16x4 ov;
  ov.x = f2bf(dx * rstd * gv.x + bv.x);
  ov.y = f2bf(dy * rstd * gv.y + bv.y);
  ov.z = f2bf(dz * rstd * gv.z + bv.z);
  ov.w = f2bf(dw * rstd * gv.w + bv.w);
  ((U16x4*)(out + ((size_t)row << 10)))[threadIdx.x] = ov;
}

// ================= 256x256 8-phase bf16 GEMM =========
// r24: bv cached per-QN in registers (bv[2][..]) — quadrant order (0,0)(0,1)
// (1,1)(1,0) lets phases 3,4 reuse bv read in phases 2,1. LDS reads/group
// 32 -> 24. RDB flags which phases read bv. Register liveness safe: bv[QN]'s
// LDS source region is not overwritten until the next LB-half (stage calendar
// unchanged -> WAR/vmcnt proofs carry over).
template<int QM, int QN, int LB, int RDA, int RDB, int WAIT, typename F>
__device__ __forceinline__ void ph256(const char* lds, const int (&aoff)[2], const int (&boff)[2],
    bf16x8 (&af)[4][2], bf16x8 (&bv)[2][2][2], f32x4 (&acc)[8][4], F&& stg){
  if constexpr (RDA) {
    const char* Ar = lds + LB*65536 + QM*16384;
    #pragma unroll
    for (int fi = 0; fi < 4; ++fi)
      #pragma unroll
      for (int ks = 0; ks < 2; ++ks)
        af[fi][ks] = *(const bf16x8*)(Ar + fi*2048 + aoff[ks]);
  }
  if constexpr (RDB) {
    const char* Br = lds + LB*65536 + 32768 + QN*16384;
    #pragma unroll
    for (int fj = 0; fj < 2; ++fj)
      #pragma unroll
      for (int ks = 0; ks < 2; ++ks)
        bv[QN][fj][ks] = *(const bf16x8*)(Br + fj*2048 + boff[ks]);
  }
  stg();
  BAR();
  __builtin_amdgcn_s_setprio(1);
  #pragma unroll
  for (int fi = 0; fi < 4; ++fi)
    #pragma unroll
    for (int fj = 0; fj < 2; ++fj){
      acc[QM*4+fi][QN*2+fj] = __builtin_amdgcn_mfma_f32_16x16x32_bf16(af[fi][0], bv[QN][fj][0], acc[QM*4+fi][QN*2+fj], 0, 0, 0);
      acc[QM*4+fi][QN*2+fj] = __builtin_amdgcn_mfma_f32_16x16x32_bf16(af[fi][1], bv[QN][fj][1], acc[QM*4+fi][QN*2+fj], 0, 0, 0);
    }
  __builtin_amdgcn_s_setprio(0);
  if constexpr (WAIT >= 0)
    asm volatile("s_waitcnt vmcnt(%0)" :: "n"(WAIT) : "memory");
  BAR();
}

// EPI 0: bf16 scatter to q/k/v [3][B*NH, S, HD] (+bias)
// EPI 2: bf16 = gelu(acc + bias)   [tanh-form sigmoid approx]
// launch_bounds (512,1): LDS 144KB already caps 1 block/CU; VGPR demand ~132
// needs the 256-cap (the (512,2) 128-cap would spill — r14 lesson).
template<int EPI>
__global__ __launch_bounds__(512, 1) void gemm8(
    const u16* __restrict__ A, const u16* __restrict__ Bt,
    const float* __restrict__ bias, const float* __restrict__ add,
    void* __restrict__ out, int M, int N, int K)
{
  __shared__ char lds[147456];
  const int NT = K >> 6;
  const int NI = NT >> 1;
  const int nbx = N >> 8;
  const int nwg = gridDim.x, orig = blockIdx.x;
  const int q = nwg >> 3, r = nwg & 7, x = orig & 7;
  const int wg = (x < r ? x * (q + 1) : r * (q + 1) + (x - r) * q) + (orig >> 3);
  const int bx = wg % nbx, by = wg / nbx;
  const int m0 = by << 8, n0 = bx << 8;

  const int tid = threadIdx.x, wave = tid >> 6, lane = tid & 63;
  const int wr = (wave >> 2) & 1, wc = wave & 3;
  const int lcol = lane & 15, lrow4 = lane >> 4;

  int aoff[2], boff[2];
  #pragma unroll
  for (int ks = 0; ks < 2; ++ks){
    const int chunk = (ks*4 + lrow4) ^ (lane & 7);
    aoff[ks] = (wr*64 + lcol)*128 + chunk*16;
    boff[ks] = (wc*32 + lcol)*128 + chunk*16;
  }

  const int o0 = tid << 4, o1 = (tid + 512) << 4;
  const int row0 = o0 >> 7, c0 = (o0 >> 4) & 7;
  const int row1 = o1 >> 7, c1 = (o1 >> 4) & 7;
  const char* gbase[2][2][2];
  #pragma unroll
  for (int h = 0; h < 2; ++h) {
    gbase[0][h][0] = (const char*)(A  + (size_t)(m0 + h*128 + row0) * K) + ((c0 ^ (row0 & 7)) << 4);
    gbase[0][h][1] = (const char*)(A  + (size_t)(m0 + h*128 + row1) * K) + ((c1 ^ (row1 & 7)) << 4);
    gbase[1][h][0] = (const char*)(Bt + (size_t)(n0 + h*128 + row0) * K) + ((c0 ^ (row0 & 7)) << 4);
    gbase[1][h][1] = (const char*)(Bt + (size_t)(n0 + h*128 + row1) * K) + ((c1 ^ (row1 & 7)) << 4);
  }

  auto STAGE = [&](int isB, int h, int tt){
    const int rb = (tt < NT) ? ((tt & 1) * 65536 + isB * 32768 + h * 16384) : 131072;
    const size_t tb = (size_t)((tt < NT) ? tt : NT - 1) << 7;
    gload_lds16(gbase[isB][h][0] + tb, (char*)lds + rb + o0);
    gload_lds16(gbase[isB][h][1] + tb, (char*)lds + rb + o1);
  };

  f32x4 acc[8][4] = {};
  bf16x8 af[4][2], bv[2][2][2];

  STAGE(0, 0, 0);
  STAGE(1, 0, 0);
  STAGE(0, 1, 0);
  STAGE(1, 1, 0);
  STAGE(0, 0, 1);
  STAGE(1, 1, 1);
  STAGE(0, 1, 1);
  asm volatile("s_waitcnt vmcnt(6)" ::: "memory");
  BAR();

  for (int i = 0; i < NI; ++i) {
    const int T = 2*i;
    //    QM QN LB RDA RDB  W
    ph256<0, 0, 0, 1,  1, -1>(lds, aoff, boff, af, bv, acc, [&]{ STAGE(1, 0, T+1); });
    ph256<0, 1, 0, 0,  1, -1>(lds, aoff, boff, af, bv, acc, [&]{ STAGE(0, 0, T+2); });
    ph256<1, 1, 0, 1,  0, -1>(lds, aoff, boff, af, bv, acc, [&]{});
    ph256<1, 0, 0, 0,  0,  4>(lds, aoff, boff, af, bv, acc, [&]{ STAGE(1, 1, T+2); });
    ph256<0, 0, 1, 1,  1, -1>(lds, aoff, boff, af, bv, acc, [&]{ STAGE(1, 0, T+2); });
    ph256<0, 1, 1, 0,  1, -1>(lds, aoff, boff, af, bv, acc, [&]{ STAGE(0, 1, T+2); });
    ph256<1, 1, 1, 1,  0, -1>(lds, aoff, boff, af, bv, acc, [&]{ STAGE(0, 0, T+3); });
    ph256<1, 0, 1, 0,  0,  6>(lds, aoff, boff, af, bv, acc, [&]{ STAGE(1, 1, T+3); STAGE(0, 1, T+3); });
  }

  { size_t bp = (size_t)bias, ap = (size_t)add;
    asm volatile("" : "+v"(bp), "+v"(ap));
    bias = (const float*)bp; add = (const float*)ap; }

  #pragma unroll
  for (int mi = 0; mi < 8; ++mi) {
    const int gmb = m0 + (mi>>2)*128 + wr*64 + (mi&3)*16 + lrow4*4;
    #pragma unroll
    for (int ni = 0; ni < 4; ++ni) {
      const int gn = n0 + (ni>>1)*128 + wc*32 + (ni&1)*16 + lcol;
      const float bs = bias[gn];
      #pragma unroll
      for (int rr = 0; rr < 4; ++rr) {
        const int gm = gmb + rr;
        float v = acc[mi][ni][rr] + bs;
        if constexpr (EPI == 0) {
          const int which = gn >> 10, g = gn & 1023;
          const int b = gm >> 11, s = gm & 2047;
          const int h = g >> 6, d = g & 63;
          ((u16*)out)[(size_t)which * 8388608 + ((((size_t)((b << 4) + h) << 11) + s) << 6) + d] = f2bf(v);
        } else {
          const float y2 = 1.5957691216f * v + 0.0713548353f * v * v * v;
          const float e = __expf(y2);
          ((u16*)out)[(size_t)gm * N + gn] = f2bf(v - v / (1.f + e));
        }
      }
    }
  }
}

// ================= 128x256 4-phase bf16 GEMM (wide) ====
// EPI 1: proj  -> out bf16 = acc + bias + add(f32)
// EPI 3: ffn2  -> out f32  = acc + bias + add(bf16)
template<int QN, int LB, int RDA, int WAIT, typename F>
__device__ __forceinline__ void phW(const char* lds, const int (&aoff)[2], const int (&boff)[2],
    bf16x8 (&af)[4][2], bf16x8 (&bv)[2][2], f32x4 (&acc)[4][4], F&& stg){
  if constexpr (RDA) {
    const char* Ar = lds + LB*49152;
    #pragma unroll
    for (int fi = 0; fi < 4; ++fi)
      #pragma unroll
      for (int ks = 0; ks < 2; ++ks)
        af[fi][ks] = *(const bf16x8*)(Ar + fi*2048 + aoff[ks]);
  }
  {
    const char* Br = lds + LB*49152 + 16384 + QN*16384;
    #pragma unroll
    for (int fj = 0; fj < 2; ++fj)
      #pragma unroll
      for (int ks = 0; ks < 2; ++ks)
        bv[fj][ks] = *(const bf16x8*)(Br + fj*2048 + boff[ks]);
  }
  stg();
  BAR();
  __builtin_amdgcn_s_setprio(1);
  #pragma unroll
  for (int fi = 0; fi < 4; ++fi)
    #pragma unroll
    for (int fj = 0; fj < 2; ++fj){
      acc[fi][QN*2+fj] = __builtin_amdgcn_mfma_f32_16x16x32_bf16(af[fi][0], bv[fj][0], acc[fi][QN*2+fj], 0, 0, 0);
      acc[fi][QN*2+fj] = __builtin_amdgcn_mfma_f32_16x16x32_bf16(af[fi][1], bv[fj][1], acc[fi][QN*2+fj], 0, 0, 0);
    }
  __builtin_amdgcn_s_setprio(0);
  if constexpr (WAIT >= 0)
    asm volatile("s_waitcnt vmcnt(%0)" :: "n"(WAIT) : "memory");
  BAR();
}

template<int EPI>
__global__ __launch_bounds__(512, 2) void gemmW(
    const u16* __restrict__ A, const u16* __restrict__ Bt,
    const float* __restrict__ bias, const void* __restrict__ add,
    void* __restrict__ out, int M, int N, int K)
{
  __shared__ char lds[106496];
  const int NT = K >> 6;
  const int NI = NT >> 1;
  const int nbx = N >> 8;
  const int nwg = gridDim.x, orig = blockIdx.x;
  const int q = nwg >> 3, r = nwg & 7, x = orig & 7;
  const int wg = (x < r ? x * (q + 1) : r * (q + 1) + (x - r) * q) + (orig >> 3);
  const int bx = wg % nbx, by = wg / nbx;
  const int m0 = by << 7, n0 = bx << 8;

  const int tid = threadIdx.x, wave = tid >> 6, lane = tid & 63;
  const int wr = wave >> 2, wc = wave & 3;
  const int lcol = lane & 15, lrow4 = lane >> 4;

  int aoff[2], boff[2];
  #pragma unroll
  for (int ks = 0; ks < 2; ++ks){
    const int chunk = (ks*4 + lrow4) ^ (lane & 7);
    aoff[ks] = (wr*64 + lcol)*128 + chunk*16;
    boff[ks] = (wc*32 + lcol)*128 + chunk*16;
  }

  const int o0 = tid << 4, o1 = (tid + 512) << 4;
  const int row0 = o0 >> 7, c0 = (o0 >> 4) & 7;
  const int row1 = o1 >> 7, c1 = (o1 >> 4) & 7;
  const char* gbase[3][2];
  gbase[0][0] = (const char*)(A  + (size_t)(m0 + row0) * K) + ((c0 ^ (row0 & 7)) << 4);
  gbase[0][1] = (const char*)(A  + (size_t)(m0 + row1) * K) + ((c1 ^ (row1 & 7)) << 4);
  gbase[1][0] = (const char*)(Bt + (size_t)(n0 + row0) * K) + ((c0 ^ (row0 & 7)) << 4);
  gbase[1][1] = (const char*)(Bt + (size_t)(n0 + row1) * K) + ((c1 ^ (row1 & 7)) << 4);
  gbase[2][0] = (const char*)(Bt + (size_t)(n0 + 128 + row0) * K) + ((c0 ^ (row0 & 7)) << 4);
  gbase[2][1] = (const char*)(Bt + (size_t)(n0 + 128 + row1) * K) + ((c1 ^ (row1 & 7)) << 4);

  auto STAGE = [&](int kind, int tt){
    const int rb = (tt < NT) ? ((tt & 1) * 49152 + kind * 16384) : 98304;
    const size_t tb = (size_t)((tt < NT) ? tt : NT - 1) << 7;
    gload_lds16(gbase[kind][0] + tb, (char*)lds + rb + o0);
    gload_lds16(gbase[kind][1] + tb, (char*)lds + rb + o1);
  };

  f32x4 acc[4][4] = {};
  bf16x8 af[4][2], bv[2][2];

  STAGE(0, 0);
  STAGE(1, 0);
  STAGE(2, 0);
  STAGE(0, 1);
  STAGE(1, 1);
  asm volatile("s_waitcnt vmcnt(4)" ::: "memory");
  BAR();

  for (int i = 0; i < NI; ++i) {
    const int T = 2*i;
    phW<0, 0, 1, -1>(lds, aoff, boff, af, bv, acc, [&]{ STAGE(2, T+1); });
    phW<1, 0, 0,  4>(lds, aoff, boff, af, bv, acc, [&]{ STAGE(0, T+2); STAGE(1, T+2); });
    phW<0, 1, 1, -1>(lds, aoff, boff, af, bv, acc, [&]{ STAGE(2, T+2); });
    phW<1, 1, 0,  4>(lds, aoff, boff, af, bv, acc, [&]{ STAGE(0, T+3); STAGE(1, T+3); });
  }

  { size_t bp = (size_t)bias, ap = (size_t)add;
    asm volatile("" : "+v"(bp), "+v"(ap));
    bias = (const float*)bp; add = (const void*)ap; }

  #pragma unroll
  for (int fi = 0; fi < 4; ++fi) {
    const int gmb = m0 + wr*64 + fi*16 + lrow4*4;
    #pragma unroll
    for (int j = 0; j < 4; ++j) {
      const int gn = n0 + (j>>1)*128 + wc*32 + (j&1)*16 + lcol;
      const float bs = bias[gn];
      #pragma unroll
      for (int rr = 0; rr < 4; ++rr) {
        const int gm = gmb + rr;
        float v = acc[fi][j][rr] + bs;
        if constexpr (EPI == 1) {
          ((u16*)out)[(size_t)gm * N + gn] = f2bf(v + ((const float*)add)[(size_t)gm * N + gn]);
        } else {
          ((float*)out)[(size_t)gm * N + gn] = v + bf2f(((const u16*)add)[(size_t)gm * N + gn]);
        }
      }
    }
  }
}

// ================= windowed attention: quarter-split + K in LDS, 512 threads ==
// (r19 structure; r21 cvt_pk packs)
template<int NJ>  // NJ = W/16 (24 or 32)
__device__ void attn_core(const u16* __restrict__ Qp, u16* __restrict__ ctxP,
    const char* ktb, const char* vtb, int start, int widx, int bh)
{
  const int tid = threadIdx.x, wave = tid >> 6, lane = tid & 63;
  const int q = lane & 15, g = lane >> 4;
  constexpr int QTR = NJ / 4;
  const float scale = 0.125f;  // 64^-0.5
  const int b = bh >> 4, h = bh & 15;
  const int sw0 = ((g ^ (q & 7)) << 4);
  const int sw1 = (((4 | g) ^ (q & 7)) << 4);

  for (int qt = wave; qt < NJ; qt += 8) {
    const int q0 = qt * 16;
    const bf16x8 bq0 = *(const bf16x8*)(Qp + (q0 + q) * 64 + g * 8);
    const bf16x8 bq1 = *(const bf16x8*)(Qp + (q0 + q) * 64 + 32 + g * 8);
    float m = -3.0e38f, l = 0.f;
    f32x4 o[4] = {};
    const int s0 = ((g & 1) << 5) + q;
    const int s1 = s0 + 16;
    const bool lowj = (g < 2);

    #pragma unroll
    for (int hh = 0; hh < 4; ++hh) {
      f32x4 acc[QTR];
      #pragma unroll
      for (int j = 0; j < QTR; ++j) {
        const int jj = hh * QTR + j;
        const char* kr = ktb + (jj*16 + q) * 128;
        bf16x8 k0 = *(const bf16x8*)(kr + sw0);
        bf16x8 k1 = *(const bf16x8*)(kr + sw1);
        f32x4 t = {};
        t = __builtin_amdgcn_mfma_f32_16x16x32_bf16(k0, bq0, t, 0, 0, 0);
        t = __builtin_amdgcn_mfma_f32_16x16x32_bf16(k1, bq1, t, 0, 0, 0);
        acc[j] = t;
        if ((j & 3) == 3) __builtin_amdgcn_sched_barrier(0);  // cap read hoisting
      }
      float mh = -3.0e38f;
      #pragma unroll
      for (int j = 0; j < QTR; ++j)
        #pragma unroll
        for (int r = 0; r < 4; ++r) mh = fmaxf(mh, acc[j][r]);
      mh = fmaxf(mh, __shfl_xor(mh, 16, 64));
      mh = fmaxf(mh, __shfl_xor(mh, 32, 64));
      const float mn = fmaxf(m, mh);
      const float fr = __expf((m - mn) * scale);
      m = mn;
      l *= fr;
      #pragma unroll
      for (int df = 0; df < 4; ++df)
        #pragma unroll
        for (int r = 0; r < 4; ++r) o[df][r] *= fr;
      #pragma unroll
      for (int j = 0; j < QTR; ++j)
        #pragma unroll
        for (int r = 0; r < 4; ++r) {
          float e = __expf((acc[j][r] - mn) * scale);
          acc[j][r] = e;
          l += e;
        }
      #pragma unroll
      for (int c = 0; c < QTR / 2; ++c) {
        const u32 a0 = pack2cvt(acc[2*c][0],   acc[2*c][1]);
        const u32 b0 = pack2cvt(acc[2*c][2],   acc[2*c][3]);
        const u32 a1 = pack2cvt(acc[2*c+1][0], acc[2*c+1][1]);
        const u32 b1 = pack2cvt(acc[2*c+1][2], acc[2*c+1][3]);
        const u32 A0l = __shfl(a0, s0, 64), A1l = __shfl(a1, s0, 64);
        const u32 B0l = __shfl(b0, s0, 64), B1l = __shfl(b1, s0, 64);
        const u32 A0h = __shfl(a0, s1, 64), A1h = __shfl(a1, s1, 64);
        const u32 B0h = __shfl(b0, s1, 64), B1h = __shfl(b1, s1, 64);
        union { u32 u[4]; bf16x8 v; } pf;
        pf.u[0] = lowj ? A0l : A1l;
        pf.u[1] = lowj ? B0l : B1l;
        pf.u[2] = lowj ? A0h : A1h;
        pf.u[3] = lowj ? B0h : B1h;
        const int cg = hh * (QTR / 2) + c;
        #pragma unroll
        for (int df = 0; df < 4; ++df) {
          bf16x8 pv = *(const bf16x8*)(vtb + swz(df*16 + q, (cg*32 + g*8) * 2));
          o[df] = __builtin_amdgcn_mfma_f32_16x16x32_bf16(pv, pf.v, o[df], 0, 0, 0);
        }
        if ((c & 1) == 1) __builtin_amdgcn_sched_barrier(0);
      }
    }
    l += __shfl_xor(l, 16, 64);
    l += __shfl_xor(l, 32, 64);
    const float rs = 1.f / l;

    const int p = start + q0 + q;
    const int rel = p - (widx * 256 - 128);
    const float wgt = (rel < 256) ? ((widx == 0) ? 1.f : (float)rel * (1.f / 255.f))
                                  : ((widx == 7) ? 1.f : (1.f - (float)(rel - 256) * (1.f / 255.f)));
    const float rw = rs * wgt;
    u32 w0[4], w1[4];
    #pragma unroll
    for (int df = 0; df < 4; ++df) {
      w0[df] = pack2cvt(o[df][0] * rw, o[df][1] * rw);
      w1[df] = pack2cvt(o[df][2] * rw, o[df][3] * rw);
    }
    u32 W8[8] = {};
    #pragma unroll
    for (int df = 0; df < 4; ++df)
      #pragma unroll
      for (int sg = 0; sg < 4; ++sg) {
        const u32 t0 = __shfl(w0[df], sg*16 + q, 64);
        const u32 t1 = __shfl(w1[df], sg*16 + q, 64);
        if (g == df) { W8[2*sg] = t0; W8[2*sg+1] = t1; }
      }
    u16* dst = ctxP + ((((size_t)(b << 11) + (size_t)p) << 10) + (h << 6) + (g << 4));
    u32x4 lo = { W8[0], W8[1], W8[2], W8[3] };
    u32x4 hi = { W8[4], W8[5], W8[6], W8[7] };
    *(u32x4*)dst = lo;
    *(u32x4*)(dst + 8) = hi;
  }
}

__global__ __launch_bounds__(512, 1) void attn_kernel(const u16* __restrict__ qg, const u16* __restrict__ kg,
    const u16* __restrict__ vg, u16* __restrict__ ctxE, u16* __restrict__ ctxO){
  __shared__ char lds[131072];   // K @0 (64KB), V^T @65536 (64KB) -> 1 block/CU
  const int widx = (int)blockIdx.x >> 6;
  const int bh = blockIdx.x & 63;
  const int i0 = widx << 8;
  int start = i0 - 128; if (start < 0) start = 0;
  int end = i0 + 384;   if (end > 2048) end = 2048;
  const int W = end - start;
  const int tid = threadIdx.x;
  const u16* Qp = qg + (((size_t)bh << 11) + start) * 64;
  const u16* Kp = kg + (((size_t)bh << 11) + start) * 64;
  const u16* Vp = vg + (((size_t)bh << 11) + start) * 64;
  const int nks = W >> 6;             // W*8 16B-chunks / 512 threads
  for (int s = 0; s < nks; ++s) {
    const int o = (tid + s*512) << 4;
    const int row = o >> 7, c = (o >> 4) & 7;
    const char* src = (const char*)(Kp + (size_t)row * 64) + ((c ^ (row & 7)) << 4);
    gload_lds16(src, (char*)lds + o);
  }
  char* vtb = (char*)lds + 65536;
  for (int idx = tid; idx < W * 8; idx += 512) {
    const int key = idx % W, d0 = (idx / W) << 3;
    u16x8 vv = *(const u16x8*)(Vp + key * 64 + d0);
    #pragma unroll
    for (int z = 0; z < 8; ++z)
      *(u16*)(vtb + swz(d0 + z, key * 2)) = vv[z];
  }
  __syncthreads();
  u16* ctxP = (widx & 1) ? ctxO : ctxE;
  if (W == 512) attn_core<32>(Qp, ctxP, (const char*)lds, vtb, start, widx, bh);
  else          attn_core<24>(Qp, ctxP, (const char*)lds, vtb, start, widx, bh);
}

// merge parity buffers: p<128 -> E; p>=1920 -> O; else E+O. In-place on E is safe.
__global__ __launch_bounds__(256) void merge_kernel(const u16* __restrict__ e,
    const u16* __restrict__ o, u16* __restrict__ out){
  const int i = blockIdx.x * 256 + threadIdx.x;     // u16x8 index
  const int p = (i >> 7) & 2047;                    // (i*8 >> 10) & 2047
  u16x8 ev = ((const u16x8*)e)[i];
  u16x8 ov = ((const u16x8*)o)[i];
  u16x8 r;
  if (p < 128)        r = ev;
  else if (p >= 1920) r = ov;
  else {
    #pragma unroll
    for (int z = 0; z < 8; ++z) r[z] = f2bf(bf2f(ev[z]) + bf2f(ov[z]));
  }
  ((u16x8*)out)[i] = r;
}

// ---------------- host
extern "C" void kernel_launch(void* const* d_in, const int* in_sizes, int n_in,
                              void* d_out, int out_size, void* d_ws, size_t ws_size,
                              hipStream_t stream) {
  const float* hidden = (const float*)d_in[0];
  const float* ln1_g  = (const float*)d_in[1];
  const float* ln1_b  = (const float*)d_in[2];
  const float* wq     = (const float*)d_in[3];
  const float* bq     = (const float*)d_in[4];
  const float* wk     = (const float*)d_in[5];
  const float* bk     = (const float*)d_in[6];
  const float* wv     = (const float*)d_in[7];
  const float* bv     = (const float*)d_in[8];
  const float* wproj  = (const float*)d_in[9];
  const float* bproj  = (const float*)d_in[10];
  const float* ln2_g  = (const float*)d_in[11];
  const float* ln2_b  = (const float*)d_in[12];
  const float* w1     = (const float*)d_in[13];
  const float* b1     = (const float*)d_in[14];
  const float* w2     = (const float*)d_in[15];
  const float* b2     = (const float*)d_in[16];

  char* ws = (char*)d_ws;
  u16* xb    = (u16*)(ws + 0);            // 16 MiB (LN1/LN2 out; ctxO during attn)
  u16* wqkvT = (u16*)(ws + 16777216);     // 6 MiB [3072][1024]
  u16* wpT   = (u16*)(ws + 23068672);     // 2 MiB
  u16* w1T   = (u16*)(ws + 25165824);     // 8 MiB
  u16* w2T   = (u16*)(ws + 33554432);     // 8 MiB
  u16* qb    = (u16*)(ws + 41943040);     // q,k,v contiguous: 3 x 16 MiB
  u16* kb    = (u16*)(ws + 58720256);
  u16* vb    = (u16*)(ws + 75497472);
  u16* ctxE  = (u16*)(ws + 92274688);     // 16 MiB (merged ctx in-place)
  u16* ctxO  = (u16*)(ws + 0);            // aliases xb (dead between qkv and ln2)
  float* bqkv = (float*)(ws + 92274688);  // aliases ctxE start (dead before attn)
  u16* res2  = (u16*)(ws + 109051904);    // 16 MiB bf16
  u16* mid   = (u16*)(ws + 41943040);     // 64 MiB, reuses qb..ctx

  prep_kernel<<<12300, dim3(32, 8), 0, stream>>>(wq, wk, wv, wproj, w1, w2,
                                                 bq, bk, bv,
                                                 wqkvT, wpT, w1T, w2T, bqkv);

  ln_kernel<0><<<8192, 256, 0, stream>>>(hidden, ln1_g, ln1_b, xb);

  gemm8<0><<<384, 512, 0, stream>>>(xb, wqkvT, bqkv, nullptr, qb, 8192, 3072, 1024);

  attn_kernel<<<512, 512, 0, stream>>>(qb, kb, vb, ctxE, ctxO);
  merge_kernel<<<4096, 256, 0, stream>>>(ctxE, ctxO, ctxE);

  gemmW<1><<<256, 512, 0, stream>>>(ctxE, wpT, bproj, hidden, res2, 8192, 1024, 1024);

  ln_kernel<1><<<8192, 256, 0, stream>>>(res2, ln2_g, ln2_b, xb);

  gemm8<2><<<512, 512, 0, stream>>>(xb, w1T, b1, nullptr, mid, 8192, 4096, 1024);
  gemmW<3><<<256, 512, 0, stream>>>(mid, w2T, b2, res2, (float*)d_out, 8192, 1024, 4096);
}

// Round 25
// 351.789 us; speedup vs baseline: 1.2124x; 1.0210x over previous
//
#include <hip/hip_runtime.h>
#include <math.h>

typedef unsigned short u16;
typedef unsigned int u32;
typedef __attribute__((ext_vector_type(8))) short bf16x8;
typedef __attribute__((ext_vector_type(8))) unsigned short u16x8;
typedef __attribute__((ext_vector_type(4))) float f32x4;
typedef __attribute__((ext_vector_type(4))) unsigned int u32x4;

__device__ __forceinline__ u16 f2bf(float f){
  union { float f; unsigned u; } c; c.f = f;
  unsigned u = c.u;
  return (u16)((u + 0x7fffu + ((u >> 16) & 1u)) >> 16);
}
__device__ __forceinline__ float bf2f(u16 h){
  union { unsigned u; float f; } c; c.u = ((unsigned)h) << 16;
  return c.f;
}
// single-instruction packed f32->bf16 (RNE), gfx950 has no builtin (T12/m240)
__device__ __forceinline__ u32 pack2cvt(float lo, float hi){
  u32 r;
  asm("v_cvt_pk_bf16_f32 %0, %1, %2" : "=v"(r) : "v"(lo), "v"(hi));
  return r;
}
__device__ __forceinline__ void gload_lds16(const void* g, void* l){
  __builtin_amdgcn_global_load_lds((const __attribute__((address_space(1))) void*)g,
                                   (__attribute__((address_space(3))) void*)l, 16, 0, 0);
}
// attention V^T swizzle (r17): XOR row bits into chunk bits (byte bits 6-9).
__device__ __forceinline__ int swz(int row, int bc){
  return (row << 10) + (bc ^ ((row & 15) << 6));
}

#define BAR() asm volatile("s_barrier" ::: "memory")

// ---------------- fused prep: 6 weight transposes (f32 [K][N] -> bf16 [N][K])
// + bias concat, one launch.
__global__ __launch_bounds__(256) void prep_kernel(
    const float* __restrict__ wq, const float* __restrict__ wk,
    const float* __restrict__ wv, const float* __restrict__ wproj,
    const float* __restrict__ w1, const float* __restrict__ w2,
    const float* __restrict__ bq, const float* __restrict__ bk,
    const float* __restrict__ bv,
    u16* __restrict__ wqkvT, u16* __restrict__ wpT,
    u16* __restrict__ w1T, u16* __restrict__ w2T, float* __restrict__ bqkv)
{
  const int id = blockIdx.x;
  const int tx = threadIdx.x, ty = threadIdx.y;
  if (id >= 12288) {                       // bias concat
    const int i = (id - 12288) * 256 + ty * 32 + tx;
    bqkv[i] = i < 1024 ? bq[i] : (i < 2048 ? bk[i - 1024] : bv[i - 2048]);
    return;
  }
  const float* in; u16* out; int K, N, rel;
  if (id < 3072)      { const int w = id >> 10; rel = id & 1023;
                        in = w == 0 ? wq : (w == 1 ? wk : wv);
                        out = wqkvT + w * 1048576; K = 1024; N = 1024; }
  else if (id < 4096) { rel = id - 3072; in = wproj; out = wpT;  K = 1024; N = 1024; }
  else if (id < 8192) { rel = id - 4096; in = w1;    out = w1T;  K = 1024; N = 4096; }
  else                { rel = id - 8192; in = w2;    out = w2T;  K = 4096; N = 1024; }
  const int nbx = N >> 5;
  const int n0 = (rel % nbx) << 5, k0 = (rel / nbx) << 5;
  __shared__ float tile[32][33];
  #pragma unroll
  for (int r = 0; r < 32; r += 8)
    tile[ty + r][tx] = in[(size_t)(k0 + ty + r) * N + n0 + tx];
  __syncthreads();
  #pragma unroll
  for (int r = 0; r < 32; r += 8)
    out[(size_t)(n0 + ty + r) * K + k0 + tx] = f2bf(tile[tx][ty + r]);
}

// ---------------- layernorm: [rows][1024] (f32 or bf16 in) -> bf16 out
__device__ __forceinline__ float blockReduce(float v, float* ws){
  #pragma unroll
  for (int m = 1; m < 64; m <<= 1) v += __shfl_xor(v, m, 64);
  int w = threadIdx.x >> 6;
  __syncthreads();
  if ((threadIdx.x & 63) == 0) ws[w] = v;
  __syncthreads();
  return ws[0] + ws[1] + ws[2] + ws[3];
}

struct U16x4 { u16 x, y, z, w; };

template<int BF16IN>
__global__ __launch_bounds__(256) void ln_kernel(const void* __restrict__ in_, const float* __restrict__ g,
    const float* __restrict__ be, u16* __restrict__ out){
  __shared__ float ws[4];
  int row = blockIdx.x;
  float vx, vy, vz, vw;
  if constexpr (BF16IN) {
    const U16x4 v = ((const U16x4*)((const u16*)in_ + ((size_t)row << 10)))[threadIdx.x];
    vx = bf2f(v.x); vy = bf2f(v.y); vz = bf2f(v.z); vw = bf2f(v.w);
  } else {
    const float4 v = ((const float4*)((const float*)in_ + ((size_t)row << 10)))[threadIdx.x];
    vx = v.x; vy = v.y; vz = v.z; vw = v.w;
  }
  float s = vx + vy + vz + vw;
  s = blockReduce(s, ws);
  float mean = s * (1.f / 1024.f);
  float dx = vx - mean, dy = vy - mean, dz = vz - mean, dw = vw - mean;
  float s2 = dx*dx + dy*dy + dz*dz + dw*dw;
  s2 = blockReduce(s2, ws);
  float rstd = rsqrtf(s2 * (1.f / 1024.f) + 1e-5f);
  float4 gv = ((const float4*)g)[threadIdx.x];
  float4 bv = ((const float4*)be)[threadIdx.x];
  U16x4 ov;
  ov.x = f2bf(dx * rstd * gv.x + bv.x);
  ov.y = f2bf(dy * rstd * gv.y + bv.y);
  ov.z = f2bf(dz * rstd * gv.z + bv.z);
  ov.w = f2bf(dw * rstd * gv.w + bv.w);
  ((U16x4*)(out + ((size_t)row << 10)))[threadIdx.x] = ov;
}

// ================= 256x256 8-phase bf16 GEMM (r24: bv cached per-QN) =========
template<int QM, int QN, int LB, int RDA, int RDB, int WAIT, typename F>
__device__ __forceinline__ void ph256(const char* lds, const int (&aoff)[2], const int (&boff)[2],
    bf16x8 (&af)[4][2], bf16x8 (&bv)[2][2][2], f32x4 (&acc)[8][4], F&& stg){
  if constexpr (RDA) {
    const char* Ar = lds + LB*65536 + QM*16384;
    #pragma unroll
    for (int fi = 0; fi < 4; ++fi)
      #pragma unroll
      for (int ks = 0; ks < 2; ++ks)
        af[fi][ks] = *(const bf16x8*)(Ar + fi*2048 + aoff[ks]);
  }
  if constexpr (RDB) {
    const char* Br = lds + LB*65536 + 32768 + QN*16384;
    #pragma unroll
    for (int fj = 0; fj < 2; ++fj)
      #pragma unroll
      for (int ks = 0; ks < 2; ++ks)
        bv[QN][fj][ks] = *(const bf16x8*)(Br + fj*2048 + boff[ks]);
  }
  stg();
  BAR();
  __builtin_amdgcn_s_setprio(1);
  #pragma unroll
  for (int fi = 0; fi < 4; ++fi)
    #pragma unroll
    for (int fj = 0; fj < 2; ++fj){
      acc[QM*4+fi][QN*2+fj] = __builtin_amdgcn_mfma_f32_16x16x32_bf16(af[fi][0], bv[QN][fj][0], acc[QM*4+fi][QN*2+fj], 0, 0, 0);
      acc[QM*4+fi][QN*2+fj] = __builtin_amdgcn_mfma_f32_16x16x32_bf16(af[fi][1], bv[QN][fj][1], acc[QM*4+fi][QN*2+fj], 0, 0, 0);
    }
  __builtin_amdgcn_s_setprio(0);
  if constexpr (WAIT >= 0)
    asm volatile("s_waitcnt vmcnt(%0)" :: "n"(WAIT) : "memory");
  BAR();
}

// EPI 0: bf16 scatter to q/k/v [3][B*NH, S, HD] (+bias)
// EPI 2: bf16 = gelu(acc + bias)   [tanh-form sigmoid approx; r25: rcp not div]
template<int EPI>
__global__ __launch_bounds__(512, 1) void gemm8(
    const u16* __restrict__ A, const u16* __restrict__ Bt,
    const float* __restrict__ bias, const float* __restrict__ add,
    void* __restrict__ out, int M, int N, int K)
{
  __shared__ char lds[147456];
  const int NT = K >> 6;
  const int NI = NT >> 1;
  const int nbx = N >> 8;
  const int nwg = gridDim.x, orig = blockIdx.x;
  const int q = nwg >> 3, r = nwg & 7, x = orig & 7;
  const int wg = (x < r ? x * (q + 1) : r * (q + 1) + (x - r) * q) + (orig >> 3);
  const int bx = wg % nbx, by = wg / nbx;
  const int m0 = by << 8, n0 = bx << 8;

  const int tid = threadIdx.x, wave = tid >> 6, lane = tid & 63;
  const int wr = (wave >> 2) & 1, wc = wave & 3;
  const int lcol = lane & 15, lrow4 = lane >> 4;

  int aoff[2], boff[2];
  #pragma unroll
  for (int ks = 0; ks < 2; ++ks){
    const int chunk = (ks*4 + lrow4) ^ (lane & 7);
    aoff[ks] = (wr*64 + lcol)*128 + chunk*16;
    boff[ks] = (wc*32 + lcol)*128 + chunk*16;
  }

  const int o0 = tid << 4, o1 = (tid + 512) << 4;
  const int row0 = o0 >> 7, c0 = (o0 >> 4) & 7;
  const int row1 = o1 >> 7, c1 = (o1 >> 4) & 7;
  const char* gbase[2][2][2];
  #pragma unroll
  for (int h = 0; h < 2; ++h) {
    gbase[0][h][0] = (const char*)(A  + (size_t)(m0 + h*128 + row0) * K) + ((c0 ^ (row0 & 7)) << 4);
    gbase[0][h][1] = (const char*)(A  + (size_t)(m0 + h*128 + row1) * K) + ((c1 ^ (row1 & 7)) << 4);
    gbase[1][h][0] = (const char*)(Bt + (size_t)(n0 + h*128 + row0) * K) + ((c0 ^ (row0 & 7)) << 4);
    gbase[1][h][1] = (const char*)(Bt + (size_t)(n0 + h*128 + row1) * K) + ((c1 ^ (row1 & 7)) << 4);
  }

  auto STAGE = [&](int isB, int h, int tt){
    const int rb = (tt < NT) ? ((tt & 1) * 65536 + isB * 32768 + h * 16384) : 131072;
    const size_t tb = (size_t)((tt < NT) ? tt : NT - 1) << 7;
    gload_lds16(gbase[isB][h][0] + tb, (char*)lds + rb + o0);
    gload_lds16(gbase[isB][h][1] + tb, (char*)lds + rb + o1);
  };

  f32x4 acc[8][4] = {};
  bf16x8 af[4][2], bv[2][2][2];

  STAGE(0, 0, 0);
  STAGE(1, 0, 0);
  STAGE(0, 1, 0);
  STAGE(1, 1, 0);
  STAGE(0, 0, 1);
  STAGE(1, 1, 1);
  STAGE(0, 1, 1);
  asm volatile("s_waitcnt vmcnt(6)" ::: "memory");
  BAR();

  for (int i = 0; i < NI; ++i) {
    const int T = 2*i;
    //    QM QN LB RDA RDB  W
    ph256<0, 0, 0, 1,  1, -1>(lds, aoff, boff, af, bv, acc, [&]{ STAGE(1, 0, T+1); });
    ph256<0, 1, 0, 0,  1, -1>(lds, aoff, boff, af, bv, acc, [&]{ STAGE(0, 0, T+2); });
    ph256<1, 1, 0, 1,  0, -1>(lds, aoff, boff, af, bv, acc, [&]{});
    ph256<1, 0, 0, 0,  0,  4>(lds, aoff, boff, af, bv, acc, [&]{ STAGE(1, 1, T+2); });
    ph256<0, 0, 1, 1,  1, -1>(lds, aoff, boff, af, bv, acc, [&]{ STAGE(1, 0, T+2); });
    ph256<0, 1, 1, 0,  1, -1>(lds, aoff, boff, af, bv, acc, [&]{ STAGE(0, 1, T+2); });
    ph256<1, 1, 1, 1,  0, -1>(lds, aoff, boff, af, bv, acc, [&]{ STAGE(0, 0, T+3); });
    ph256<1, 0, 1, 0,  0,  6>(lds, aoff, boff, af, bv, acc, [&]{ STAGE(1, 1, T+3); STAGE(0, 1, T+3); });
  }

  { size_t bp = (size_t)bias, ap = (size_t)add;
    asm volatile("" : "+v"(bp), "+v"(ap));
    bias = (const float*)bp; add = (const float*)ap; }

  #pragma unroll
  for (int mi = 0; mi < 8; ++mi) {
    const int gmb = m0 + (mi>>2)*128 + wr*64 + (mi&3)*16 + lrow4*4;
    #pragma unroll
    for (int ni = 0; ni < 4; ++ni) {
      const int gn = n0 + (ni>>1)*128 + wc*32 + (ni&1)*16 + lcol;
      const float bs = bias[gn];
      #pragma unroll
      for (int rr = 0; rr < 4; ++rr) {
        const int gm = gmb + rr;
        float v = acc[mi][ni][rr] + bs;
        if constexpr (EPI == 0) {
          const int which = gn >> 10, g = gn & 1023;
          const int b = gm >> 11, s = gm & 2047;
          const int h = g >> 6, d = g & 63;
          ((u16*)out)[(size_t)which * 8388608 + ((((size_t)((b << 4) + h) << 11) + s) << 6) + d] = f2bf(v);
        } else {
          const float y2 = 1.5957691216f * v + 0.0713548353f * v * v * v;
          const float e = __expf(y2);
          const float rc = __builtin_amdgcn_rcpf(1.f + e);   // r25: rcp not div
          ((u16*)out)[(size_t)gm * N + gn] = f2bf(v - v * rc);
        }
      }
    }
  }
}

// ================= 128x256 4-phase bf16 GEMM (wide) ====
// EPI 1: proj  -> out bf16 = acc + bias + add(f32)
// EPI 3: ffn2  -> out f32  = acc + bias + add(bf16)
template<int QN, int LB, int RDA, int WAIT, typename F>
__device__ __forceinline__ void phW(const char* lds, const int (&aoff)[2], const int (&boff)[2],
    bf16x8 (&af)[4][2], bf16x8 (&bv)[2][2], f32x4 (&acc)[4][4], F&& stg){
  if constexpr (RDA) {
    const char* Ar = lds + LB*49152;
    #pragma unroll
    for (int fi = 0; fi < 4; ++fi)
      #pragma unroll
      for (int ks = 0; ks < 2; ++ks)
        af[fi][ks] = *(const bf16x8*)(Ar + fi*2048 + aoff[ks]);
  }
  {
    const char* Br = lds + LB*49152 + 16384 + QN*16384;
    #pragma unroll
    for (int fj = 0; fj < 2; ++fj)
      #pragma unroll
      for (int ks = 0; ks < 2; ++ks)
        bv[fj][ks] = *(const bf16x8*)(Br + fj*2048 + boff[ks]);
  }
  stg();
  BAR();
  __builtin_amdgcn_s_setprio(1);
  #pragma unroll
  for (int fi = 0; fi < 4; ++fi)
    #pragma unroll
    for (int fj = 0; fj < 2; ++fj){
      acc[fi][QN*2+fj] = __builtin_amdgcn_mfma_f32_16x16x32_bf16(af[fi][0], bv[fj][0], acc[fi][QN*2+fj], 0, 0, 0);
      acc[fi][QN*2+fj] = __builtin_amdgcn_mfma_f32_16x16x32_bf16(af[fi][1], bv[fj][1], acc[fi][QN*2+fj], 0, 0, 0);
    }
  __builtin_amdgcn_s_setprio(0);
  if constexpr (WAIT >= 0)
    asm volatile("s_waitcnt vmcnt(%0)" :: "n"(WAIT) : "memory");
  BAR();
}

template<int EPI>
__global__ __launch_bounds__(512, 2) void gemmW(
    const u16* __restrict__ A, const u16* __restrict__ Bt,
    const float* __restrict__ bias, const void* __restrict__ add,
    void* __restrict__ out, int M, int N, int K)
{
  __shared__ char lds[106496];
  const int NT = K >> 6;
  const int NI = NT >> 1;
  const int nbx = N >> 8;
  const int nwg = gridDim.x, orig = blockIdx.x;
  const int q = nwg >> 3, r = nwg & 7, x = orig & 7;
  const int wg = (x < r ? x * (q + 1) : r * (q + 1) + (x - r) * q) + (orig >> 3);
  const int bx = wg % nbx, by = wg / nbx;
  const int m0 = by << 7, n0 = bx << 8;

  const int tid = threadIdx.x, wave = tid >> 6, lane = tid & 63;
  const int wr = wave >> 2, wc = wave & 3;
  const int lcol = lane & 15, lrow4 = lane >> 4;

  int aoff[2], boff[2];
  #pragma unroll
  for (int ks = 0; ks < 2; ++ks){
    const int chunk = (ks*4 + lrow4) ^ (lane & 7);
    aoff[ks] = (wr*64 + lcol)*128 + chunk*16;
    boff[ks] = (wc*32 + lcol)*128 + chunk*16;
  }

  const int o0 = tid << 4, o1 = (tid + 512) << 4;
  const int row0 = o0 >> 7, c0 = (o0 >> 4) & 7;
  const int row1 = o1 >> 7, c1 = (o1 >> 4) & 7;
  const char* gbase[3][2];
  gbase[0][0] = (const char*)(A  + (size_t)(m0 + row0) * K) + ((c0 ^ (row0 & 7)) << 4);
  gbase[0][1] = (const char*)(A  + (size_t)(m0 + row1) * K) + ((c1 ^ (row1 & 7)) << 4);
  gbase[1][0] = (const char*)(Bt + (size_t)(n0 + row0) * K) + ((c0 ^ (row0 & 7)) << 4);
  gbase[1][1] = (const char*)(Bt + (size_t)(n0 + row1) * K) + ((c1 ^ (row1 & 7)) << 4);
  gbase[2][0] = (const char*)(Bt + (size_t)(n0 + 128 + row0) * K) + ((c0 ^ (row0 & 7)) << 4);
  gbase[2][1] = (const char*)(Bt + (size_t)(n0 + 128 + row1) * K) + ((c1 ^ (row1 & 7)) << 4);

  auto STAGE = [&](int kind, int tt){
    const int rb = (tt < NT) ? ((tt & 1) * 49152 + kind * 16384) : 98304;
    const size_t tb = (size_t)((tt < NT) ? tt : NT - 1) << 7;
    gload_lds16(gbase[kind][0] + tb, (char*)lds + rb + o0);
    gload_lds16(gbase[kind][1] + tb, (char*)lds + rb + o1);
  };

  f32x4 acc[4][4] = {};
  bf16x8 af[4][2], bv[2][2];

  STAGE(0, 0);
  STAGE(1, 0);
  STAGE(2, 0);
  STAGE(0, 1);
  STAGE(1, 1);
  asm volatile("s_waitcnt vmcnt(4)" ::: "memory");
  BAR();

  for (int i = 0; i < NI; ++i) {
    const int T = 2*i;
    phW<0, 0, 1, -1>(lds, aoff, boff, af, bv, acc, [&]{ STAGE(2, T+1); });
    phW<1, 0, 0,  4>(lds, aoff, boff, af, bv, acc, [&]{ STAGE(0, T+2); STAGE(1, T+2); });
    phW<0, 1, 1, -1>(lds, aoff, boff, af, bv, acc, [&]{ STAGE(2, T+2); });
    phW<1, 1, 0,  4>(lds, aoff, boff, af, bv, acc, [&]{ STAGE(0, T+3); STAGE(1, T+3); });
  }

  { size_t bp = (size_t)bias, ap = (size_t)add;
    asm volatile("" : "+v"(bp), "+v"(ap));
    bias = (const float*)bp; add = (const void*)ap; }

  #pragma unroll
  for (int fi = 0; fi < 4; ++fi) {
    const int gmb = m0 + wr*64 + fi*16 + lrow4*4;
    #pragma unroll
    for (int j = 0; j < 4; ++j) {
      const int gn = n0 + (j>>1)*128 + wc*32 + (j&1)*16 + lcol;
      const float bs = bias[gn];
      #pragma unroll
      for (int rr = 0; rr < 4; ++rr) {
        const int gm = gmb + rr;
        float v = acc[fi][j][rr] + bs;
        if constexpr (EPI == 1) {
          ((u16*)out)[(size_t)gm * N + gn] = f2bf(v + ((const float*)add)[(size_t)gm * N + gn]);
        } else {
          ((float*)out)[(size_t)gm * N + gn] = v + bf2f(((const u16*)add)[(size_t)gm * N + gn]);
        }
      }
    }
  }
}

// ================= windowed attention: quarter-split + K in LDS, 512 threads ==
// (r19 structure; r21 cvt_pk packs)
template<int NJ>  // NJ = W/16 (24 or 32)
__device__ void attn_core(const u16* __restrict__ Qp, u16* __restrict__ ctxP,
    const char* ktb, const char* vtb, int start, int widx, int bh)
{
  const int tid = threadIdx.x, wave = tid >> 6, lane = tid & 63;
  const int q = lane & 15, g = lane >> 4;
  constexpr int QTR = NJ / 4;
  const float scale = 0.125f;  // 64^-0.5
  const int b = bh >> 4, h = bh & 15;
  const int sw0 = ((g ^ (q & 7)) << 4);
  const int sw1 = (((4 | g) ^ (q & 7)) << 4);

  for (int qt = wave; qt < NJ; qt += 8) {
    const int q0 = qt * 16;
    const bf16x8 bq0 = *(const bf16x8*)(Qp + (q0 + q) * 64 + g * 8);
    const bf16x8 bq1 = *(const bf16x8*)(Qp + (q0 + q) * 64 + 32 + g * 8);
    float m = -3.0e38f, l = 0.f;
    f32x4 o[4] = {};
    const int s0 = ((g & 1) << 5) + q;
    const int s1 = s0 + 16;
    const bool lowj = (g < 2);

    #pragma unroll
    for (int hh = 0; hh < 4; ++hh) {
      f32x4 acc[QTR];
      #pragma unroll
      for (int j = 0; j < QTR; ++j) {
        const int jj = hh * QTR + j;
        const char* kr = ktb + (jj*16 + q) * 128;
        bf16x8 k0 = *(const bf16x8*)(kr + sw0);
        bf16x8 k1 = *(const bf16x8*)(kr + sw1);
        f32x4 t = {};
        t = __builtin_amdgcn_mfma_f32_16x16x32_bf16(k0, bq0, t, 0, 0, 0);
        t = __builtin_amdgcn_mfma_f32_16x16x32_bf16(k1, bq1, t, 0, 0, 0);
        acc[j] = t;
        if ((j & 3) == 3) __builtin_amdgcn_sched_barrier(0);  // cap read hoisting
      }
      float mh = -3.0e38f;
      #pragma unroll
      for (int j = 0; j < QTR; ++j)
        #pragma unroll
        for (int r = 0; r < 4; ++r) mh = fmaxf(mh, acc[j][r]);
      mh = fmaxf(mh, __shfl_xor(mh, 16, 64));
      mh = fmaxf(mh, __shfl_xor(mh, 32, 64));
      const float mn = fmaxf(m, mh);
      const float fr = __expf((m - mn) * scale);
      m = mn;
      l *= fr;
      #pragma unroll
      for (int df = 0; df < 4; ++df)
        #pragma unroll
        for (int r = 0; r < 4; ++r) o[df][r] *= fr;
      #pragma unroll
      for (int j = 0; j < QTR; ++j)
        #pragma unroll
        for (int r = 0; r < 4; ++r) {
          float e = __expf((acc[j][r] - mn) * scale);
          acc[j][r] = e;
          l += e;
        }
      #pragma unroll
      for (int c = 0; c < QTR / 2; ++c) {
        const u32 a0 = pack2cvt(acc[2*c][0],   acc[2*c][1]);
        const u32 b0 = pack2cvt(acc[2*c][2],   acc[2*c][3]);
        const u32 a1 = pack2cvt(acc[2*c+1][0], acc[2*c+1][1]);
        const u32 b1 = pack2cvt(acc[2*c+1][2], acc[2*c+1][3]);
        const u32 A0l = __shfl(a0, s0, 64), A1l = __shfl(a1, s0, 64);
        const u32 B0l = __shfl(b0, s0, 64), B1l = __shfl(b1, s0, 64);
        const u32 A0h = __shfl(a0, s1, 64), A1h = __shfl(a1, s1, 64);
        const u32 B0h = __shfl(b0, s1, 64), B1h = __shfl(b1, s1, 64);
        union { u32 u[4]; bf16x8 v; } pf;
        pf.u[0] = lowj ? A0l : A1l;
        pf.u[1] = lowj ? B0l : B1l;
        pf.u[2] = lowj ? A0h : A1h;
        pf.u[3] = lowj ? B0h : B1h;
        const int cg = hh * (QTR / 2) + c;
        #pragma unroll
        for (int df = 0; df < 4; ++df) {
          bf16x8 pv = *(const bf16x8*)(vtb + swz(df*16 + q, (cg*32 + g*8) * 2));
          o[df] = __builtin_amdgcn_mfma_f32_16x16x32_bf16(pv, pf.v, o[df], 0, 0, 0);
        }
        if ((c & 1) == 1) __builtin_amdgcn_sched_barrier(0);
      }
    }
    l += __shfl_xor(l, 16, 64);
    l += __shfl_xor(l, 32, 64);
    const float rs = 1.f / l;

    const int p = start + q0 + q;
    const int rel = p - (widx * 256 - 128);
    const float wgt = (rel < 256) ? ((widx == 0) ? 1.f : (float)rel * (1.f / 255.f))
                                  : ((widx == 7) ? 1.f : (1.f - (float)(rel - 256) * (1.f / 255.f)));
    const float rw = rs * wgt;
    u32 w0[4], w1[4];
    #pragma unroll
    for (int df = 0; df < 4; ++df) {
      w0[df] = pack2cvt(o[df][0] * rw, o[df][1] * rw);
      w1[df] = pack2cvt(o[df][2] * rw, o[df][3] * rw);
    }
    u32 W8[8] = {};
    #pragma unroll
    for (int df = 0; df < 4; ++df)
      #pragma unroll
      for (int sg = 0; sg < 4; ++sg) {
        const u32 t0 = __shfl(w0[df], sg*16 + q, 64);
        const u32 t1 = __shfl(w1[df], sg*16 + q, 64);
        if (g == df) { W8[2*sg] = t0; W8[2*sg+1] = t1; }
      }
    u16* dst = ctxP + ((((size_t)(b << 11) + (size_t)p) << 10) + (h << 6) + (g << 4));
    u32x4 lo = { W8[0], W8[1], W8[2], W8[3] };
    u32x4 hi = { W8[4], W8[5], W8[6], W8[7] };
    *(u32x4*)dst = lo;
    *(u32x4*)(dst + 8) = hi;
  }
}

__global__ __launch_bounds__(512, 1) void attn_kernel(const u16* __restrict__ qg, const u16* __restrict__ kg,
    const u16* __restrict__ vg, u16* __restrict__ ctxE, u16* __restrict__ ctxO){
  __shared__ char lds[131072];   // K @0 (64KB), V^T @65536 (64KB) -> 1 block/CU
  const int widx = (int)blockIdx.x >> 6;
  const int bh = blockIdx.x & 63;
  const int i0 = widx << 8;
  int start = i0 - 128; if (start < 0) start = 0;
  int end = i0 + 384;   if (end > 2048) end = 2048;
  const int W = end - start;
  const int tid = threadIdx.x;
  const u16* Qp = qg + (((size_t)bh << 11) + start) * 64;
  const u16* Kp = kg + (((size_t)bh << 11) + start) * 64;
  const u16* Vp = vg + (((size_t)bh << 11) + start) * 64;
  const int nks = W >> 6;             // W*8 16B-chunks / 512 threads
  for (int s = 0; s < nks; ++s) {
    const int o = (tid + s*512) << 4;
    const int row = o >> 7, c = (o >> 4) & 7;
    const char* src = (const char*)(Kp + (size_t)row * 64) + ((c ^ (row & 7)) << 4);
    gload_lds16(src, (char*)lds + o);
  }
  char* vtb = (char*)lds + 65536;
  for (int idx = tid; idx < W * 8; idx += 512) {
    const int key = idx % W, d0 = (idx / W) << 3;
    u16x8 vv = *(const u16x8*)(Vp + key * 64 + d0);
    #pragma unroll
    for (int z = 0; z < 8; ++z)
      *(u16*)(vtb + swz(d0 + z, key * 2)) = vv[z];
  }
  __syncthreads();
  u16* ctxP = (widx & 1) ? ctxO : ctxE;
  if (W == 512) attn_core<32>(Qp, ctxP, (const char*)lds, vtb, start, widx, bh);
  else          attn_core<24>(Qp, ctxP, (const char*)lds, vtb, start, widx, bh);
}

// merge parity buffers: p<128 -> E; p>=1920 -> O; else E+O. In-place on E is safe.
__global__ __launch_bounds__(256) void merge_kernel(const u16* __restrict__ e,
    const u16* __restrict__ o, u16* __restrict__ out){
  const int i = blockIdx.x * 256 + threadIdx.x;     // u16x8 index
  const int p = (i >> 7) & 2047;                    // (i*8 >> 10) & 2047
  u16x8 ev = ((const u16x8*)e)[i];
  u16x8 ov = ((const u16x8*)o)[i];
  u16x8 r;
  if (p < 128)        r = ev;
  else if (p >= 1920) r = ov;
  else {
    #pragma unroll
    for (int z = 0; z < 8; ++z) r[z] = f2bf(bf2f(ev[z]) + bf2f(ov[z]));
  }
  ((u16x8*)out)[i] = r;
}

// ---------------- host
extern "C" void kernel_launch(void* const* d_in, const int* in_sizes, int n_in,
                              void* d_out, int out_size, void* d_ws, size_t ws_size,
                              hipStream_t stream) {
  const float* hidden = (const float*)d_in[0];
  const float* ln1_g  = (const float*)d_in[1];
  const float* ln1_b  = (const float*)d_in[2];
  const float* wq     = (const float*)d_in[3];
  const float* bq     = (const float*)d_in[4];
  const float* wk     = (const float*)d_in[5];
  const float* bk     = (const float*)d_in[6];
  const float* wv     = (const float*)d_in[7];
  const float* bv     = (const float*)d_in[8];
  const float* wproj  = (const float*)d_in[9];
  const float* bproj  = (const float*)d_in[10];
  const float* ln2_g  = (const float*)d_in[11];
  const float* ln2_b  = (const float*)d_in[12];
  const float* w1     = (const float*)d_in[13];
  const float* b1     = (const float*)d_in[14];
  const float* w2     = (const float*)d_in[15];
  const float* b2     = (const float*)d_in[16];

  char* ws = (char*)d_ws;
  u16* xb    = (u16*)(ws + 0);            // 16 MiB (LN1/LN2 out; ctxO during attn)
  u16* wqkvT = (u16*)(ws + 16777216);     // 6 MiB [3072][1024]
  u16* wpT   = (u16*)(ws + 23068672);     // 2 MiB
  u16* w1T   = (u16*)(ws + 25165824);     // 8 MiB
  u16* w2T   = (u16*)(ws + 33554432);     // 8 MiB
  u16* qb    = (u16*)(ws + 41943040);     // q,k,v contiguous: 3 x 16 MiB
  u16* kb    = (u16*)(ws + 58720256);
  u16* vb    = (u16*)(ws + 75497472);
  u16* ctxE  = (u16*)(ws + 92274688);     // 16 MiB (merged ctx in-place)
  u16* ctxO  = (u16*)(ws + 0);            // aliases xb (dead between qkv and ln2)
  float* bqkv = (float*)(ws + 92274688);  // aliases ctxE start (dead before attn)
  u16* res2  = (u16*)(ws + 109051904);    // 16 MiB bf16
  u16* mid   = (u16*)(ws + 41943040);     // 64 MiB, reuses qb..ctx

  prep_kernel<<<12300, dim3(32, 8), 0, stream>>>(wq, wk, wv, wproj, w1, w2,
                                                 bq, bk, bv,
                                                 wqkvT, wpT, w1T, w2T, bqkv);

  ln_kernel<0><<<8192, 256, 0, stream>>>(hidden, ln1_g, ln1_b, xb);

  gemm8<0><<<384, 512, 0, stream>>>(xb, wqkvT, bqkv, nullptr, qb, 8192, 3072, 1024);

  attn_kernel<<<512, 512, 0, stream>>>(qb, kb, vb, ctxE, ctxO);
  merge_kernel<<<4096, 256, 0, stream>>>(ctxE, ctxO, ctxE);

  gemmW<1><<<256, 512, 0, stream>>>(ctxE, wpT, bproj, hidden, res2, 8192, 1024, 1024);

  ln_kernel<1><<<8192, 256, 0, stream>>>(res2, ln2_g, ln2_b, xb);

  gemm8<2><<<512, 512, 0, stream>>>(xb, w1T, b1, nullptr, mid, 8192, 4096, 1024);
  gemmW<3><<<256, 512, 0, stream>>>(mid, w2T, b2, res2, (float*)d_out, 8192, 1024, 4096);
}

// Round 26
// 350.787 us; speedup vs baseline: 1.2159x; 1.0029x over previous
//
#include <hip/hip_runtime.h>
#include <math.h>

typedef unsigned short u16;
typedef unsigned int u32;
typedef __attribute__((ext_vector_type(8))) short bf16x8;
typedef __attribute__((ext_vector_type(8))) unsigned short u16x8;
typedef __attribute__((ext_vector_type(4))) float f32x4;
typedef __attribute__((ext_vector_type(4))) unsigned int u32x4;

__device__ __forceinline__ u16 f2bf(float f){
  union { float f; unsigned u; } c; c.f = f;
  unsigned u = c.u;
  return (u16)((u + 0x7fffu + ((u >> 16) & 1u)) >> 16);
}
__device__ __forceinline__ float bf2f(u16 h){
  union { unsigned u; float f; } c; c.u = ((unsigned)h) << 16;
  return c.f;
}
// single-instruction packed f32->bf16 (RNE), gfx950 has no builtin (T12/m240)
__device__ __forceinline__ u32 pack2cvt(float lo, float hi){
  u32 r;
  asm("v_cvt_pk_bf16_f32 %0, %1, %2" : "=v"(r) : "v"(lo), "v"(hi));
  return r;
}
__device__ __forceinline__ void gload_lds16(const void* g, void* l){
  __builtin_amdgcn_global_load_lds((const __attribute__((address_space(1))) void*)g,
                                   (__attribute__((address_space(3))) void*)l, 16, 0, 0);
}
// attention V^T swizzle (r17): XOR row bits into chunk bits (byte bits 6-9).
__device__ __forceinline__ int swz(int row, int bc){
  return (row << 10) + (bc ^ ((row & 15) << 6));
}

#define BAR() asm volatile("s_barrier" ::: "memory")

// ---------------- fused prep: 6 weight transposes (f32 [K][N] -> bf16 [N][K])
// + bias concat, one launch.
__global__ __launch_bounds__(256) void prep_kernel(
    const float* __restrict__ wq, const float* __restrict__ wk,
    const float* __restrict__ wv, const float* __restrict__ wproj,
    const float* __restrict__ w1, const float* __restrict__ w2,
    const float* __restrict__ bq, const float* __restrict__ bk,
    const float* __restrict__ bv,
    u16* __restrict__ wqkvT, u16* __restrict__ wpT,
    u16* __restrict__ w1T, u16* __restrict__ w2T, float* __restrict__ bqkv)
{
  const int id = blockIdx.x;
  const int tx = threadIdx.x, ty = threadIdx.y;
  if (id >= 12288) {                       // bias concat
    const int i = (id - 12288) * 256 + ty * 32 + tx;
    bqkv[i] = i < 1024 ? bq[i] : (i < 2048 ? bk[i - 1024] : bv[i - 2048]);
    return;
  }
  const float* in; u16* out; int K, N, rel;
  if (id < 3072)      { const int w = id >> 10; rel = id & 1023;
                        in = w == 0 ? wq : (w == 1 ? wk : wv);
                        out = wqkvT + w * 1048576; K = 1024; N = 1024; }
  else if (id < 4096) { rel = id - 3072; in = wproj; out = wpT;  K = 1024; N = 1024; }
  else if (id < 8192) { rel = id - 4096; in = w1;    out = w1T;  K = 1024; N = 4096; }
  else                { rel = id - 8192; in = w2;    out = w2T;  K = 4096; N = 1024; }
  const int nbx = N >> 5;
  const int n0 = (rel % nbx) << 5, k0 = (rel / nbx) << 5;
  __shared__ float tile[32][33];
  #pragma unroll
  for (int r = 0; r < 32; r += 8)
    tile[ty + r][tx] = in[(size_t)(k0 + ty + r) * N + n0 + tx];
  __syncthreads();
  #pragma unroll
  for (int r = 0; r < 32; r += 8)
    out[(size_t)(n0 + ty + r) * K + k0 + tx] = f2bf(tile[tx][ty + r]);
}

// ---------------- layernorm: [rows][1024] (f32 or bf16 in) -> bf16 out
__device__ __forceinline__ float blockReduce(float v, float* ws){
  #pragma unroll
  for (int m = 1; m < 64; m <<= 1) v += __shfl_xor(v, m, 64);
  int w = threadIdx.x >> 6;
  __syncthreads();
  if ((threadIdx.x & 63) == 0) ws[w] = v;
  __syncthreads();
  return ws[0] + ws[1] + ws[2] + ws[3];
}

struct U16x4 { u16 x, y, z, w; };

template<int BF16IN>
__global__ __launch_bounds__(256) void ln_kernel(const void* __restrict__ in_, const float* __restrict__ g,
    const float* __restrict__ be, u16* __restrict__ out){
  __shared__ float ws[4];
  int row = blockIdx.x;
  float vx, vy, vz, vw;
  if constexpr (BF16IN) {
    const U16x4 v = ((const U16x4*)((const u16*)in_ + ((size_t)row << 10)))[threadIdx.x];
    vx = bf2f(v.x); vy = bf2f(v.y); vz = bf2f(v.z); vw = bf2f(v.w);
  } else {
    const float4 v = ((const float4*)((const float*)in_ + ((size_t)row << 10)))[threadIdx.x];
    vx = v.x; vy = v.y; vz = v.z; vw = v.w;
  }
  float s = vx + vy + vz + vw;
  s = blockReduce(s, ws);
  float mean = s * (1.f / 1024.f);
  float dx = vx - mean, dy = vy - mean, dz = vz - mean, dw = vw - mean;
  float s2 = dx*dx + dy*dy + dz*dz + dw*dw;
  s2 = blockReduce(s2, ws);
  float rstd = rsqrtf(s2 * (1.f / 1024.f) + 1e-5f);
  float4 gv = ((const float4*)g)[threadIdx.x];
  float4 bv = ((const float4*)be)[threadIdx.x];
  U16x4 ov;
  ov.x = f2bf(dx * rstd * gv.x + bv.x);
  ov.y = f2bf(dy * rstd * gv.y + bv.y);
  ov.z = f2bf(dz * rstd * gv.z + bv.z);
  ov.w = f2bf(dw * rstd * gv.w + bv.w);
  ((U16x4*)(out + ((size_t)row << 10)))[threadIdx.x] = ov;
}

// ================= 256x256 8-phase bf16 GEMM (r24: bv cached per-QN) =========
template<int QM, int QN, int LB, int RDA, int RDB, int WAIT, typename F>
__device__ __forceinline__ void ph256(const char* lds, const int (&aoff)[2], const int (&boff)[2],
    bf16x8 (&af)[4][2], bf16x8 (&bv)[2][2][2], f32x4 (&acc)[8][4], F&& stg){
  if constexpr (RDA) {
    const char* Ar = lds + LB*65536 + QM*16384;
    #pragma unroll
    for (int fi = 0; fi < 4; ++fi)
      #pragma unroll
      for (int ks = 0; ks < 2; ++ks)
        af[fi][ks] = *(const bf16x8*)(Ar + fi*2048 + aoff[ks]);
  }
  if constexpr (RDB) {
    const char* Br = lds + LB*65536 + 32768 + QN*16384;
    #pragma unroll
    for (int fj = 0; fj < 2; ++fj)
      #pragma unroll
      for (int ks = 0; ks < 2; ++ks)
        bv[QN][fj][ks] = *(const bf16x8*)(Br + fj*2048 + boff[ks]);
  }
  stg();
  BAR();
  __builtin_amdgcn_s_setprio(1);
  #pragma unroll
  for (int fi = 0; fi < 4; ++fi)
    #pragma unroll
    for (int fj = 0; fj < 2; ++fj){
      acc[QM*4+fi][QN*2+fj] = __builtin_amdgcn_mfma_f32_16x16x32_bf16(af[fi][0], bv[QN][fj][0], acc[QM*4+fi][QN*2+fj], 0, 0, 0);
      acc[QM*4+fi][QN*2+fj] = __builtin_amdgcn_mfma_f32_16x16x32_bf16(af[fi][1], bv[QN][fj][1], acc[QM*4+fi][QN*2+fj], 0, 0, 0);
    }
  __builtin_amdgcn_s_setprio(0);
  if constexpr (WAIT >= 0)
    asm volatile("s_waitcnt vmcnt(%0)" :: "n"(WAIT) : "memory");
  BAR();
}

// EPI 0: bf16 scatter to q/k/v [3][B*NH, S, HD] (+bias); q pre-scaled by 0.125
//        (exact pow-2 scale; removes softmax scale mul from attn inner loop)
// EPI 2: bf16 = gelu(acc + bias)   [tanh-form sigmoid approx; rcp not div]
template<int EPI>
__global__ __launch_bounds__(512, 1) void gemm8(
    const u16* __restrict__ A, const u16* __restrict__ Bt,
    const float* __restrict__ bias, const float* __restrict__ add,
    void* __restrict__ out, int M, int N, int K)
{
  __shared__ char lds[147456];
  const int NT = K >> 6;
  const int NI = NT >> 1;
  const int nbx = N >> 8;
  const int nwg = gridDim.x, orig = blockIdx.x;
  const int q = nwg >> 3, r = nwg & 7, x = orig & 7;
  const int wg = (x < r ? x * (q + 1) : r * (q + 1) + (x - r) * q) + (orig >> 3);
  const int bx = wg % nbx, by = wg / nbx;
  const int m0 = by << 8, n0 = bx << 8;

  const int tid = threadIdx.x, wave = tid >> 6, lane = tid & 63;
  const int wr = (wave >> 2) & 1, wc = wave & 3;
  const int lcol = lane & 15, lrow4 = lane >> 4;

  int aoff[2], boff[2];
  #pragma unroll
  for (int ks = 0; ks < 2; ++ks){
    const int chunk = (ks*4 + lrow4) ^ (lane & 7);
    aoff[ks] = (wr*64 + lcol)*128 + chunk*16;
    boff[ks] = (wc*32 + lcol)*128 + chunk*16;
  }

  const int o0 = tid << 4, o1 = (tid + 512) << 4;
  const int row0 = o0 >> 7, c0 = (o0 >> 4) & 7;
  const int row1 = o1 >> 7, c1 = (o1 >> 4) & 7;
  const char* gbase[2][2][2];
  #pragma unroll
  for (int h = 0; h < 2; ++h) {
    gbase[0][h][0] = (const char*)(A  + (size_t)(m0 + h*128 + row0) * K) + ((c0 ^ (row0 & 7)) << 4);
    gbase[0][h][1] = (const char*)(A  + (size_t)(m0 + h*128 + row1) * K) + ((c1 ^ (row1 & 7)) << 4);
    gbase[1][h][0] = (const char*)(Bt + (size_t)(n0 + h*128 + row0) * K) + ((c0 ^ (row0 & 7)) << 4);
    gbase[1][h][1] = (const char*)(Bt + (size_t)(n0 + h*128 + row1) * K) + ((c1 ^ (row1 & 7)) << 4);
  }

  auto STAGE = [&](int isB, int h, int tt){
    const int rb = (tt < NT) ? ((tt & 1) * 65536 + isB * 32768 + h * 16384) : 131072;
    const size_t tb = (size_t)((tt < NT) ? tt : NT - 1) << 7;
    gload_lds16(gbase[isB][h][0] + tb, (char*)lds + rb + o0);
    gload_lds16(gbase[isB][h][1] + tb, (char*)lds + rb + o1);
  };

  f32x4 acc[8][4] = {};
  bf16x8 af[4][2], bv[2][2][2];

  STAGE(0, 0, 0);
  STAGE(1, 0, 0);
  STAGE(0, 1, 0);
  STAGE(1, 1, 0);
  STAGE(0, 0, 1);
  STAGE(1, 1, 1);
  STAGE(0, 1, 1);
  asm volatile("s_waitcnt vmcnt(6)" ::: "memory");
  BAR();

  for (int i = 0; i < NI; ++i) {
    const int T = 2*i;
    //    QM QN LB RDA RDB  W
    ph256<0, 0, 0, 1,  1, -1>(lds, aoff, boff, af, bv, acc, [&]{ STAGE(1, 0, T+1); });
    ph256<0, 1, 0, 0,  1, -1>(lds, aoff, boff, af, bv, acc, [&]{ STAGE(0, 0, T+2); });
    ph256<1, 1, 0, 1,  0, -1>(lds, aoff, boff, af, bv, acc, [&]{});
    ph256<1, 0, 0, 0,  0,  4>(lds, aoff, boff, af, bv, acc, [&]{ STAGE(1, 1, T+2); });
    ph256<0, 0, 1, 1,  1, -1>(lds, aoff, boff, af, bv, acc, [&]{ STAGE(1, 0, T+2); });
    ph256<0, 1, 1, 0,  1, -1>(lds, aoff, boff, af, bv, acc, [&]{ STAGE(0, 1, T+2); });
    ph256<1, 1, 1, 1,  0, -1>(lds, aoff, boff, af, bv, acc, [&]{ STAGE(0, 0, T+3); });
    ph256<1, 0, 1, 0,  0,  6>(lds, aoff, boff, af, bv, acc, [&]{ STAGE(1, 1, T+3); STAGE(0, 1, T+3); });
  }

  { size_t bp = (size_t)bias, ap = (size_t)add;
    asm volatile("" : "+v"(bp), "+v"(ap));
    bias = (const float*)bp; add = (const float*)ap; }

  #pragma unroll
  for (int mi = 0; mi < 8; ++mi) {
    const int gmb = m0 + (mi>>2)*128 + wr*64 + (mi&3)*16 + lrow4*4;
    #pragma unroll
    for (int ni = 0; ni < 4; ++ni) {
      const int gn = n0 + (ni>>1)*128 + wc*32 + (ni&1)*16 + lcol;
      const float bs = bias[gn];
      #pragma unroll
      for (int rr = 0; rr < 4; ++rr) {
        const int gm = gmb + rr;
        float v = acc[mi][ni][rr] + bs;
        if constexpr (EPI == 0) {
          const int which = gn >> 10, g = gn & 1023;
          const int b = gm >> 11, s = gm & 2047;
          const int h = g >> 6, d = g & 63;
          const float vs = (which == 0) ? v * 0.125f : v;   // q pre-scale (exact)
          ((u16*)out)[(size_t)which * 8388608 + ((((size_t)((b << 4) + h) << 11) + s) << 6) + d] = f2bf(vs);
        } else {
          const float y2 = 1.5957691216f * v + 0.0713548353f * v * v * v;
          const float e = __expf(y2);
          const float rc = __builtin_amdgcn_rcpf(1.f + e);
          ((u16*)out)[(size_t)gm * N + gn] = f2bf(v - v * rc);
        }
      }
    }
  }
}

// ================= 128x256 4-phase bf16 GEMM (wide) ====
// EPI 1: proj  -> out bf16 = acc + bias + add(f32)
// EPI 3: ffn2  -> out f32  = acc + bias + add(bf16)
template<int QN, int LB, int RDA, int WAIT, typename F>
__device__ __forceinline__ void phW(const char* lds, const int (&aoff)[2], const int (&boff)[2],
    bf16x8 (&af)[4][2], bf16x8 (&bv)[2][2], f32x4 (&acc)[4][4], F&& stg){
  if constexpr (RDA) {
    const char* Ar = lds + LB*49152;
    #pragma unroll
    for (int fi = 0; fi < 4; ++fi)
      #pragma unroll
      for (int ks = 0; ks < 2; ++ks)
        af[fi][ks] = *(const bf16x8*)(Ar + fi*2048 + aoff[ks]);
  }
  {
    const char* Br = lds + LB*49152 + 16384 + QN*16384;
    #pragma unroll
    for (int fj = 0; fj < 2; ++fj)
      #pragma unroll
      for (int ks = 0; ks < 2; ++ks)
        bv[fj][ks] = *(const bf16x8*)(Br + fj*2048 + boff[ks]);
  }
  stg();
  BAR();
  __builtin_amdgcn_s_setprio(1);
  #pragma unroll
  for (int fi = 0; fi < 4; ++fi)
    #pragma unroll
    for (int fj = 0; fj < 2; ++fj){
      acc[fi][QN*2+fj] = __builtin_amdgcn_mfma_f32_16x16x32_bf16(af[fi][0], bv[fj][0], acc[fi][QN*2+fj], 0, 0, 0);
      acc[fi][QN*2+fj] = __builtin_amdgcn_mfma_f32_16x16x32_bf16(af[fi][1], bv[fj][1], acc[fi][QN*2+fj], 0, 0, 0);
    }
  __builtin_amdgcn_s_setprio(0);
  if constexpr (WAIT >= 0)
    asm volatile("s_waitcnt vmcnt(%0)" :: "n"(WAIT) : "memory");
  BAR();
}

template<int EPI>
__global__ __launch_bounds__(512, 2) void gemmW(
    const u16* __restrict__ A, const u16* __restrict__ Bt,
    const float* __restrict__ bias, const void* __restrict__ add,
    void* __restrict__ out, int M, int N, int K)
{
  __shared__ char lds[106496];
  const int NT = K >> 6;
  const int NI = NT >> 1;
  const int nbx = N >> 8;
  const int nwg = gridDim.x, orig = blockIdx.x;
  const int q = nwg >> 3, r = nwg & 7, x = orig & 7;
  const int wg = (x < r ? x * (q + 1) : r * (q + 1) + (x - r) * q) + (orig >> 3);
  const int bx = wg % nbx, by = wg / nbx;
  const int m0 = by << 7, n0 = bx << 8;

  const int tid = threadIdx.x, wave = tid >> 6, lane = tid & 63;
  const int wr = wave >> 2, wc = wave & 3;
  const int lcol = lane & 15, lrow4 = lane >> 4;

  int aoff[2], boff[2];
  #pragma unroll
  for (int ks = 0; ks < 2; ++ks){
    const int chunk = (ks*4 + lrow4) ^ (lane & 7);
    aoff[ks] = (wr*64 + lcol)*128 + chunk*16;
    boff[ks] = (wc*32 + lcol)*128 + chunk*16;
  }

  const int o0 = tid << 4, o1 = (tid + 512) << 4;
  const int row0 = o0 >> 7, c0 = (o0 >> 4) & 7;
  const int row1 = o1 >> 7, c1 = (o1 >> 4) & 7;
  const char* gbase[3][2];
  gbase[0][0] = (const char*)(A  + (size_t)(m0 + row0) * K) + ((c0 ^ (row0 & 7)) << 4);
  gbase[0][1] = (const char*)(A  + (size_t)(m0 + row1) * K) + ((c1 ^ (row1 & 7)) << 4);
  gbase[1][0] = (const char*)(Bt + (size_t)(n0 + row0) * K) + ((c0 ^ (row0 & 7)) << 4);
  gbase[1][1] = (const char*)(Bt + (size_t)(n0 + row1) * K) + ((c1 ^ (row1 & 7)) << 4);
  gbase[2][0] = (const char*)(Bt + (size_t)(n0 + 128 + row0) * K) + ((c0 ^ (row0 & 7)) << 4);
  gbase[2][1] = (const char*)(Bt + (size_t)(n0 + 128 + row1) * K) + ((c1 ^ (row1 & 7)) << 4);

  auto STAGE = [&](int kind, int tt){
    const int rb = (tt < NT) ? ((tt & 1) * 49152 + kind * 16384) : 98304;
    const size_t tb = (size_t)((tt < NT) ? tt : NT - 1) << 7;
    gload_lds16(gbase[kind][0] + tb, (char*)lds + rb + o0);
    gload_lds16(gbase[kind][1] + tb, (char*)lds + rb + o1);
  };

  f32x4 acc[4][4] = {};
  bf16x8 af[4][2], bv[2][2];

  STAGE(0, 0);
  STAGE(1, 0);
  STAGE(2, 0);
  STAGE(0, 1);
  STAGE(1, 1);
  asm volatile("s_waitcnt vmcnt(4)" ::: "memory");
  BAR();

  for (int i = 0; i < NI; ++i) {
    const int T = 2*i;
    phW<0, 0, 1, -1>(lds, aoff, boff, af, bv, acc, [&]{ STAGE(2, T+1); });
    phW<1, 0, 0,  4>(lds, aoff, boff, af, bv, acc, [&]{ STAGE(0, T+2); STAGE(1, T+2); });
    phW<0, 1, 1, -1>(lds, aoff, boff, af, bv, acc, [&]{ STAGE(2, T+2); });
    phW<1, 1, 0,  4>(lds, aoff, boff, af, bv, acc, [&]{ STAGE(0, T+3); STAGE(1, T+3); });
  }

  { size_t bp = (size_t)bias, ap = (size_t)add;
    asm volatile("" : "+v"(bp), "+v"(ap));
    bias = (const float*)bp; add = (const void*)ap; }

  #pragma unroll
  for (int fi = 0; fi < 4; ++fi) {
    const int gmb = m0 + wr*64 + fi*16 + lrow4*4;
    #pragma unroll
    for (int j = 0; j < 4; ++j) {
      const int gn = n0 + (j>>1)*128 + wc*32 + (j&1)*16 + lcol;
      const float bs = bias[gn];
      #pragma unroll
      for (int rr = 0; rr < 4; ++rr) {
        const int gm = gmb + rr;
        float v = acc[fi][j][rr] + bs;
        if constexpr (EPI == 1) {
          ((u16*)out)[(size_t)gm * N + gn] = f2bf(v + ((const float*)add)[(size_t)gm * N + gn]);
        } else {
          ((float*)out)[(size_t)gm * N + gn] = v + bf2f(((const u16*)add)[(size_t)gm * N + gn]);
        }
      }
    }
  }
}

// ================= windowed attention: quarter-split + K in LDS, 512 threads ==
// (r19 structure; r21 cvt_pk; r26: Q pre-scaled by 0.125 in qkv -> no scale here)
template<int NJ>  // NJ = W/16 (24 or 32)
__device__ void attn_core(const u16* __restrict__ Qp, u16* __restrict__ ctxP,
    const char* ktb, const char* vtb, int start, int widx, int bh)
{
  const int tid = threadIdx.x, wave = tid >> 6, lane = tid & 63;
  const int q = lane & 15, g = lane >> 4;
  constexpr int QTR = NJ / 4;
  const int b = bh >> 4, h = bh & 15;
  const int sw0 = ((g ^ (q & 7)) << 4);
  const int sw1 = (((4 | g) ^ (q & 7)) << 4);

  for (int qt = wave; qt < NJ; qt += 8) {
    const int q0 = qt * 16;
    const bf16x8 bq0 = *(const bf16x8*)(Qp + (q0 + q) * 64 + g * 8);
    const bf16x8 bq1 = *(const bf16x8*)(Qp + (q0 + q) * 64 + 32 + g * 8);
    float m = -3.0e38f, l = 0.f;
    f32x4 o[4] = {};
    const int s0 = ((g & 1) << 5) + q;
    const int s1 = s0 + 16;
    const bool lowj = (g < 2);

    #pragma unroll
    for (int hh = 0; hh < 4; ++hh) {
      f32x4 acc[QTR];
      #pragma unroll
      for (int j = 0; j < QTR; ++j) {
        const int jj = hh * QTR + j;
        const char* kr = ktb + (jj*16 + q) * 128;
        bf16x8 k0 = *(const bf16x8*)(kr + sw0);
        bf16x8 k1 = *(const bf16x8*)(kr + sw1);
        f32x4 t = {};
        t = __builtin_amdgcn_mfma_f32_16x16x32_bf16(k0, bq0, t, 0, 0, 0);
        t = __builtin_amdgcn_mfma_f32_16x16x32_bf16(k1, bq1, t, 0, 0, 0);
        acc[j] = t;
        if ((j & 3) == 3) __builtin_amdgcn_sched_barrier(0);  // cap read hoisting
      }
      float mh = -3.0e38f;
      #pragma unroll
      for (int j = 0; j < QTR; ++j)
        #pragma unroll
        for (int r = 0; r < 4; ++r) mh = fmaxf(mh, acc[j][r]);
      mh = fmaxf(mh, __shfl_xor(mh, 16, 64));
      mh = fmaxf(mh, __shfl_xor(mh, 32, 64));
      const float mn = fmaxf(m, mh);
      const float fr = __expf(m - mn);        // scores pre-scaled; no scale mul
      m = mn;
      l *= fr;
      #pragma unroll
      for (int df = 0; df < 4; ++df)
        #pragma unroll
        for (int r = 0; r < 4; ++r) o[df][r] *= fr;
      #pragma unroll
      for (int j = 0; j < QTR; ++j)
        #pragma unroll
        for (int r = 0; r < 4; ++r) {
          float e = __expf(acc[j][r] - mn);
          acc[j][r] = e;
          l += e;
        }
      #pragma unroll
      for (int c = 0; c < QTR / 2; ++c) {
        const u32 a0 = pack2cvt(acc[2*c][0],   acc[2*c][1]);
        const u32 b0 = pack2cvt(acc[2*c][2],   acc[2*c][3]);
        const u32 a1 = pack2cvt(acc[2*c+1][0], acc[2*c+1][1]);
        const u32 b1 = pack2cvt(acc[2*c+1][2], acc[2*c+1][3]);
        const u32 A0l = __shfl(a0, s0, 64), A1l = __shfl(a1, s0, 64);
        const u32 B0l = __shfl(b0, s0, 64), B1l = __shfl(b1, s0, 64);
        const u32 A0h = __shfl(a0, s1, 64), A1h = __shfl(a1, s1, 64);
        const u32 B0h = __shfl(b0, s1, 64), B1h = __shfl(b1, s1, 64);
        union { u32 u[4]; bf16x8 v; } pf;
        pf.u[0] = lowj ? A0l : A1l;
        pf.u[1] = lowj ? B0l : B1l;
        pf.u[2] = lowj ? A0h : A1h;
        pf.u[3] = lowj ? B0h : B1h;
        const int cg = hh * (QTR / 2) + c;
        #pragma unroll
        for (int df = 0; df < 4; ++df) {
          bf16x8 pv = *(const bf16x8*)(vtb + swz(df*16 + q, (cg*32 + g*8) * 2));
          o[df] = __builtin_amdgcn_mfma_f32_16x16x32_bf16(pv, pf.v, o[df], 0, 0, 0);
        }
        if ((c & 1) == 1) __builtin_amdgcn_sched_barrier(0);
      }
    }
    l += __shfl_xor(l, 16, 64);
    l += __shfl_xor(l, 32, 64);
    const float rs = __builtin_amdgcn_rcpf(l);   // r26: rcp (l > 0, well-cond.)

    const int p = start + q0 + q;
    const int rel = p - (widx * 256 - 128);
    const float wgt = (rel < 256) ? ((widx == 0) ? 1.f : (float)rel * (1.f / 255.f))
                                  : ((widx == 7) ? 1.f : (1.f - (float)(rel - 256) * (1.f / 255.f)));
    const float rw = rs * wgt;
    u32 w0[4], w1[4];
    #pragma unroll
    for (int df = 0; df < 4; ++df) {
      w0[df] = pack2cvt(o[df][0] * rw, o[df][1] * rw);
      w1[df] = pack2cvt(o[df][2] * rw, o[df][3] * rw);
    }
    u32 W8[8] = {};
    #pragma unroll
    for (int df = 0; df < 4; ++df)
      #pragma unroll
      for (int sg = 0; sg < 4; ++sg) {
        const u32 t0 = __shfl(w0[df], sg*16 + q, 64);
        const u32 t1 = __shfl(w1[df], sg*16 + q, 64);
        if (g == df) { W8[2*sg] = t0; W8[2*sg+1] = t1; }
      }
    u16* dst = ctxP + ((((size_t)(b << 11) + (size_t)p) << 10) + (h << 6) + (g << 4));
    u32x4 lo = { W8[0], W8[1], W8[2], W8[3] };
    u32x4 hi = { W8[4], W8[5], W8[6], W8[7] };
    *(u32x4*)dst = lo;
    *(u32x4*)(dst + 8) = hi;
  }
}

__global__ __launch_bounds__(512, 1) void attn_kernel(const u16* __restrict__ qg, const u16* __restrict__ kg,
    const u16* __restrict__ vg, u16* __restrict__ ctxE, u16* __restrict__ ctxO){
  __shared__ char lds[131072];   // K @0 (64KB), V^T @65536 (64KB) -> 1 block/CU
  const int widx = (int)blockIdx.x >> 6;
  const int bh = blockIdx.x & 63;
  const int i0 = widx << 8;
  int start = i0 - 128; if (start < 0) start = 0;
  int end = i0 + 384;   if (end > 2048) end = 2048;
  const int W = end - start;
  const int tid = threadIdx.x;
  const u16* Qp = qg + (((size_t)bh << 11) + start) * 64;
  const u16* Kp = kg + (((size_t)bh << 11) + start) * 64;
  const u16* Vp = vg + (((size_t)bh << 11) + start) * 64;
  const int nks = W >> 6;             // W*8 16B-chunks / 512 threads
  for (int s = 0; s < nks; ++s) {
    const int o = (tid + s*512) << 4;
    const int row = o >> 7, c = (o >> 4) & 7;
    const char* src = (const char*)(Kp + (size_t)row * 64) + ((c ^ (row & 7)) << 4);
    gload_lds16(src, (char*)lds + o);
  }
  char* vtb = (char*)lds + 65536;
  for (int idx = tid; idx < W * 8; idx += 512) {
    const int key = idx % W, d0 = (idx / W) << 3;
    u16x8 vv = *(const u16x8*)(Vp + key * 64 + d0);
    #pragma unroll
    for (int z = 0; z < 8; ++z)
      *(u16*)(vtb + swz(d0 + z, key * 2)) = vv[z];
  }
  __syncthreads();
  u16* ctxP = (widx & 1) ? ctxO : ctxE;
  if (W == 512) attn_core<32>(Qp, ctxP, (const char*)lds, vtb, start, widx, bh);
  else          attn_core<24>(Qp, ctxP, (const char*)lds, vtb, start, widx, bh);
}

// merge parity buffers: p<128 -> E; p>=1920 -> O; else E+O. In-place on E is safe.
__global__ __launch_bounds__(256) void merge_kernel(const u16* __restrict__ e,
    const u16* __restrict__ o, u16* __restrict__ out){
  const int i = blockIdx.x * 256 + threadIdx.x;     // u16x8 index
  const int p = (i >> 7) & 2047;                    // (i*8 >> 10) & 2047
  u16x8 ev = ((const u16x8*)e)[i];
  u16x8 ov = ((const u16x8*)o)[i];
  u16x8 r;
  if (p < 128)        r = ev;
  else if (p >= 1920) r = ov;
  else {
    #pragma unroll
    for (int z = 0; z < 8; ++z) r[z] = f2bf(bf2f(ev[z]) + bf2f(ov[z]));
  }
  ((u16x8*)out)[i] = r;
}

// ---------------- host
extern "C" void kernel_launch(void* const* d_in, const int* in_sizes, int n_in,
                              void* d_out, int out_size, void* d_ws, size_t ws_size,
                              hipStream_t stream) {
  const float* hidden = (const float*)d_in[0];
  const float* ln1_g  = (const float*)d_in[1];
  const float* ln1_b  = (const float*)d_in[2];
  const float* wq     = (const float*)d_in[3];
  const float* bq     = (const float*)d_in[4];
  const float* wk     = (const float*)d_in[5];
  const float* bk     = (const float*)d_in[6];
  const float* wv     = (const float*)d_in[7];
  const float* bv     = (const float*)d_in[8];
  const float* wproj  = (const float*)d_in[9];
  const float* bproj  = (const float*)d_in[10];
  const float* ln2_g  = (const float*)d_in[11];
  const float* ln2_b  = (const float*)d_in[12];
  const float* w1     = (const float*)d_in[13];
  const float* b1     = (const float*)d_in[14];
  const float* w2     = (const float*)d_in[15];
  const float* b2     = (const float*)d_in[16];

  char* ws = (char*)d_ws;
  u16* xb    = (u16*)(ws + 0);            // 16 MiB (LN1/LN2 out; ctxO during attn)
  u16* wqkvT = (u16*)(ws + 16777216);     // 6 MiB [3072][1024]
  u16* wpT   = (u16*)(ws + 23068672);     // 2 MiB
  u16* w1T   = (u16*)(ws + 25165824);     // 8 MiB
  u16* w2T   = (u16*)(ws + 33554432);     // 8 MiB
  u16* qb    = (u16*)(ws + 41943040);     // q,k,v contiguous: 3 x 16 MiB
  u16* kb    = (u16*)(ws + 58720256);
  u16* vb    = (u16*)(ws + 75497472);
  u16* ctxE  = (u16*)(ws + 92274688);     // 16 MiB (merged ctx in-place)
  u16* ctxO  = (u16*)(ws + 0);            // aliases xb (dead between qkv and ln2)
  float* bqkv = (float*)(ws + 92274688);  // aliases ctxE start (dead before attn)
  u16* res2  = (u16*)(ws + 109051904);    // 16 MiB bf16
  u16* mid   = (u16*)(ws + 41943040);     // 64 MiB, reuses qb..ctx

  prep_kernel<<<12300, dim3(32, 8), 0, stream>>>(wq, wk, wv, wproj, w1, w2,
                                                 bq, bk, bv,
                                                 wqkvT, wpT, w1T, w2T, bqkv);

  ln_kernel<0><<<8192, 256, 0, stream>>>(hidden, ln1_g, ln1_b, xb);

  gemm8<0><<<384, 512, 0, stream>>>(xb, wqkvT, bqkv, nullptr, qb, 8192, 3072, 1024);

  attn_kernel<<<512, 512, 0, stream>>>(qb, kb, vb, ctxE, ctxO);
  merge_kernel<<<4096, 256, 0, stream>>>(ctxE, ctxO, ctxE);

  gemmW<1><<<256, 512, 0, stream>>>(ctxE, wpT, bproj, hidden, res2, 8192, 1024, 1024);

  ln_kernel<1><<<8192, 256, 0, stream>>>(res2, ln2_g, ln2_b, xb);

  gemm8<2><<<512, 512, 0, stream>>>(xb, w1T, b1, nullptr, mid, 8192, 4096, 1024);
  gemmW<3><<<256, 512, 0, stream>>>(mid, w2T, b2, res2, (float*)d_out, 8192, 1024, 4096);
}

// Round 27
// 347.504 us; speedup vs baseline: 1.2274x; 1.0094x over previous
//
#include <hip/hip_runtime.h>
#include <math.h>

typedef unsigned short u16;
typedef unsigned int u32;
typedef __attribute__((ext_vector_type(8))) short bf16x8;
typedef __attribute__((ext_vector_type(8))) unsigned short u16x8;
typedef __attribute__((ext_vector_type(4))) float f32x4;
typedef __attribute__((ext_vector_type(4))) unsigned int u32x4;

__device__ __forceinline__ u16 f2bf(float f){
  union { float f; unsigned u; } c; c.f = f;
  unsigned u = c.u;
  return (u16)((u + 0x7fffu + ((u >> 16) & 1u)) >> 16);
}
__device__ __forceinline__ float bf2f(u16 h){
  union { unsigned u; float f; } c; c.u = ((unsigned)h) << 16;
  return c.f;
}
// single-instruction packed f32->bf16 (RNE), gfx950 has no builtin (T12/m240)
__device__ __forceinline__ u32 pack2cvt(float lo, float hi){
  u32 r;
  asm("v_cvt_pk_bf16_f32 %0, %1, %2" : "=v"(r) : "v"(lo), "v"(hi));
  return r;
}
__device__ __forceinline__ void gload_lds16(const void* g, void* l){
  __builtin_amdgcn_global_load_lds((const __attribute__((address_space(1))) void*)g,
                                   (__attribute__((address_space(3))) void*)l, 16, 0, 0);
}
// attention V^T swizzle (r17): XOR row bits into chunk bits (byte bits 6-9).
__device__ __forceinline__ int swz(int row, int bc){
  return (row << 10) + (bc ^ ((row & 15) << 6));
}

#define BAR() asm volatile("s_barrier" ::: "memory")

__device__ __forceinline__ float blockReduce(float v, float* ws){
  #pragma unroll
  for (int m = 1; m < 64; m <<= 1) v += __shfl_xor(v, m, 64);
  int w = threadIdx.x >> 6;
  __syncthreads();
  if ((threadIdx.x & 63) == 0) ws[w] = v;
  __syncthreads();
  return ws[0] + ws[1] + ws[2] + ws[3];
}

struct U16x4 { u16 x, y, z, w; };

// ---------------- fused prep + LN1: 6 weight transposes + bias concat + LN1,
// one launch (prep and LN1 are independent -> co-scheduled in one wave pool).
// id < 12288: transpose; < 12300: bias concat; else LN1 row = id - 12300.
__global__ __launch_bounds__(256) void prep_ln_kernel(
    const float* __restrict__ wq, const float* __restrict__ wk,
    const float* __restrict__ wv, const float* __restrict__ wproj,
    const float* __restrict__ w1, const float* __restrict__ w2,
    const float* __restrict__ bq, const float* __restrict__ bk,
    const float* __restrict__ bv,
    u16* __restrict__ wqkvT, u16* __restrict__ wpT,
    u16* __restrict__ w1T, u16* __restrict__ w2T, float* __restrict__ bqkv,
    const float* __restrict__ hidden, const float* __restrict__ ln1_g,
    const float* __restrict__ ln1_b, u16* __restrict__ xb)
{
  __shared__ float tile[32][33];
  __shared__ float ws[4];
  const int id = blockIdx.x;
  const int tid = threadIdx.x;

  if (id >= 12300) {                       // ---- LN1 (f32 in, bf16 out)
    const int row = id - 12300;
    const float4 v = ((const float4*)(hidden + ((size_t)row << 10)))[tid];
    float s = v.x + v.y + v.z + v.w;
    s = blockReduce(s, ws);
    float mean = s * (1.f / 1024.f);
    float dx = v.x - mean, dy = v.y - mean, dz = v.z - mean, dw = v.w - mean;
    float s2 = dx*dx + dy*dy + dz*dz + dw*dw;
    s2 = blockReduce(s2, ws);
    float rstd = rsqrtf(s2 * (1.f / 1024.f) + 1e-5f);
    float4 gv = ((const float4*)ln1_g)[tid];
    float4 bvv = ((const float4*)ln1_b)[tid];
    U16x4 ov;
    ov.x = f2bf(dx * rstd * gv.x + bvv.x);
    ov.y = f2bf(dy * rstd * gv.y + bvv.y);
    ov.z = f2bf(dz * rstd * gv.z + bvv.z);
    ov.w = f2bf(dw * rstd * gv.w + bvv.w);
    ((U16x4*)(xb + ((size_t)row << 10)))[tid] = ov;
    return;
  }
  if (id >= 12288) {                       // ---- bias concat
    const int i = (id - 12288) * 256 + tid;
    bqkv[i] = i < 1024 ? bq[i] : (i < 2048 ? bk[i - 1024] : bv[i - 2048]);
    return;
  }
  // ---- weight transpose (f32 [K][N] -> bf16 [N][K])
  const int tx = tid & 31, ty = tid >> 5;
  const float* in; u16* out; int K, N, rel;
  if (id < 3072)      { const int w = id >> 10; rel = id & 1023;
                        in = w == 0 ? wq : (w == 1 ? wk : wv);
                        out = wqkvT + w * 1048576; K = 1024; N = 1024; }
  else if (id < 4096) { rel = id - 3072; in = wproj; out = wpT;  K = 1024; N = 1024; }
  else if (id < 8192) { rel = id - 4096; in = w1;    out = w1T;  K = 1024; N = 4096; }
  else                { rel = id - 8192; in = w2;    out = w2T;  K = 4096; N = 1024; }
  const int nbx = N >> 5;
  const int n0 = (rel % nbx) << 5, k0 = (rel / nbx) << 5;
  #pragma unroll
  for (int r = 0; r < 32; r += 8)
    tile[ty + r][tx] = in[(size_t)(k0 + ty + r) * N + n0 + tx];
  __syncthreads();
  #pragma unroll
  for (int r = 0; r < 32; r += 8)
    out[(size_t)(n0 + ty + r) * K + k0 + tx] = f2bf(tile[tx][ty + r]);
}

// ---------------- layernorm (bf16 in) -> bf16 out (LN2 only)
__global__ __launch_bounds__(256) void ln_kernel(const u16* __restrict__ in_, const float* __restrict__ g,
    const float* __restrict__ be, u16* __restrict__ out){
  __shared__ float ws[4];
  int row = blockIdx.x;
  const U16x4 v = ((const U16x4*)(in_ + ((size_t)row << 10)))[threadIdx.x];
  float vx = bf2f(v.x), vy = bf2f(v.y), vz = bf2f(v.z), vw = bf2f(v.w);
  float s = vx + vy + vz + vw;
  s = blockReduce(s, ws);
  float mean = s * (1.f / 1024.f);
  float dx = vx - mean, dy = vy - mean, dz = vz - mean, dw = vw - mean;
  float s2 = dx*dx + dy*dy + dz*dz + dw*dw;
  s2 = blockReduce(s2, ws);
  float rstd = rsqrtf(s2 * (1.f / 1024.f) + 1e-5f);
  float4 gv = ((const float4*)g)[threadIdx.x];
  float4 bv = ((const float4*)be)[threadIdx.x];
  U16x4 ov;
  ov.x = f2bf(dx * rstd * gv.x + bv.x);
  ov.y = f2bf(dy * rstd * gv.y + bv.y);
  ov.z = f2bf(dz * rstd * gv.z + bv.z);
  ov.w = f2bf(dw * rstd * gv.w + bv.w);
  ((U16x4*)(out + ((size_t)row << 10)))[threadIdx.x] = ov;
}

// ================= 256x256 8-phase bf16 GEMM (r24: bv cached per-QN) =========
template<int QM, int QN, int LB, int RDA, int RDB, int WAIT, typename F>
__device__ __forceinline__ void ph256(const char* lds, const int (&aoff)[2], const int (&boff)[2],
    bf16x8 (&af)[4][2], bf16x8 (&bv)[2][2][2], f32x4 (&acc)[8][4], F&& stg){
  if constexpr (RDA) {
    const char* Ar = lds + LB*65536 + QM*16384;
    #pragma unroll
    for (int fi = 0; fi < 4; ++fi)
      #pragma unroll
      for (int ks = 0; ks < 2; ++ks)
        af[fi][ks] = *(const bf16x8*)(Ar + fi*2048 + aoff[ks]);
  }
  if constexpr (RDB) {
    const char* Br = lds + LB*65536 + 32768 + QN*16384;
    #pragma unroll
    for (int fj = 0; fj < 2; ++fj)
      #pragma unroll
      for (int ks = 0; ks < 2; ++ks)
        bv[QN][fj][ks] = *(const bf16x8*)(Br + fj*2048 + boff[ks]);
  }
  stg();
  BAR();
  __builtin_amdgcn_s_setprio(1);
  #pragma unroll
  for (int fi = 0; fi < 4; ++fi)
    #pragma unroll
    for (int fj = 0; fj < 2; ++fj){
      acc[QM*4+fi][QN*2+fj] = __builtin_amdgcn_mfma_f32_16x16x32_bf16(af[fi][0], bv[QN][fj][0], acc[QM*4+fi][QN*2+fj], 0, 0, 0);
      acc[QM*4+fi][QN*2+fj] = __builtin_amdgcn_mfma_f32_16x16x32_bf16(af[fi][1], bv[QN][fj][1], acc[QM*4+fi][QN*2+fj], 0, 0, 0);
    }
  __builtin_amdgcn_s_setprio(0);
  if constexpr (WAIT >= 0)
    asm volatile("s_waitcnt vmcnt(%0)" :: "n"(WAIT) : "memory");
  BAR();
}

// EPI 0: bf16 scatter to q/k/v [3][B*NH, S, HD] (+bias); q pre-scaled by 0.125
// EPI 2: bf16 = gelu(acc + bias)   [tanh-form sigmoid approx; rcp not div]
template<int EPI>
__global__ __launch_bounds__(512, 1) void gemm8(
    const u16* __restrict__ A, const u16* __restrict__ Bt,
    const float* __restrict__ bias, const float* __restrict__ add,
    void* __restrict__ out, int M, int N, int K)
{
  __shared__ char lds[147456];
  const int NT = K >> 6;
  const int NI = NT >> 1;
  const int nbx = N >> 8;
  const int nwg = gridDim.x, orig = blockIdx.x;
  const int q = nwg >> 3, r = nwg & 7, x = orig & 7;
  const int wg = (x < r ? x * (q + 1) : r * (q + 1) + (x - r) * q) + (orig >> 3);
  const int bx = wg % nbx, by = wg / nbx;
  const int m0 = by << 8, n0 = bx << 8;

  const int tid = threadIdx.x, wave = tid >> 6, lane = tid & 63;
  const int wr = (wave >> 2) & 1, wc = wave & 3;
  const int lcol = lane & 15, lrow4 = lane >> 4;

  int aoff[2], boff[2];
  #pragma unroll
  for (int ks = 0; ks < 2; ++ks){
    const int chunk = (ks*4 + lrow4) ^ (lane & 7);
    aoff[ks] = (wr*64 + lcol)*128 + chunk*16;
    boff[ks] = (wc*32 + lcol)*128 + chunk*16;
  }

  const int o0 = tid << 4, o1 = (tid + 512) << 4;
  const int row0 = o0 >> 7, c0 = (o0 >> 4) & 7;
  const int row1 = o1 >> 7, c1 = (o1 >> 4) & 7;
  const char* gbase[2][2][2];
  #pragma unroll
  for (int h = 0; h < 2; ++h) {
    gbase[0][h][0] = (const char*)(A  + (size_t)(m0 + h*128 + row0) * K) + ((c0 ^ (row0 & 7)) << 4);
    gbase[0][h][1] = (const char*)(A  + (size_t)(m0 + h*128 + row1) * K) + ((c1 ^ (row1 & 7)) << 4);
    gbase[1][h][0] = (const char*)(Bt + (size_t)(n0 + h*128 + row0) * K) + ((c0 ^ (row0 & 7)) << 4);
    gbase[1][h][1] = (const char*)(Bt + (size_t)(n0 + h*128 + row1) * K) + ((c1 ^ (row1 & 7)) << 4);
  }

  auto STAGE = [&](int isB, int h, int tt){
    const int rb = (tt < NT) ? ((tt & 1) * 65536 + isB * 32768 + h * 16384) : 131072;
    const size_t tb = (size_t)((tt < NT) ? tt : NT - 1) << 7;
    gload_lds16(gbase[isB][h][0] + tb, (char*)lds + rb + o0);
    gload_lds16(gbase[isB][h][1] + tb, (char*)lds + rb + o1);
  };

  f32x4 acc[8][4] = {};
  bf16x8 af[4][2], bv[2][2][2];

  STAGE(0, 0, 0);
  STAGE(1, 0, 0);
  STAGE(0, 1, 0);
  STAGE(1, 1, 0);
  STAGE(0, 0, 1);
  STAGE(1, 1, 1);
  STAGE(0, 1, 1);
  asm volatile("s_waitcnt vmcnt(6)" ::: "memory");
  BAR();

  for (int i = 0; i < NI; ++i) {
    const int T = 2*i;
    //    QM QN LB RDA RDB  W
    ph256<0, 0, 0, 1,  1, -1>(lds, aoff, boff, af, bv, acc, [&]{ STAGE(1, 0, T+1); });
    ph256<0, 1, 0, 0,  1, -1>(lds, aoff, boff, af, bv, acc, [&]{ STAGE(0, 0, T+2); });
    ph256<1, 1, 0, 1,  0, -1>(lds, aoff, boff, af, bv, acc, [&]{});
    ph256<1, 0, 0, 0,  0,  4>(lds, aoff, boff, af, bv, acc, [&]{ STAGE(1, 1, T+2); });
    ph256<0, 0, 1, 1,  1, -1>(lds, aoff, boff, af, bv, acc, [&]{ STAGE(1, 0, T+2); });
    ph256<0, 1, 1, 0,  1, -1>(lds, aoff, boff, af, bv, acc, [&]{ STAGE(0, 1, T+2); });
    ph256<1, 1, 1, 1,  0, -1>(lds, aoff, boff, af, bv, acc, [&]{ STAGE(0, 0, T+3); });
    ph256<1, 0, 1, 0,  0,  6>(lds, aoff, boff, af, bv, acc, [&]{ STAGE(1, 1, T+3); STAGE(0, 1, T+3); });
  }

  { size_t bp = (size_t)bias, ap = (size_t)add;
    asm volatile("" : "+v"(bp), "+v"(ap));
    bias = (const float*)bp; add = (const float*)ap; }

  #pragma unroll
  for (int mi = 0; mi < 8; ++mi) {
    const int gmb = m0 + (mi>>2)*128 + wr*64 + (mi&3)*16 + lrow4*4;
    #pragma unroll
    for (int ni = 0; ni < 4; ++ni) {
      const int gn = n0 + (ni>>1)*128 + wc*32 + (ni&1)*16 + lcol;
      const float bs = bias[gn];
      #pragma unroll
      for (int rr = 0; rr < 4; ++rr) {
        const int gm = gmb + rr;
        float v = acc[mi][ni][rr] + bs;
        if constexpr (EPI == 0) {
          const int which = gn >> 10, g = gn & 1023;
          const int b = gm >> 11, s = gm & 2047;
          const int h = g >> 6, d = g & 63;
          const float vs = (which == 0) ? v * 0.125f : v;   // q pre-scale (exact)
          ((u16*)out)[(size_t)which * 8388608 + ((((size_t)((b << 4) + h) << 11) + s) << 6) + d] = f2bf(vs);
        } else {
          const float y2 = 1.5957691216f * v + 0.0713548353f * v * v * v;
          const float e = __expf(y2);
          const float rc = __builtin_amdgcn_rcpf(1.f + e);
          ((u16*)out)[(size_t)gm * N + gn] = f2bf(v - v * rc);
        }
      }
    }
  }
}

// ================= 128x256 4-phase bf16 GEMM (wide) ====
// EPI 1: proj  -> out bf16 = acc + bias + add(f32)
// EPI 3: ffn2  -> out f32  = acc + bias + add(bf16)
template<int QN, int LB, int RDA, int WAIT, typename F>
__device__ __forceinline__ void phW(const char* lds, const int (&aoff)[2], const int (&boff)[2],
    bf16x8 (&af)[4][2], bf16x8 (&bv)[2][2], f32x4 (&acc)[4][4], F&& stg){
  if constexpr (RDA) {
    const char* Ar = lds + LB*49152;
    #pragma unroll
    for (int fi = 0; fi < 4; ++fi)
      #pragma unroll
      for (int ks = 0; ks < 2; ++ks)
        af[fi][ks] = *(const bf16x8*)(Ar + fi*2048 + aoff[ks]);
  }
  {
    const char* Br = lds + LB*49152 + 16384 + QN*16384;
    #pragma unroll
    for (int fj = 0; fj < 2; ++fj)
      #pragma unroll
      for (int ks = 0; ks < 2; ++ks)
        bv[fj][ks] = *(const bf16x8*)(Br + fj*2048 + boff[ks]);
  }
  stg();
  BAR();
  __builtin_amdgcn_s_setprio(1);
  #pragma unroll
  for (int fi = 0; fi < 4; ++fi)
    #pragma unroll
    for (int fj = 0; fj < 2; ++fj){
      acc[fi][QN*2+fj] = __builtin_amdgcn_mfma_f32_16x16x32_bf16(af[fi][0], bv[fj][0], acc[fi][QN*2+fj], 0, 0, 0);
      acc[fi][QN*2+fj] = __builtin_amdgcn_mfma_f32_16x16x32_bf16(af[fi][1], bv[fj][1], acc[fi][QN*2+fj], 0, 0, 0);
    }
  __builtin_amdgcn_s_setprio(0);
  if constexpr (WAIT >= 0)
    asm volatile("s_waitcnt vmcnt(%0)" :: "n"(WAIT) : "memory");
  BAR();
}

template<int EPI>
__global__ __launch_bounds__(512, 2) void gemmW(
    const u16* __restrict__ A, const u16* __restrict__ Bt,
    const float* __restrict__ bias, const void* __restrict__ add,
    void* __restrict__ out, int M, int N, int K)
{
  __shared__ char lds[106496];
  const int NT = K >> 6;
  const int NI = NT >> 1;
  const int nbx = N >> 8;
  const int nwg = gridDim.x, orig = blockIdx.x;
  const int q = nwg >> 3, r = nwg & 7, x = orig & 7;
  const int wg = (x < r ? x * (q + 1) : r * (q + 1) + (x - r) * q) + (orig >> 3);
  const int bx = wg % nbx, by = wg / nbx;
  const int m0 = by << 7, n0 = bx << 8;

  const int tid = threadIdx.x, wave = tid >> 6, lane = tid & 63;
  const int wr = wave >> 2, wc = wave & 3;
  const int lcol = lane & 15, lrow4 = lane >> 4;

  int aoff[2], boff[2];
  #pragma unroll
  for (int ks = 0; ks < 2; ++ks){
    const int chunk = (ks*4 + lrow4) ^ (lane & 7);
    aoff[ks] = (wr*64 + lcol)*128 + chunk*16;
    boff[ks] = (wc*32 + lcol)*128 + chunk*16;
  }

  const int o0 = tid << 4, o1 = (tid + 512) << 4;
  const int row0 = o0 >> 7, c0 = (o0 >> 4) & 7;
  const int row1 = o1 >> 7, c1 = (o1 >> 4) & 7;
  const char* gbase[3][2];
  gbase[0][0] = (const char*)(A  + (size_t)(m0 + row0) * K) + ((c0 ^ (row0 & 7)) << 4);
  gbase[0][1] = (const char*)(A  + (size_t)(m0 + row1) * K) + ((c1 ^ (row1 & 7)) << 4);
  gbase[1][0] = (const char*)(Bt + (size_t)(n0 + row0) * K) + ((c0 ^ (row0 & 7)) << 4);
  gbase[1][1] = (const char*)(Bt + (size_t)(n0 + row1) * K) + ((c1 ^ (row1 & 7)) << 4);
  gbase[2][0] = (const char*)(Bt + (size_t)(n0 + 128 + row0) * K) + ((c0 ^ (row0 & 7)) << 4);
  gbase[2][1] = (const char*)(Bt + (size_t)(n0 + 128 + row1) * K) + ((c1 ^ (row1 & 7)) << 4);

  auto STAGE = [&](int kind, int tt){
    const int rb = (tt < NT) ? ((tt & 1) * 49152 + kind * 16384) : 98304;
    const size_t tb = (size_t)((tt < NT) ? tt : NT - 1) << 7;
    gload_lds16(gbase[kind][0] + tb, (char*)lds + rb + o0);
    gload_lds16(gbase[kind][1] + tb, (char*)lds + rb + o1);
  };

  f32x4 acc[4][4] = {};
  bf16x8 af[4][2], bv[2][2];

  STAGE(0, 0);
  STAGE(1, 0);
  STAGE(2, 0);
  STAGE(0, 1);
  STAGE(1, 1);
  asm volatile("s_waitcnt vmcnt(4)" ::: "memory");
  BAR();

  for (int i = 0; i < NI; ++i) {
    const int T = 2*i;
    phW<0, 0, 1, -1>(lds, aoff, boff, af, bv, acc, [&]{ STAGE(2, T+1); });
    phW<1, 0, 0,  4>(lds, aoff, boff, af, bv, acc, [&]{ STAGE(0, T+2); STAGE(1, T+2); });
    phW<0, 1, 1, -1>(lds, aoff, boff, af, bv, acc, [&]{ STAGE(2, T+2); });
    phW<1, 1, 0,  4>(lds, aoff, boff, af, bv, acc, [&]{ STAGE(0, T+3); STAGE(1, T+3); });
  }

  { size_t bp = (size_t)bias, ap = (size_t)add;
    asm volatile("" : "+v"(bp), "+v"(ap));
    bias = (const float*)bp; add = (const void*)ap; }

  #pragma unroll
  for (int fi = 0; fi < 4; ++fi) {
    const int gmb = m0 + wr*64 + fi*16 + lrow4*4;
    #pragma unroll
    for (int j = 0; j < 4; ++j) {
      const int gn = n0 + (j>>1)*128 + wc*32 + (j&1)*16 + lcol;
      const float bs = bias[gn];
      #pragma unroll
      for (int rr = 0; rr < 4; ++rr) {
        const int gm = gmb + rr;
        float v = acc[fi][j][rr] + bs;
        if constexpr (EPI == 1) {
          ((u16*)out)[(size_t)gm * N + gn] = f2bf(v + ((const float*)add)[(size_t)gm * N + gn]);
        } else {
          ((float*)out)[(size_t)gm * N + gn] = v + bf2f(((const u16*)add)[(size_t)gm * N + gn]);
        }
      }
    }
  }
}

// ================= windowed attention: quarter-split + K in LDS, 512 threads ==
// (r19 structure; r21 cvt_pk; r26: Q pre-scaled, rcp for 1/l)
template<int NJ>  // NJ = W/16 (24 or 32)
__device__ void attn_core(const u16* __restrict__ Qp, u16* __restrict__ ctxP,
    const char* ktb, const char* vtb, int start, int widx, int bh)
{
  const int tid = threadIdx.x, wave = tid >> 6, lane = tid & 63;
  const int q = lane & 15, g = lane >> 4;
  constexpr int QTR = NJ / 4;
  const int b = bh >> 4, h = bh & 15;
  const int sw0 = ((g ^ (q & 7)) << 4);
  const int sw1 = (((4 | g) ^ (q & 7)) << 4);

  for (int qt = wave; qt < NJ; qt += 8) {
    const int q0 = qt * 16;
    const bf16x8 bq0 = *(const bf16x8*)(Qp + (q0 + q) * 64 + g * 8);
    const bf16x8 bq1 = *(const bf16x8*)(Qp + (q0 + q) * 64 + 32 + g * 8);
    float m = -3.0e38f, l = 0.f;
    f32x4 o[4] = {};
    const int s0 = ((g & 1) << 5) + q;
    const int s1 = s0 + 16;
    const bool lowj = (g < 2);

    #pragma unroll
    for (int hh = 0; hh < 4; ++hh) {
      f32x4 acc[QTR];
      #pragma unroll
      for (int j = 0; j < QTR; ++j) {
        const int jj = hh * QTR + j;
        const char* kr = ktb + (jj*16 + q) * 128;
        bf16x8 k0 = *(const bf16x8*)(kr + sw0);
        bf16x8 k1 = *(const bf16x8*)(kr + sw1);
        f32x4 t = {};
        t = __builtin_amdgcn_mfma_f32_16x16x32_bf16(k0, bq0, t, 0, 0, 0);
        t = __builtin_amdgcn_mfma_f32_16x16x32_bf16(k1, bq1, t, 0, 0, 0);
        acc[j] = t;
        if ((j & 3) == 3) __builtin_amdgcn_sched_barrier(0);  // cap read hoisting
      }
      float mh = -3.0e38f;
      #pragma unroll
      for (int j = 0; j < QTR; ++j)
        #pragma unroll
        for (int r = 0; r < 4; ++r) mh = fmaxf(mh, acc[j][r]);
      mh = fmaxf(mh, __shfl_xor(mh, 16, 64));
      mh = fmaxf(mh, __shfl_xor(mh, 32, 64));
      const float mn = fmaxf(m, mh);
      const float fr = __expf(m - mn);        // scores pre-scaled; no scale mul
      m = mn;
      l *= fr;
      #pragma unroll
      for (int df = 0; df < 4; ++df)
        #pragma unroll
        for (int r = 0; r < 4; ++r) o[df][r] *= fr;
      #pragma unroll
      for (int j = 0; j < QTR; ++j)
        #pragma unroll
        for (int r = 0; r < 4; ++r) {
          float e = __expf(acc[j][r] - mn);
          acc[j][r] = e;
          l += e;
        }
      #pragma unroll
      for (int c = 0; c < QTR / 2; ++c) {
        const u32 a0 = pack2cvt(acc[2*c][0],   acc[2*c][1]);
        const u32 b0 = pack2cvt(acc[2*c][2],   acc[2*c][3]);
        const u32 a1 = pack2cvt(acc[2*c+1][0], acc[2*c+1][1]);
        const u32 b1 = pack2cvt(acc[2*c+1][2], acc[2*c+1][3]);
        const u32 A0l = __shfl(a0, s0, 64), A1l = __shfl(a1, s0, 64);
        const u32 B0l = __shfl(b0, s0, 64), B1l = __shfl(b1, s0, 64);
        const u32 A0h = __shfl(a0, s1, 64), A1h = __shfl(a1, s1, 64);
        const u32 B0h = __shfl(b0, s1, 64), B1h = __shfl(b1, s1, 64);
        union { u32 u[4]; bf16x8 v; } pf;
        pf.u[0] = lowj ? A0l : A1l;
        pf.u[1] = lowj ? B0l : B1l;
        pf.u[2] = lowj ? A0h : A1h;
        pf.u[3] = lowj ? B0h : B1h;
        const int cg = hh * (QTR / 2) + c;
        #pragma unroll
        for (int df = 0; df < 4; ++df) {
          bf16x8 pv = *(const bf16x8*)(vtb + swz(df*16 + q, (cg*32 + g*8) * 2));
          o[df] = __builtin_amdgcn_mfma_f32_16x16x32_bf16(pv, pf.v, o[df], 0, 0, 0);
        }
        if ((c & 1) == 1) __builtin_amdgcn_sched_barrier(0);
      }
    }
    l += __shfl_xor(l, 16, 64);
    l += __shfl_xor(l, 32, 64);
    const float rs = __builtin_amdgcn_rcpf(l);

    const int p = start + q0 + q;
    const int rel = p - (widx * 256 - 128);
    const float wgt = (rel < 256) ? ((widx == 0) ? 1.f : (float)rel * (1.f / 255.f))
                                  : ((widx == 7) ? 1.f : (1.f - (float)(rel - 256) * (1.f / 255.f)));
    const float rw = rs * wgt;
    u32 w0[4], w1[4];
    #pragma unroll
    for (int df = 0; df < 4; ++df) {
      w0[df] = pack2cvt(o[df][0] * rw, o[df][1] * rw);
      w1[df] = pack2cvt(o[df][2] * rw, o[df][3] * rw);
    }
    u32 W8[8] = {};
    #pragma unroll
    for (int df = 0; df < 4; ++df)
      #pragma unroll
      for (int sg = 0; sg < 4; ++sg) {
        const u32 t0 = __shfl(w0[df], sg*16 + q, 64);
        const u32 t1 = __shfl(w1[df], sg*16 + q, 64);
        if (g == df) { W8[2*sg] = t0; W8[2*sg+1] = t1; }
      }
    u16* dst = ctxP + ((((size_t)(b << 11) + (size_t)p) << 10) + (h << 6) + (g << 4));
    u32x4 lo = { W8[0], W8[1], W8[2], W8[3] };
    u32x4 hi = { W8[4], W8[5], W8[6], W8[7] };
    *(u32x4*)dst = lo;
    *(u32x4*)(dst + 8) = hi;
  }
}

__global__ __launch_bounds__(512, 1) void attn_kernel(const u16* __restrict__ qg, const u16* __restrict__ kg,
    const u16* __restrict__ vg, u16* __restrict__ ctxE, u16* __restrict__ ctxO){
  __shared__ char lds[131072];   // K @0 (64KB), V^T @65536 (64KB) -> 1 block/CU
  const int widx = (int)blockIdx.x >> 6;
  const int bh = blockIdx.x & 63;
  const int i0 = widx << 8;
  int start = i0 - 128; if (start < 0) start = 0;
  int end = i0 + 384;   if (end > 2048) end = 2048;
  const int W = end - start;
  const int tid = threadIdx.x;
  const u16* Qp = qg + (((size_t)bh << 11) + start) * 64;
  const u16* Kp = kg + (((size_t)bh << 11) + start) * 64;
  const u16* Vp = vg + (((size_t)bh << 11) + start) * 64;
  const int nks = W >> 6;             // W*8 16B-chunks / 512 threads
  for (int s = 0; s < nks; ++s) {
    const int o = (tid + s*512) << 4;
    const int row = o >> 7, c = (o >> 4) & 7;
    const char* src = (const char*)(Kp + (size_t)row * 64) + ((c ^ (row & 7)) << 4);
    gload_lds16(src, (char*)lds + o);
  }
  char* vtb = (char*)lds + 65536;
  for (int idx = tid; idx < W * 8; idx += 512) {
    const int key = idx % W, d0 = (idx / W) << 3;
    u16x8 vv = *(const u16x8*)(Vp + key * 64 + d0);
    #pragma unroll
    for (int z = 0; z < 8; ++z)
      *(u16*)(vtb + swz(d0 + z, key * 2)) = vv[z];
  }
  __syncthreads();
  u16* ctxP = (widx & 1) ? ctxO : ctxE;
  if (W == 512) attn_core<32>(Qp, ctxP, (const char*)lds, vtb, start, widx, bh);
  else          attn_core<24>(Qp, ctxP, (const char*)lds, vtb, start, widx, bh);
}

// merge parity buffers: p<128 -> E; p>=1920 -> O; else E+O. In-place on E is safe.
__global__ __launch_bounds__(256) void merge_kernel(const u16* __restrict__ e,
    const u16* __restrict__ o, u16* __restrict__ out){
  const int i = blockIdx.x * 256 + threadIdx.x;     // u16x8 index
  const int p = (i >> 7) & 2047;                    // (i*8 >> 10) & 2047
  u16x8 ev = ((const u16x8*)e)[i];
  u16x8 ov = ((const u16x8*)o)[i];
  u16x8 r;
  if (p < 128)        r = ev;
  else if (p >= 1920) r = ov;
  else {
    #pragma unroll
    for (int z = 0; z < 8; ++z) r[z] = f2bf(bf2f(ev[z]) + bf2f(ov[z]));
  }
  ((u16x8*)out)[i] = r;
}

// ---------------- host
extern "C" void kernel_launch(void* const* d_in, const int* in_sizes, int n_in,
                              void* d_out, int out_size, void* d_ws, size_t ws_size,
                              hipStream_t stream) {
  const float* hidden = (const float*)d_in[0];
  const float* ln1_g  = (const float*)d_in[1];
  const float* ln1_b  = (const float*)d_in[2];
  const float* wq     = (const float*)d_in[3];
  const float* bq     = (const float*)d_in[4];
  const float* wk     = (const float*)d_in[5];
  const float* bk     = (const float*)d_in[6];
  const float* wv     = (const float*)d_in[7];
  const float* bv     = (const float*)d_in[8];
  const float* wproj  = (const float*)d_in[9];
  const float* bproj  = (const float*)d_in[10];
  const float* ln2_g  = (const float*)d_in[11];
  const float* ln2_b  = (const float*)d_in[12];
  const float* w1     = (const float*)d_in[13];
  const float* b1     = (const float*)d_in[14];
  const float* w2     = (const float*)d_in[15];
  const float* b2     = (const float*)d_in[16];

  char* ws = (char*)d_ws;
  u16* xb    = (u16*)(ws + 0);            // 16 MiB (LN1/LN2 out; ctxO during attn)
  u16* wqkvT = (u16*)(ws + 16777216);     // 6 MiB [3072][1024]
  u16* wpT   = (u16*)(ws + 23068672);     // 2 MiB
  u16* w1T   = (u16*)(ws + 25165824);     // 8 MiB
  u16* w2T   = (u16*)(ws + 33554432);     // 8 MiB
  u16* qb    = (u16*)(ws + 41943040);     // q,k,v contiguous: 3 x 16 MiB
  u16* kb    = (u16*)(ws + 58720256);
  u16* vb    = (u16*)(ws + 75497472);
  u16* ctxE  = (u16*)(ws + 92274688);     // 16 MiB (merged ctx in-place)
  u16* ctxO  = (u16*)(ws + 0);            // aliases xb (dead between qkv and ln2)
  float* bqkv = (float*)(ws + 92274688);  // aliases ctxE start (dead before attn)
  u16* res2  = (u16*)(ws + 109051904);    // 16 MiB bf16
  u16* mid   = (u16*)(ws + 41943040);     // 64 MiB, reuses qb..ctx

  // fused: 6 weight transposes + bias concat + LN1 (independent work, one pool)
  prep_ln_kernel<<<20492, 256, 0, stream>>>(wq, wk, wv, wproj, w1, w2,
                                            bq, bk, bv,
                                            wqkvT, wpT, w1T, w2T, bqkv,
                                            hidden, ln1_g, ln1_b, xb);

  gemm8<0><<<384, 512, 0, stream>>>(xb, wqkvT, bqkv, nullptr, qb, 8192, 3072, 1024);

  attn_kernel<<<512, 512, 0, stream>>>(qb, kb, vb, ctxE, ctxO);
  merge_kernel<<<4096, 256, 0, stream>>>(ctxE, ctxO, ctxE);

  gemmW<1><<<256, 512, 0, stream>>>(ctxE, wpT, bproj, hidden, res2, 8192, 1024, 1024);

  ln_kernel<<<8192, 256, 0, stream>>>(res2, ln2_g, ln2_b, xb);

  gemm8<2><<<512, 512, 0, stream>>>(xb, w1T, b1, nullptr, mid, 8192, 4096, 1024);
  gemmW<3><<<256, 512, 0, stream>>>(mid, w2T, b2, res2, (float*)d_out, 8192, 1024, 4096);
}